// Round 2
// baseline (5872.167 us; speedup 1.0000x reference)
//
#include <hip/hip_runtime.h>
#include <hip/hip_bf16.h>
#include <math.h>

#define B_ 16
#define L_ 3072
#define D_ 512
#define H_ 8
#define DH_ 64
#define CH_ (B_ * D_)   // 8192 channels (b*512 + h*64 + dh)
#define TOPK_ 40

// ---------------------------------------------------------------------------
// Projection GEMM: P[c][t] = sum_j X[b][t][j] * W[i][j] + bias[i],
// c = bz*512 + i (bz = chunk-local batch), output channel-major [nb*512][L_].
// AccT = double for Q/K (selection-critical precision), float for V.
// grid (L/64, D/64, nb), block 256.
// ---------------------------------------------------------------------------
template <typename AccT>
__global__ __launch_bounds__(256) void proj_kernel(const float* __restrict__ X,
                                                   const float* __restrict__ W,
                                                   const float* __restrict__ bias,
                                                   AccT* __restrict__ P) {
  __shared__ float Xs[64][65];  // [t][j]
  __shared__ float Ws[64][65];  // [i][j]
  const int t0 = blockIdx.x * 64;
  const int i0 = blockIdx.y * 64;
  const int b  = blockIdx.z;
  const int tid = threadIdx.x;
  const int tx = tid & 15, ty = tid >> 4;

  AccT acc[4][4];
#pragma unroll
  for (int r = 0; r < 4; ++r)
#pragma unroll
    for (int s = 0; s < 4; ++s) acc[r][s] = (AccT)0;

  for (int j0 = 0; j0 < D_; j0 += 64) {
#pragma unroll
    for (int p = 0; p < 4; ++p) {
      int flat = p * 256 + tid;
      int row = flat >> 4, c4 = (flat & 15) << 2;
      float4 xv = *(const float4*)(X + ((size_t)b * L_ + t0 + row) * D_ + j0 + c4);
      Xs[row][c4 + 0] = xv.x; Xs[row][c4 + 1] = xv.y;
      Xs[row][c4 + 2] = xv.z; Xs[row][c4 + 3] = xv.w;
      float4 wv = *(const float4*)(W + (size_t)(i0 + row) * D_ + j0 + c4);
      Ws[row][c4 + 0] = wv.x; Ws[row][c4 + 1] = wv.y;
      Ws[row][c4 + 2] = wv.z; Ws[row][c4 + 3] = wv.w;
    }
    __syncthreads();
#pragma unroll 4
    for (int kk = 0; kk < 64; ++kk) {
      float a[4], w4[4];
#pragma unroll
      for (int r = 0; r < 4; ++r) a[r] = Xs[4 * ty + r][kk];
#pragma unroll
      for (int s = 0; s < 4; ++s) w4[s] = Ws[4 * tx + s][kk];
#pragma unroll
      for (int r = 0; r < 4; ++r)
#pragma unroll
        for (int s = 0; s < 4; ++s)
          acc[r][s] += (AccT)a[r] * (AccT)w4[s];
    }
    __syncthreads();
  }
#pragma unroll
  for (int s = 0; s < 4; ++s) {
    int i = i0 + 4 * tx + s;
    AccT bia = (AccT)bias[i];
#pragma unroll
    for (int r = 0; r < 4; ++r) {
      int t = t0 + 4 * ty + r;
      P[(size_t)(b * D_ + i) * L_ + t] = acc[r][s] + bia;
    }
  }
}

// ---------------------------------------------------------------------------
// Autocorrelation (f64, direct O(L^2)) + exact top-40 extraction per channel.
// ac[tau] = sum_t q[(t+tau)%L] * k[t]. One block (256 thr) per channel.
// Each thread owns 12 contiguous lags via a 12-register sliding window:
// per t-step: 1 LDS q read + 1 broadcast k read + 12 f64 FMAs.
// c0 = global channel offset of this chunk.
// ---------------------------------------------------------------------------
__global__ __launch_bounds__(256) void autocorr_topk_kernel(const double* __restrict__ Q,
                                                            const double* __restrict__ K,
                                                            double* __restrict__ top_vals,
                                                            int* __restrict__ top_idx,
                                                            int c0) {
  __shared__ double q_s[L_];
  __shared__ double k_s[L_];
  __shared__ double redv[4];
  __shared__ int    redi[4];
  const int c = blockIdx.x;
  const int tid = threadIdx.x;
  const double* Qp = Q + (size_t)c * L_;
  const double* Kp = K + (size_t)c * L_;
  for (int i = tid; i < L_; i += 256) { q_s[i] = Qp[i]; k_s[i] = Kp[i]; }
  __syncthreads();

  const int tau0 = tid * 12;
  double acc[12];
#pragma unroll
  for (int r = 0; r < 12; ++r) acc[r] = 0.0;
  double w[12];
  int ri = tau0;
#pragma unroll
  for (int j = 0; j < 12; ++j) { w[j] = q_s[ri]; ri = (ri + 1 == L_) ? 0 : ri + 1; }

  for (int tb = 0; tb < L_; tb += 12) {
#pragma unroll
    for (int j = 0; j < 12; ++j) {
      double kv = k_s[tb + j];
#pragma unroll
      for (int r = 0; r < 12; ++r)
        acc[r] = fma(w[(j + r) % 12], kv, acc[r]);  // w[(j+r)%12] == q[(tau0+t+r)%L]
      w[j] = q_s[ri];
      ri = (ri + 1 == L_) ? 0 : ri + 1;
    }
  }
  __syncthreads();                 // everyone done reading q_s
  double* ac_s = q_s;              // reuse q buffer for ac
#pragma unroll
  for (int r = 0; r < 12; ++r) ac_s[tau0 + r] = acc[r];
  __syncthreads();

  // iterative argmax extraction, tie -> smaller index (matches lax.top_k)
  for (int kk = 0; kk < TOPK_; ++kk) {
    double bv = -INFINITY; int bi = 1 << 30;
#pragma unroll
    for (int r = 0; r < 12; ++r) {
      int i = r * 256 + tid;
      double v = ac_s[i];
      if (v > bv || (v == bv && i < bi)) { bv = v; bi = i; }
    }
#pragma unroll
    for (int off = 32; off > 0; off >>= 1) {
      double ov = __shfl_down(bv, off);
      int    oi = __shfl_down(bi, off);
      if (ov > bv || (ov == bv && oi < bi)) { bv = ov; bi = oi; }
    }
    int wv = tid >> 6;
    if ((tid & 63) == 0) { redv[wv] = bv; redi[wv] = bi; }
    __syncthreads();
    if (tid == 0) {
      bv = redv[0]; bi = redi[0];
#pragma unroll
      for (int u = 1; u < 4; ++u)
        if (redv[u] > bv || (redv[u] == bv && redi[u] < bi)) { bv = redv[u]; bi = redi[u]; }
      top_vals[(size_t)(c0 + c) * TOPK_ + kk] = bv;
      top_idx[(size_t)(c0 + c) * TOPK_ + kk]  = bi;
      ac_s[bi] = -1.0e308;  // remove from further consideration
    }
    __syncthreads();
  }
}

// ---------------------------------------------------------------------------
// shifts[k] = int(mean over channels of top_idx[c][k]); f64 mean, trunc.
// grid = TOPK_ blocks of 256.
// ---------------------------------------------------------------------------
__global__ __launch_bounds__(256) void shifts_kernel(const int* __restrict__ top_idx,
                                                     int* __restrict__ shifts) {
  const int k = blockIdx.x;
  __shared__ double sred[256];
  double s = 0.0;
  for (int c = threadIdx.x; c < CH_; c += 256) s += (double)top_idx[(size_t)c * TOPK_ + k];
  sred[threadIdx.x] = s;
  __syncthreads();
  for (int o = 128; o > 0; o >>= 1) {
    if (threadIdx.x < o) sred[threadIdx.x] += sred[threadIdx.x + o];
    __syncthreads();
  }
  if (threadIdx.x == 0) shifts[k] = (int)((float)(sred[0] / (double)CH_));
}

// ---------------------------------------------------------------------------
// Per-channel softmax over the 40 top values. One thread per channel.
// ---------------------------------------------------------------------------
__global__ __launch_bounds__(256) void softmax_kernel(const double* __restrict__ top_vals,
                                                      float* __restrict__ weights) {
  const int c = blockIdx.x * 256 + threadIdx.x;
  const double* v = top_vals + (size_t)c * TOPK_;
  double m = v[0];
  for (int k = 1; k < TOPK_; ++k) m = fmax(m, v[k]);
  double sum = 0.0;
  for (int k = 0; k < TOPK_; ++k) sum += exp(v[k] - m);
  double inv = 1.0 / sum;
  for (int k = 0; k < TOPK_; ++k)
    weights[(size_t)c * TOPK_ + k] = (float)(exp(v[k] - m) * inv);
}

// ---------------------------------------------------------------------------
// agg[c][t] = sum_k w[c][k] * V[c][(t + shift[k]) % L]. Block per channel.
// IN-PLACE: the V row is staged in LDS, then the same global row is
// overwritten with agg (only this block touches this row).
// ---------------------------------------------------------------------------
__global__ __launch_bounds__(256) void agg_kernel(float* __restrict__ Vc,
                                                  const float* __restrict__ weights,
                                                  const int* __restrict__ shifts) {
  const int c = blockIdx.x;
  __shared__ float v_s[L_];
  __shared__ float w_s[TOPK_];
  __shared__ int   s_s[TOPK_];
  for (int i = threadIdx.x; i < L_; i += 256) v_s[i] = Vc[(size_t)c * L_ + i];
  if (threadIdx.x < TOPK_) {
    w_s[threadIdx.x] = weights[(size_t)c * TOPK_ + threadIdx.x];
    s_s[threadIdx.x] = shifts[threadIdx.x];
  }
  __syncthreads();
  for (int t = threadIdx.x; t < L_; t += 256) {
    float sum = 0.0f;
#pragma unroll
    for (int k = 0; k < TOPK_; ++k) {
      int idx = t + s_s[k];
      if (idx >= L_) idx -= L_;
      sum = fmaf(w_s[k], v_s[idx], sum);
    }
    Vc[(size_t)c * L_ + t] = sum;
  }
}

// ---------------------------------------------------------------------------
// out[b][t][i] = sum_j agg[b*512+j][t] * Wo[i][j] + bo[i].
// agg is channel-major; tile-transpose through LDS. grid (L/64, D/64, NB).
// For bounce mode, pass pre-offset pointers and gridDim.z == 1.
// ---------------------------------------------------------------------------
__global__ __launch_bounds__(256) void out_gemm_kernel(const float* __restrict__ agg,
                                                       const float* __restrict__ Wo,
                                                       const float* __restrict__ bo,
                                                       float* __restrict__ out) {
  __shared__ float As[64][65];  // [jj][tt]
  __shared__ float Bs[64][65];  // [ii][jj]
  const int t0 = blockIdx.x * 64;
  const int i0 = blockIdx.y * 64;
  const int b  = blockIdx.z;
  const int tid = threadIdx.x;
  const int tx = tid & 15, ty = tid >> 4;

  float acc[4][4];
#pragma unroll
  for (int r = 0; r < 4; ++r)
#pragma unroll
    for (int s = 0; s < 4; ++s) acc[r][s] = 0.0f;

  for (int j0 = 0; j0 < D_; j0 += 64) {
#pragma unroll
    for (int p = 0; p < 4; ++p) {
      int flat = p * 256 + tid;
      int row = flat >> 4, c4 = (flat & 15) << 2;
      float4 av = *(const float4*)(agg + (size_t)(b * D_ + j0 + row) * L_ + t0 + c4);
      As[row][c4 + 0] = av.x; As[row][c4 + 1] = av.y;
      As[row][c4 + 2] = av.z; As[row][c4 + 3] = av.w;
      float4 wv = *(const float4*)(Wo + (size_t)(i0 + row) * D_ + j0 + c4);
      Bs[row][c4 + 0] = wv.x; Bs[row][c4 + 1] = wv.y;
      Bs[row][c4 + 2] = wv.z; Bs[row][c4 + 3] = wv.w;
    }
    __syncthreads();
#pragma unroll 4
    for (int kk = 0; kk < 64; ++kk) {
      float a[4], w4[4];
#pragma unroll
      for (int r = 0; r < 4; ++r) a[r] = As[kk][4 * ty + r];
#pragma unroll
      for (int s = 0; s < 4; ++s) w4[s] = Bs[4 * tx + s][kk];
#pragma unroll
      for (int r = 0; r < 4; ++r)
#pragma unroll
        for (int s = 0; s < 4; ++s)
          acc[r][s] += a[r] * w4[s];
    }
    __syncthreads();
  }
#pragma unroll
  for (int r = 0; r < 4; ++r) {
    int t = t0 + 4 * ty + r;
#pragma unroll
    for (int s = 0; s < 4; ++s) {
      int i = i0 + 4 * tx + s;
      out[((size_t)b * L_ + t) * D_ + i] = acc[r][s] + bo[i];
    }
  }
}

// ---------------------------------------------------------------------------
extern "C" void kernel_launch(void* const* d_in, const int* in_sizes, int n_in,
                              void* d_out, int out_size, void* d_ws, size_t ws_size,
                              hipStream_t stream) {
  const float* query = (const float*)d_in[0];
  const float* key   = (const float*)d_in[1];
  const float* value = (const float*)d_in[2];
  const float* Wq = (const float*)d_in[3];
  const float* bq = (const float*)d_in[4];
  const float* Wk = (const float*)d_in[5];
  const float* bk = (const float*)d_in[6];
  const float* Wv = (const float*)d_in[7];
  const float* bvp = (const float*)d_in[8];
  const float* Wo = (const float*)d_in[9];
  const float* bo = (const float*)d_in[10];
  float* out = (float*)d_out;
  char* ws = (char*)d_ws;

  // ---- adaptive workspace layout (NEVER exceed ws_size) ----
  auto al = [](size_t x) { return (x + 255) & ~(size_t)255; };
  size_t off = 0;
  const size_t tv_off = off; off = al(off + (size_t)CH_ * TOPK_ * 8);  // top_vals f64
  const size_t ti_off = off; off = al(off + (size_t)CH_ * TOPK_ * 4);  // top_idx i32
  const size_t w_off  = off; off = al(off + (size_t)CH_ * TOPK_ * 4);  // weights f32
  const size_t sh_off = off; off = al(off + (size_t)TOPK_ * 4);        // shifts i32
  const size_t small_end = off;                                        // ~5.3 MB

  const size_t PBQK         = (size_t)2 * D_ * L_ * 8;   // Q+K f64, one batch: 25.2 MB
  const size_t AGG_BYTES    = (size_t)CH_ * L_ * 4;      // 96 MB
  const size_t BOUNCE_BYTES = (size_t)D_ * L_ * 4;       // 6 MB

  int nb;           // batches per Q/K chunk
  bool bounce;      // true: V/agg live in d_out, out-GEMM via bounce slab
  if (ws_size >= small_end + AGG_BYTES + PBQK) {
    bounce = false;
    size_t rem = ws_size - small_end - AGG_BYTES;
    size_t n = rem / PBQK; nb = (int)(n > 16 ? 16 : n);
  } else {
    bounce = true;
    size_t rem = (ws_size > small_end + BOUNCE_BYTES) ? (ws_size - small_end - BOUNCE_BYTES) : 0;
    size_t n = rem / PBQK; nb = (int)(n > 16 ? 16 : n);
    if (nb < 1) nb = 1;  // below ~37 MB we cannot degrade further
  }

  double* top_vals = (double*)(ws + tv_off);
  int*    top_idx  = (int*)(ws + ti_off);
  float*  weights  = (float*)(ws + w_off);
  int*    shifts   = (int*)(ws + sh_off);

  float* VcAgg;
  float* bounce_buf = nullptr;
  size_t qk_off;
  if (!bounce) {
    VcAgg = (float*)(ws + small_end);
    qk_off = small_end + al(AGG_BYTES);
  } else {
    bounce_buf = (float*)(ws + small_end);
    qk_off = small_end + al(BOUNCE_BYTES);
    VcAgg = (float*)d_out;  // same element count as [CH_][L_]
  }
  double* Qc = (double*)(ws + qk_off);
  double* Kc = Qc + (size_t)nb * D_ * L_;

  // ---- selection path: chunked f64 Q/K projection + autocorr/top-k ----
  dim3 blk(256);
  for (int b0 = 0; b0 < B_; b0 += nb) {
    int nbb = (B_ - b0 < nb) ? (B_ - b0) : nb;
    dim3 g(L_ / 64, D_ / 64, nbb);
    proj_kernel<double><<<g, blk, 0, stream>>>(query + (size_t)b0 * L_ * D_, Wq, bq, Qc);
    proj_kernel<double><<<g, blk, 0, stream>>>(key   + (size_t)b0 * L_ * D_, Wk, bk, Kc);
    autocorr_topk_kernel<<<nbb * D_, blk, 0, stream>>>(Qc, Kc, top_vals, top_idx, b0 * D_);
  }
  shifts_kernel<<<TOPK_, blk, 0, stream>>>(top_idx, shifts);
  softmax_kernel<<<CH_ / 256, blk, 0, stream>>>(top_vals, weights);

  // ---- value path ----
  {
    dim3 g(L_ / 64, D_ / 64, B_);
    proj_kernel<float><<<g, blk, 0, stream>>>(value, Wv, bvp, VcAgg);
  }
  agg_kernel<<<CH_, blk, 0, stream>>>(VcAgg, weights, shifts);

  if (!bounce) {
    dim3 g(L_ / 64, D_ / 64, B_);
    out_gemm_kernel<<<g, blk, 0, stream>>>(VcAgg, Wo, bo, out);
  } else {
    for (int b = 0; b < B_; ++b) {
      hipMemcpyAsync(bounce_buf, VcAgg + (size_t)b * D_ * L_, BOUNCE_BYTES,
                     hipMemcpyDeviceToDevice, stream);
      dim3 g(L_ / 64, D_ / 64, 1);
      out_gemm_kernel<<<g, blk, 0, stream>>>(bounce_buf, Wo, bo, out + (size_t)b * L_ * D_);
    }
  }
  (void)in_sizes; (void)n_in; (void)out_size;
}

// Round 3
// 3778.330 us; speedup vs baseline: 1.5542x; 1.5542x over previous
//
#include <hip/hip_runtime.h>
#include <hip/hip_bf16.h>
#include <math.h>

#define B_ 16
#define L_ 3072
#define D_ 512
#define CH_ (B_ * D_)   // 8192 channels
#define TOPK_ 40
#define NCAND_ 64       // candidate slots per channel
#define RFN_ 24         // candidates refined exactly in f64

typedef unsigned short ushort_t;
typedef unsigned int uint_t;
typedef __attribute__((ext_vector_type(8))) short bh8;   // 8 bf16 (4 VGPRs)
typedef __attribute__((ext_vector_type(4))) float f4;    // 4 f32 acc
typedef __attribute__((ext_vector_type(4))) int i4;      // 16B vector

// ---------------------------------------------------------------------------
// Projection GEMM: P[c][t] = sum_j X[b][t][j] * W[i][j] + bias[i].
// AccT=double for Q/K (selection-critical), float for V. grid (L/64,D/64,nb).
// ---------------------------------------------------------------------------
template <typename AccT>
__global__ __launch_bounds__(256) void proj_kernel(const float* __restrict__ X,
                                                   const float* __restrict__ W,
                                                   const float* __restrict__ bias,
                                                   AccT* __restrict__ P) {
  __shared__ float Xs[64][65];
  __shared__ float Ws[64][65];
  const int t0 = blockIdx.x * 64;
  const int i0 = blockIdx.y * 64;
  const int b  = blockIdx.z;
  const int tid = threadIdx.x;
  const int tx = tid & 15, ty = tid >> 4;

  AccT acc[4][4];
#pragma unroll
  for (int r = 0; r < 4; ++r)
#pragma unroll
    for (int s = 0; s < 4; ++s) acc[r][s] = (AccT)0;

  for (int j0 = 0; j0 < D_; j0 += 64) {
#pragma unroll
    for (int p = 0; p < 4; ++p) {
      int flat = p * 256 + tid;
      int row = flat >> 4, c4 = (flat & 15) << 2;
      float4 xv = *(const float4*)(X + ((size_t)b * L_ + t0 + row) * D_ + j0 + c4);
      Xs[row][c4 + 0] = xv.x; Xs[row][c4 + 1] = xv.y;
      Xs[row][c4 + 2] = xv.z; Xs[row][c4 + 3] = xv.w;
      float4 wv = *(const float4*)(W + (size_t)(i0 + row) * D_ + j0 + c4);
      Ws[row][c4 + 0] = wv.x; Ws[row][c4 + 1] = wv.y;
      Ws[row][c4 + 2] = wv.z; Ws[row][c4 + 3] = wv.w;
    }
    __syncthreads();
#pragma unroll 4
    for (int kk = 0; kk < 64; ++kk) {
      float a[4], w4[4];
#pragma unroll
      for (int r = 0; r < 4; ++r) a[r] = Xs[4 * ty + r][kk];
#pragma unroll
      for (int s = 0; s < 4; ++s) w4[s] = Ws[4 * tx + s][kk];
#pragma unroll
      for (int r = 0; r < 4; ++r)
#pragma unroll
        for (int s = 0; s < 4; ++s)
          acc[r][s] += (AccT)a[r] * (AccT)w4[s];
    }
    __syncthreads();
  }
#pragma unroll
  for (int s = 0; s < 4; ++s) {
    int i = i0 + 4 * tx + s;
    AccT bia = (AccT)bias[i];
#pragma unroll
    for (int r = 0; r < 4; ++r) {
      int t = t0 + 4 * ty + r;
      P[(size_t)(b * D_ + i) * L_ + t] = acc[r][s] + bia;
    }
  }
}

__device__ __forceinline__ ushort_t f64_to_bf16(double d) {
  float f = (float)d;
  uint_t b = __builtin_bit_cast(uint_t, f);
  uint_t r = (b + 0x7FFFu + ((b >> 16) & 1u)) >> 16;
  return (ushort_t)r;
}

// ---------------------------------------------------------------------------
// MFMA autocorrelation candidate kernel. One block (4 waves) per channel.
// tau = f + 16 i + 256 j  (f in [0,16): wave fg owns f = 4*fg + e, e in [0,4);
// i = MFMA A-row, j = MFMA B-col, j < 12).
// D_f[i][j] = sum_u q[(u + f + 16 i) mod L] * k[(u - 256 j) mod L].
// A-frag: lane: row = l&15, k = 8*(l>>4)+jr -> 2 aligned b128 + funnel shifts
// (window shared across the wave's 4 f-values). B-frag: aligned b128, shared
// across f; cols j>=12 read a zero slot. After K-loop: ac -> LDS (permuted
// p = j + 12*(f+16i)), then bisection threshold -> 44..64 candidates/channel.
// ---------------------------------------------------------------------------
template <int P>
__device__ __forceinline__ void ac_kloop(const ushort_t* q_s, const ushort_t* k_s,
                                         int abase, int bstat, int jvalid,
                                         f4 acc[4]) {
  for (int t0 = 0; t0 < L_; t0 += 32) {
    i4 w0 = *(const i4*)&q_s[abase + t0];
    i4 w1 = *(const i4*)&q_s[abase + t0 + 8];
    uint_t w[8] = { (uint_t)w0.x, (uint_t)w0.y, (uint_t)w0.z, (uint_t)w0.w,
                    (uint_t)w1.x, (uint_t)w1.y, (uint_t)w1.z, (uint_t)w1.w };
    int koff = jvalid ? (bstat + t0) : 5888;
    bh8 Bf = *(const bh8*)&k_s[koff];
#pragma unroll
    for (int e = 0; e < 4; ++e) {
      const int ro = (e >> 1) + 2 * P;
      const int sh = (e & 1) * 16;
      uint_t a0 = (uint_t)((((unsigned long long)w[ro + 1] << 32) | w[ro + 0]) >> sh);
      uint_t a1 = (uint_t)((((unsigned long long)w[ro + 2] << 32) | w[ro + 1]) >> sh);
      uint_t a2 = (uint_t)((((unsigned long long)w[ro + 3] << 32) | w[ro + 2]) >> sh);
      uint_t a3 = (uint_t)((((unsigned long long)w[ro + 4] << 32) | w[ro + 3]) >> sh);
      i4 ai = { (int)a0, (int)a1, (int)a2, (int)a3 };
      bh8 Af = __builtin_bit_cast(bh8, ai);
      acc[e] = __builtin_amdgcn_mfma_f32_16x16x32_bf16(Af, Bf, acc[e], 0, 0, 0);
    }
  }
}

__global__ __launch_bounds__(256) void mfma_cand_kernel(const double* __restrict__ Q,
                                                        const double* __restrict__ K,
                                                        float* __restrict__ cand_val,
                                                        int* __restrict__ cand_idx,
                                                        int* __restrict__ cand_cnt) {
  __shared__ ushort_t q_s[3456];       // q[x mod L], x in [0,3456)
  __shared__ ushort_t k_s[5896];       // k[(x-2816) mod L] + 8-elem zero slot
  __shared__ float ac_s[L_];
  __shared__ float redf[8];
  __shared__ int   redi[4];
  __shared__ int   cnt_s;
  const int c = blockIdx.x;
  const int tid = threadIdx.x;
  const double* Qp = Q + (size_t)c * L_;
  const double* Kp = K + (size_t)c * L_;

  for (int x8 = tid; x8 < 432; x8 += 256) {
    int x = x8 * 8; int src = x - (x >= L_ ? L_ : 0);
    ushort_t t[8];
#pragma unroll
    for (int u = 0; u < 8; ++u) t[u] = f64_to_bf16(Qp[src + u]);
    i4 pk = { (int)((uint_t)t[0] | ((uint_t)t[1] << 16)),
              (int)((uint_t)t[2] | ((uint_t)t[3] << 16)),
              (int)((uint_t)t[4] | ((uint_t)t[5] << 16)),
              (int)((uint_t)t[6] | ((uint_t)t[7] << 16)) };
    *(i4*)&q_s[x] = pk;
  }
  for (int x8 = tid; x8 < 736; x8 += 256) {
    int x = x8 * 8; int src = x - 2816 + (x < 2816 ? L_ : 0);
    ushort_t t[8];
#pragma unroll
    for (int u = 0; u < 8; ++u) t[u] = f64_to_bf16(Kp[src + u]);
    i4 pk = { (int)((uint_t)t[0] | ((uint_t)t[1] << 16)),
              (int)((uint_t)t[2] | ((uint_t)t[3] << 16)),
              (int)((uint_t)t[4] | ((uint_t)t[5] << 16)),
              (int)((uint_t)t[6] | ((uint_t)t[7] << 16)) };
    *(i4*)&k_s[x] = pk;
  }
  if (tid < 8) k_s[5888 + tid] = 0;
  __syncthreads();

  const int lane = tid & 63, fg = tid >> 6;
  const int lg = lane >> 4, lj = lane & 15;
  const int abase = 8 * lg + 16 * lj + 8 * (fg >> 1);
  const int jvalid = (lj < 12) ? 1 : 0;
  const int bstat = 2816 + 8 * lg - 256 * lj;

  f4 acc[4];
#pragma unroll
  for (int e = 0; e < 4; ++e) acc[e] = (f4){0.f, 0.f, 0.f, 0.f};

  if (fg & 1) ac_kloop<1>(q_s, k_s, abase, bstat, jvalid, acc);
  else        ac_kloop<0>(q_s, k_s, abase, bstat, jvalid, acc);

  if (jvalid) {
#pragma unroll
    for (int e = 0; e < 4; ++e) {
      int f = 4 * fg + e;
#pragma unroll
      for (int r = 0; r < 4; ++r) {
        int g = f + 16 * (4 * lg + r);      // fine lag in [0,256)
        ac_s[lj + 12 * g] = acc[e][r];      // tau = g + 256*lj
      }
    }
  }
  __syncthreads();

  // registers: 12 values per thread
  float v[12];
#pragma unroll
  for (int it = 0; it < 12; ++it) v[it] = ac_s[tid + 256 * it];

  // block max
  float lm = v[0];
#pragma unroll
  for (int it = 1; it < 12; ++it) lm = fmaxf(lm, v[it]);
  for (int o = 32; o; o >>= 1) lm = fmaxf(lm, __shfl_down(lm, o));
  if ((tid & 63) == 0) redf[tid >> 6] = lm;
  __syncthreads();
  if (tid == 0) redf[4] = fmaxf(fmaxf(redf[0], redf[1]), fmaxf(redf[2], redf[3]));
  __syncthreads();
  const float Tmax = redf[4];

  // block count( > T )
  auto bcount = [&](float T) -> int {
    int lc = 0;
#pragma unroll
    for (int it = 0; it < 12; ++it) lc += (v[it] > T) ? 1 : 0;
    for (int o = 32; o; o >>= 1) lc += __shfl_down(lc, o);
    __syncthreads();
    if ((tid & 63) == 0) redi[tid >> 6] = lc;
    __syncthreads();
    return redi[0] + redi[1] + redi[2] + redi[3];
  };

  float lo = Tmax - 128.0f;
  int cl = bcount(lo);
  for (int wd = 1; wd <= 5 && cl < 44; ++wd) { lo = Tmax - 128.0f * (float)(1 << wd); cl = bcount(lo); }
  float hi = Tmax, T = lo;
  int cT = cl;
  for (int i = 0; i < 26 && cT > NCAND_; ++i) {
    float mid = 0.5f * (lo + hi);
    int cm = bcount(mid);
    if (cm >= 44) { lo = mid; T = mid; cT = cm; } else hi = mid;
  }

  if (tid == 0) cnt_s = 0;
  __syncthreads();
#pragma unroll
  for (int it = 0; it < 12; ++it) {
    if (v[it] > T) {
      int pos = atomicAdd(&cnt_s, 1);
      if (pos < NCAND_) {
        int m = tid + 256 * it;
        int g = m / 12, j = m - 12 * g;
        cand_val[(size_t)c * NCAND_ + pos] = v[it];
        cand_idx[(size_t)c * NCAND_ + pos] = g + 256 * j;
      }
    }
  }
  __syncthreads();
  if (tid == 0) cand_cnt[c] = cnt_s < NCAND_ ? cnt_s : NCAND_;
}

// ---------------------------------------------------------------------------
// Exact f64 refinement + final top-40. One block per channel.
// Top-RFN_ candidates (by f32 val) recomputed exactly in f64 and sorted ->
// ranks 0..RFN_-1 match the f64 reference exactly (all softmax-significant
// ranks). Remaining ranks filled by f32 order (weights < e^-40).
// ---------------------------------------------------------------------------
__global__ __launch_bounds__(256) void refine_topk_kernel(const double* __restrict__ Q,
                                                          const double* __restrict__ K,
                                                          const float* __restrict__ cand_val,
                                                          const int* __restrict__ cand_idx,
                                                          const int* __restrict__ cand_cnt,
                                                          double* __restrict__ top_vals,
                                                          int* __restrict__ top_idx,
                                                          int c0) {
  __shared__ double q_s[L_];
  __shared__ double k_s[L_];
  __shared__ float cv[NCAND_];
  __shared__ int   ci[NCAND_];
  __shared__ int   used[NCAND_];
  __shared__ double refv[RFN_];
  __shared__ int    refi[RFN_];
  __shared__ int    used2[RFN_];
  __shared__ float  rf[4];  __shared__ int rif[4]; __shared__ int rpf[4];
  __shared__ double rd[4];  __shared__ int rid[4]; __shared__ int rpd[4];
  const int c = blockIdx.x, tid = threadIdx.x;

  for (int i = tid; i < L_; i += 256) {
    q_s[i] = Q[(size_t)c * L_ + i];
    k_s[i] = K[(size_t)c * L_ + i];
  }
  const int cnt = cand_cnt[c];
  if (tid < NCAND_) {
    used[tid] = 0; cv[tid] = -1e30f; ci[tid] = 1 << 30;
    if (tid < cnt) {
      cv[tid] = cand_val[(size_t)c * NCAND_ + tid];
      ci[tid] = cand_idx[(size_t)c * NCAND_ + tid];
    }
  }
  if (tid < RFN_) used2[tid] = 0;
  __syncthreads();

  const int R = cnt < RFN_ ? cnt : RFN_;

  // --- select top-R by (f32 val desc, idx asc) ---
  for (int r = 0; r < R; ++r) {
    float bv = -1e30f; int bi = 1 << 30; int bp = -1;
    if (tid < cnt && !used[tid]) { bv = cv[tid]; bi = ci[tid]; bp = tid; }
    for (int o = 32; o; o >>= 1) {
      float ov = __shfl_down(bv, o); int oi = __shfl_down(bi, o); int op = __shfl_down(bp, o);
      if (ov > bv || (ov == bv && oi < bi)) { bv = ov; bi = oi; bp = op; }
    }
    if ((tid & 63) == 0) { rf[tid >> 6] = bv; rif[tid >> 6] = bi; rpf[tid >> 6] = bp; }
    __syncthreads();
    if (tid == 0) {
      for (int u = 1; u < 4; ++u)
        if (rf[u] > bv || (rf[u] == bv && rif[u] < bi)) { bv = rf[u]; bi = rif[u]; bp = rpf[u]; }
      refi[r] = bi;
      if (bp >= 0) used[bp] = 1;
    }
    __syncthreads();
  }

  // --- exact f64 ac for refined candidates: 8 threads per candidate ---
  {
    const int r8 = tid >> 3, sub = tid & 7;
    if (r8 < R) {
      const int tau = refi[r8];
      double a = 0.0;
#pragma unroll 4
      for (int u = 0; u < 384; ++u) {
        int t = sub + 8 * u;
        int qi = t + tau; qi -= (qi >= L_) ? L_ : 0;
        a = fma(q_s[qi], k_s[t], a);
      }
      a += __shfl_down(a, 4, 8);
      a += __shfl_down(a, 2, 8);
      a += __shfl_down(a, 1, 8);
      if (sub == 0) refv[r8] = a;
    }
  }
  __syncthreads();

  double* out_v = top_vals + (size_t)(c0 + c) * TOPK_;
  int*    out_i = top_idx  + (size_t)(c0 + c) * TOPK_;

  // --- ranks 0..R-1: exact f64 order among refined ---
  for (int r = 0; r < R; ++r) {
    double bv = -1e300; int bi = 1 << 30; int bp = -1;
    if (tid < R && !used2[tid]) { bv = refv[tid]; bi = refi[tid]; bp = tid; }
    for (int o = 32; o; o >>= 1) {
      double ov = __shfl_down(bv, o); int oi = __shfl_down(bi, o); int op = __shfl_down(bp, o);
      if (ov > bv || (ov == bv && oi < bi)) { bv = ov; bi = oi; bp = op; }
    }
    if ((tid & 63) == 0) { rd[tid >> 6] = bv; rid[tid >> 6] = bi; rpd[tid >> 6] = bp; }
    __syncthreads();
    if (tid == 0) {
      for (int u = 1; u < 4; ++u)
        if (rd[u] > bv || (rd[u] == bv && rid[u] < bi)) { bv = rd[u]; bi = rid[u]; bp = rpd[u]; }
      out_v[r] = bv; out_i[r] = (bp >= 0 && bi < L_) ? bi : 0;
      if (bp >= 0) used2[bp] = 1;
    }
    __syncthreads();
  }

  // --- ranks R..39: remaining candidates by f32 order ---
  for (int r = R; r < TOPK_; ++r) {
    float bv = -1e30f; int bi = 1 << 30; int bp = -1;
    if (tid < cnt && !used[tid]) { bv = cv[tid]; bi = ci[tid]; bp = tid; }
    for (int o = 32; o; o >>= 1) {
      float ov = __shfl_down(bv, o); int oi = __shfl_down(bi, o); int op = __shfl_down(bp, o);
      if (ov > bv || (ov == bv && oi < bi)) { bv = ov; bi = oi; bp = op; }
    }
    if ((tid & 63) == 0) { rf[tid >> 6] = bv; rif[tid >> 6] = bi; rpf[tid >> 6] = bp; }
    __syncthreads();
    if (tid == 0) {
      for (int u = 1; u < 4; ++u)
        if (rf[u] > bv || (rf[u] == bv && rif[u] < bi)) { bv = rf[u]; bi = rif[u]; bp = rpf[u]; }
      out_v[r] = (bp >= 0) ? (double)bv : -1e300;
      out_i[r] = (bp >= 0 && bi < L_) ? bi : 0;
      if (bp >= 0) used[bp] = 1;
    }
    __syncthreads();
  }
}

// ---------------------------------------------------------------------------
__global__ __launch_bounds__(256) void shifts_kernel(const int* __restrict__ top_idx,
                                                     int* __restrict__ shifts) {
  const int k = blockIdx.x;
  __shared__ double sred[256];
  double s = 0.0;
  for (int c = threadIdx.x; c < CH_; c += 256) s += (double)top_idx[(size_t)c * TOPK_ + k];
  sred[threadIdx.x] = s;
  __syncthreads();
  for (int o = 128; o > 0; o >>= 1) {
    if (threadIdx.x < o) sred[threadIdx.x] += sred[threadIdx.x + o];
    __syncthreads();
  }
  if (threadIdx.x == 0) shifts[k] = (int)((float)(sred[0] / (double)CH_));
}

__global__ __launch_bounds__(256) void softmax_kernel(const double* __restrict__ top_vals,
                                                      float* __restrict__ weights) {
  const int c = blockIdx.x * 256 + threadIdx.x;
  const double* v = top_vals + (size_t)c * TOPK_;
  double m = v[0];
  for (int k = 1; k < TOPK_; ++k) m = fmax(m, v[k]);
  double sum = 0.0;
  for (int k = 0; k < TOPK_; ++k) sum += exp(v[k] - m);
  double inv = 1.0 / sum;
  for (int k = 0; k < TOPK_; ++k)
    weights[(size_t)c * TOPK_ + k] = (float)(exp(v[k] - m) * inv);
}

__global__ __launch_bounds__(256) void agg_kernel(float* __restrict__ Vc,
                                                  const float* __restrict__ weights,
                                                  const int* __restrict__ shifts) {
  const int c = blockIdx.x;
  __shared__ float v_s[L_];
  __shared__ float w_s[TOPK_];
  __shared__ int   s_s[TOPK_];
  for (int i = threadIdx.x; i < L_; i += 256) v_s[i] = Vc[(size_t)c * L_ + i];
  if (threadIdx.x < TOPK_) {
    w_s[threadIdx.x] = weights[(size_t)c * TOPK_ + threadIdx.x];
    s_s[threadIdx.x] = shifts[threadIdx.x];
  }
  __syncthreads();
  for (int t = threadIdx.x; t < L_; t += 256) {
    float sum = 0.0f;
#pragma unroll
    for (int k = 0; k < TOPK_; ++k) {
      int idx = t + s_s[k];
      if (idx >= L_) idx -= L_;
      sum = fmaf(w_s[k], v_s[idx], sum);
    }
    Vc[(size_t)c * L_ + t] = sum;
  }
}

__global__ __launch_bounds__(256) void out_gemm_kernel(const float* __restrict__ agg,
                                                       const float* __restrict__ Wo,
                                                       const float* __restrict__ bo,
                                                       float* __restrict__ out) {
  __shared__ float As[64][65];
  __shared__ float Bs[64][65];
  const int t0 = blockIdx.x * 64;
  const int i0 = blockIdx.y * 64;
  const int b  = blockIdx.z;
  const int tid = threadIdx.x;
  const int tx = tid & 15, ty = tid >> 4;

  float acc[4][4];
#pragma unroll
  for (int r = 0; r < 4; ++r)
#pragma unroll
    for (int s = 0; s < 4; ++s) acc[r][s] = 0.0f;

  for (int j0 = 0; j0 < D_; j0 += 64) {
#pragma unroll
    for (int p = 0; p < 4; ++p) {
      int flat = p * 256 + tid;
      int row = flat >> 4, c4 = (flat & 15) << 2;
      float4 av = *(const float4*)(agg + (size_t)(b * D_ + j0 + row) * L_ + t0 + c4);
      As[row][c4 + 0] = av.x; As[row][c4 + 1] = av.y;
      As[row][c4 + 2] = av.z; As[row][c4 + 3] = av.w;
      float4 wv = *(const float4*)(Wo + (size_t)(i0 + row) * D_ + j0 + c4);
      Bs[row][c4 + 0] = wv.x; Bs[row][c4 + 1] = wv.y;
      Bs[row][c4 + 2] = wv.z; Bs[row][c4 + 3] = wv.w;
    }
    __syncthreads();
#pragma unroll 4
    for (int kk = 0; kk < 64; ++kk) {
      float a[4], w4[4];
#pragma unroll
      for (int r = 0; r < 4; ++r) a[r] = As[kk][4 * ty + r];
#pragma unroll
      for (int s = 0; s < 4; ++s) w4[s] = Bs[4 * tx + s][kk];
#pragma unroll
      for (int r = 0; r < 4; ++r)
#pragma unroll
        for (int s = 0; s < 4; ++s)
          acc[r][s] += a[r] * w4[s];
    }
    __syncthreads();
  }
#pragma unroll
  for (int r = 0; r < 4; ++r) {
    int t = t0 + 4 * ty + r;
#pragma unroll
    for (int s = 0; s < 4; ++s) {
      int i = i0 + 4 * tx + s;
      out[((size_t)b * L_ + t) * D_ + i] = acc[r][s] + bo[i];
    }
  }
}

// ---------------------------------------------------------------------------
extern "C" void kernel_launch(void* const* d_in, const int* in_sizes, int n_in,
                              void* d_out, int out_size, void* d_ws, size_t ws_size,
                              hipStream_t stream) {
  const float* query = (const float*)d_in[0];
  const float* key   = (const float*)d_in[1];
  const float* value = (const float*)d_in[2];
  const float* Wq = (const float*)d_in[3];
  const float* bq = (const float*)d_in[4];
  const float* Wk = (const float*)d_in[5];
  const float* bk = (const float*)d_in[6];
  const float* Wv = (const float*)d_in[7];
  const float* bvp = (const float*)d_in[8];
  const float* Wo = (const float*)d_in[9];
  const float* bo = (const float*)d_in[10];
  float* out = (float*)d_out;
  char* ws = (char*)d_ws;

  auto al = [](size_t x) { return (x + 255) & ~(size_t)255; };
  size_t off = 0;
  const size_t tv_off = off; off = al(off + (size_t)CH_ * TOPK_ * 8);
  const size_t ti_off = off; off = al(off + (size_t)CH_ * TOPK_ * 4);
  const size_t w_off  = off; off = al(off + (size_t)CH_ * TOPK_ * 4);
  const size_t sh_off = off; off = al(off + (size_t)TOPK_ * 4);
  const size_t small_end = off;                       // ~5.3 MB

  // per-batch chunk bytes: Qc + Kc (f64) + cand arrays
  const size_t QK1   = (size_t)D_ * L_ * 8;           // 12.6 MB
  const size_t CV1   = (size_t)D_ * NCAND_ * 4;       // 128 KB
  const size_t CN1   = (size_t)D_ * 4;                // 2 KB
  const size_t PBQK  = al(2 * QK1) + al(CV1) + al(CV1) + al(CN1);  // ~25.5 MB
  const size_t AGG_BYTES    = (size_t)CH_ * L_ * 4;   // 96 MB
  const size_t BOUNCE_BYTES = (size_t)D_ * L_ * 4;    // 6 MB

  int nb; bool bounce;
  if (ws_size >= small_end + AGG_BYTES + PBQK) {
    bounce = false;
    size_t n = (ws_size - small_end - AGG_BYTES) / PBQK;
    nb = (int)(n > 16 ? 16 : n);
  } else {
    bounce = true;
    size_t rem = (ws_size > small_end + BOUNCE_BYTES) ? (ws_size - small_end - BOUNCE_BYTES) : 0;
    size_t n = rem / PBQK; nb = (int)(n > 16 ? 16 : n);
    if (nb < 1) nb = 1;
  }

  double* top_vals = (double*)(ws + tv_off);
  int*    top_idx  = (int*)(ws + ti_off);
  float*  weights  = (float*)(ws + w_off);
  int*    shifts   = (int*)(ws + sh_off);

  float* VcAgg;
  float* bounce_buf = nullptr;
  size_t qk_off;
  if (!bounce) {
    VcAgg = (float*)(ws + small_end);
    qk_off = small_end + al(AGG_BYTES);
  } else {
    bounce_buf = (float*)(ws + small_end);
    qk_off = small_end + al(BOUNCE_BYTES);
    VcAgg = (float*)d_out;
  }
  double* Qc = (double*)(ws + qk_off);
  double* Kc = (double*)(ws + qk_off + al((size_t)nb * QK1));
  size_t cbase = qk_off + 2 * al((size_t)nb * QK1);
  float* cval = (float*)(ws + cbase);
  int*   cidx = (int*)(ws + cbase + al((size_t)nb * CV1));
  int*   ccnt = (int*)(ws + cbase + 2 * al((size_t)nb * CV1));

  dim3 blk(256);
  for (int b0 = 0; b0 < B_; b0 += nb) {
    int nbb = (B_ - b0 < nb) ? (B_ - b0) : nb;
    dim3 g(L_ / 64, D_ / 64, nbb);
    proj_kernel<double><<<g, blk, 0, stream>>>(query + (size_t)b0 * L_ * D_, Wq, bq, Qc);
    proj_kernel<double><<<g, blk, 0, stream>>>(key   + (size_t)b0 * L_ * D_, Wk, bk, Kc);
    mfma_cand_kernel<<<nbb * D_, blk, 0, stream>>>(Qc, Kc, cval, cidx, ccnt);
    refine_topk_kernel<<<nbb * D_, blk, 0, stream>>>(Qc, Kc, cval, cidx, ccnt,
                                                     top_vals, top_idx, b0 * D_);
  }
  shifts_kernel<<<TOPK_, blk, 0, stream>>>(top_idx, shifts);
  softmax_kernel<<<CH_ / 256, blk, 0, stream>>>(top_vals, weights);

  {
    dim3 g(L_ / 64, D_ / 64, B_);
    proj_kernel<float><<<g, blk, 0, stream>>>(value, Wv, bvp, VcAgg);
  }
  agg_kernel<<<CH_, blk, 0, stream>>>(VcAgg, weights, shifts);

  if (!bounce) {
    dim3 g(L_ / 64, D_ / 64, B_);
    out_gemm_kernel<<<g, blk, 0, stream>>>(VcAgg, Wo, bo, out);
  } else {
    for (int b = 0; b < B_; ++b) {
      hipMemcpyAsync(bounce_buf, VcAgg + (size_t)b * D_ * L_, BOUNCE_BYTES,
                     hipMemcpyDeviceToDevice, stream);
      dim3 g(L_ / 64, D_ / 64, 1);
      out_gemm_kernel<<<g, blk, 0, stream>>>(bounce_buf, Wo, bo, out + (size_t)b * L_ * D_);
    }
  }
  (void)in_sizes; (void)n_in; (void)out_size;
}

// Round 4
// 2835.738 us; speedup vs baseline: 2.0708x; 1.3324x over previous
//
#include <hip/hip_runtime.h>
#include <hip/hip_bf16.h>
#include <math.h>

#define B_ 16
#define L_ 3072
#define D_ 512
#define CH_ (B_ * D_)   // 8192 channels
#define TOPK_ 40
#define NCAND_ 64       // candidate slots per channel
#define RFN_ 24         // candidates refined exactly in f64

typedef unsigned short ushort_t;
typedef unsigned int uint_t;
typedef __attribute__((ext_vector_type(8))) short bh8;   // 8 bf16 (4 VGPRs)
typedef __attribute__((ext_vector_type(4))) float f4;    // 4 f32 acc
typedef __attribute__((ext_vector_type(4))) int i4;      // 16B vector

// ---------------------------------------------------------------------------
// Projection GEMM: P[c][t] = sum_j X[b][t][j] * W[i][j] + bias[i].
// f32 accumulate (error 3e-6 per element << selection gaps; see notes).
// grid (L/64, D/64, nb), block 256. Output channel-major [nb*512][L_].
// ---------------------------------------------------------------------------
__global__ __launch_bounds__(256) void proj_kernel(const float* __restrict__ X,
                                                   const float* __restrict__ W,
                                                   const float* __restrict__ bias,
                                                   float* __restrict__ P) {
  __shared__ float Xs[64][65];
  __shared__ float Ws[64][65];
  const int t0 = blockIdx.x * 64;
  const int i0 = blockIdx.y * 64;
  const int b  = blockIdx.z;
  const int tid = threadIdx.x;
  const int tx = tid & 15, ty = tid >> 4;

  float acc[4][4];
#pragma unroll
  for (int r = 0; r < 4; ++r)
#pragma unroll
    for (int s = 0; s < 4; ++s) acc[r][s] = 0.0f;

  for (int j0 = 0; j0 < D_; j0 += 64) {
#pragma unroll
    for (int p = 0; p < 4; ++p) {
      int flat = p * 256 + tid;
      int row = flat >> 4, c4 = (flat & 15) << 2;
      float4 xv = *(const float4*)(X + ((size_t)b * L_ + t0 + row) * D_ + j0 + c4);
      Xs[row][c4 + 0] = xv.x; Xs[row][c4 + 1] = xv.y;
      Xs[row][c4 + 2] = xv.z; Xs[row][c4 + 3] = xv.w;
      float4 wv = *(const float4*)(W + (size_t)(i0 + row) * D_ + j0 + c4);
      Ws[row][c4 + 0] = wv.x; Ws[row][c4 + 1] = wv.y;
      Ws[row][c4 + 2] = wv.z; Ws[row][c4 + 3] = wv.w;
    }
    __syncthreads();
#pragma unroll 4
    for (int kk = 0; kk < 64; ++kk) {
      float a[4], w4[4];
#pragma unroll
      for (int r = 0; r < 4; ++r) a[r] = Xs[4 * ty + r][kk];
#pragma unroll
      for (int s = 0; s < 4; ++s) w4[s] = Ws[4 * tx + s][kk];
#pragma unroll
      for (int r = 0; r < 4; ++r)
#pragma unroll
        for (int s = 0; s < 4; ++s)
          acc[r][s] = fmaf(a[r], w4[s], acc[r][s]);
    }
    __syncthreads();
  }
#pragma unroll
  for (int s = 0; s < 4; ++s) {
    int i = i0 + 4 * tx + s;
    float bia = bias[i];
#pragma unroll
    for (int r = 0; r < 4; ++r) {
      int t = t0 + 4 * ty + r;
      P[(size_t)(b * D_ + i) * L_ + t] = acc[r][s] + bia;
    }
  }
}

__device__ __forceinline__ ushort_t f32_to_bf16(float f) {
  uint_t b = __builtin_bit_cast(uint_t, f);
  uint_t r = (b + 0x7FFFu + ((b >> 16) & 1u)) >> 16;
  return (ushort_t)r;
}

// ---------------------------------------------------------------------------
// FUSED MFMA autocorrelation + candidate selection + f64 refinement + top-40.
// One block (4 waves) per channel.
// tau = f + 16 i + 256 j  (f in [0,16): wave fg owns f = 4*fg + e, e in [0,4);
// i = MFMA A-row, j = MFMA B-col, j < 12).
// D_f[i][j] = sum_u q[(u + f + 16 i) mod L] * k[(u - 256 j) mod L].
// Phase A: bf16-MFMA ac for all 3072 lags -> LDS; bisection threshold ->
//          44..64 candidates (guaranteed superset of true top-40: bf16 noise
//          sigma~0.09 << rank-40 order-stat margin).
// Phase B: wave 0 extracts top-40 in f32 order (no __syncthreads in loop).
// Phase C: top-24 recomputed exactly in f64 from global f32 Q/K (L1/L2-hot).
// Phase D: wave 0 sorts refined in f64 -> ranks 0..23 exact; 24..39 f32 order
//          (proven irrelevant: weights < e^-20, round-3 A/B identical absmax).
// ---------------------------------------------------------------------------
template <int P>
__device__ __forceinline__ void ac_kloop(const ushort_t* q_s, const ushort_t* k_s,
                                         int abase, int bstat, int jvalid,
                                         f4 acc[4]) {
  for (int t0 = 0; t0 < L_; t0 += 32) {
    i4 w0 = *(const i4*)&q_s[abase + t0];
    i4 w1 = *(const i4*)&q_s[abase + t0 + 8];
    uint_t w[8] = { (uint_t)w0.x, (uint_t)w0.y, (uint_t)w0.z, (uint_t)w0.w,
                    (uint_t)w1.x, (uint_t)w1.y, (uint_t)w1.z, (uint_t)w1.w };
    int koff = jvalid ? (bstat + t0) : 5888;
    bh8 Bf = *(const bh8*)&k_s[koff];
#pragma unroll
    for (int e = 0; e < 4; ++e) {
      const int ro = (e >> 1) + 2 * P;
      const int sh = (e & 1) * 16;
      uint_t a0 = (uint_t)((((unsigned long long)w[ro + 1] << 32) | w[ro + 0]) >> sh);
      uint_t a1 = (uint_t)((((unsigned long long)w[ro + 2] << 32) | w[ro + 1]) >> sh);
      uint_t a2 = (uint_t)((((unsigned long long)w[ro + 3] << 32) | w[ro + 2]) >> sh);
      uint_t a3 = (uint_t)((((unsigned long long)w[ro + 4] << 32) | w[ro + 3]) >> sh);
      i4 ai = { (int)a0, (int)a1, (int)a2, (int)a3 };
      bh8 Af = __builtin_bit_cast(bh8, ai);
      acc[e] = __builtin_amdgcn_mfma_f32_16x16x32_bf16(Af, Bf, acc[e], 0, 0, 0);
    }
  }
}

__global__ __launch_bounds__(256) void cand_refine_kernel(const float* __restrict__ Q,
                                                          const float* __restrict__ K,
                                                          double* __restrict__ top_vals,
                                                          int* __restrict__ top_idx,
                                                          int c0) {
  __shared__ ushort_t q_s[3456];       // q[x mod L] bf16
  __shared__ ushort_t k_s[5896];       // k[(x-2816) mod L] bf16 + zero slot
  __shared__ float ac_s[L_];
  __shared__ float redf[8];
  __shared__ int   redi[4];
  __shared__ int   cnt_s;
  __shared__ float cv[NCAND_];
  __shared__ int   ci[NCAND_];
  __shared__ float sv[TOPK_];          // f32-order sorted top-40
  __shared__ int   si[TOPK_];
  __shared__ double refv[RFN_];
  const int c = blockIdx.x;
  const int tid = threadIdx.x;
  const float* Qp = Q + (size_t)c * L_;
  const float* Kp = K + (size_t)c * L_;

  // ---- Phase A: stage bf16 q/k ----
  for (int x8 = tid; x8 < 432; x8 += 256) {
    int x = x8 * 8; int src = x - (x >= L_ ? L_ : 0);
    float4 f0 = *(const float4*)(Qp + src);
    float4 f1 = *(const float4*)(Qp + src + 4);
    i4 pk = { (int)((uint_t)f32_to_bf16(f0.x) | ((uint_t)f32_to_bf16(f0.y) << 16)),
              (int)((uint_t)f32_to_bf16(f0.z) | ((uint_t)f32_to_bf16(f0.w) << 16)),
              (int)((uint_t)f32_to_bf16(f1.x) | ((uint_t)f32_to_bf16(f1.y) << 16)),
              (int)((uint_t)f32_to_bf16(f1.z) | ((uint_t)f32_to_bf16(f1.w) << 16)) };
    *(i4*)&q_s[x] = pk;
  }
  for (int x8 = tid; x8 < 736; x8 += 256) {
    int x = x8 * 8; int src = x - 2816 + (x < 2816 ? L_ : 0);
    float4 f0 = *(const float4*)(Kp + src);
    float4 f1 = *(const float4*)(Kp + src + 4);
    i4 pk = { (int)((uint_t)f32_to_bf16(f0.x) | ((uint_t)f32_to_bf16(f0.y) << 16)),
              (int)((uint_t)f32_to_bf16(f0.z) | ((uint_t)f32_to_bf16(f0.w) << 16)),
              (int)((uint_t)f32_to_bf16(f1.x) | ((uint_t)f32_to_bf16(f1.y) << 16)),
              (int)((uint_t)f32_to_bf16(f1.z) | ((uint_t)f32_to_bf16(f1.w) << 16)) };
    *(i4*)&k_s[x] = pk;
  }
  if (tid < 8) k_s[5888 + tid] = 0;
  __syncthreads();

  const int lane = tid & 63, fg = tid >> 6;
  const int lg = lane >> 4, lj = lane & 15;
  const int abase = 8 * lg + 16 * lj + 8 * (fg >> 1);
  const int jvalid = (lj < 12) ? 1 : 0;
  const int bstat = 2816 + 8 * lg - 256 * lj;

  f4 acc[4];
#pragma unroll
  for (int e = 0; e < 4; ++e) acc[e] = (f4){0.f, 0.f, 0.f, 0.f};

  if (fg & 1) ac_kloop<1>(q_s, k_s, abase, bstat, jvalid, acc);
  else        ac_kloop<0>(q_s, k_s, abase, bstat, jvalid, acc);

  if (jvalid) {
#pragma unroll
    for (int e = 0; e < 4; ++e) {
      int f = 4 * fg + e;
#pragma unroll
      for (int r = 0; r < 4; ++r) {
        int g = f + 16 * (4 * lg + r);      // fine lag in [0,256)
        ac_s[lj + 12 * g] = acc[e][r];      // tau = g + 256*lj
      }
    }
  }
  __syncthreads();

  float v[12];
#pragma unroll
  for (int it = 0; it < 12; ++it) v[it] = ac_s[tid + 256 * it];

  // block max
  float lm = v[0];
#pragma unroll
  for (int it = 1; it < 12; ++it) lm = fmaxf(lm, v[it]);
  for (int o = 32; o; o >>= 1) lm = fmaxf(lm, __shfl_down(lm, o));
  if ((tid & 63) == 0) redf[tid >> 6] = lm;
  __syncthreads();
  if (tid == 0) redf[4] = fmaxf(fmaxf(redf[0], redf[1]), fmaxf(redf[2], redf[3]));
  __syncthreads();
  const float Tmax = redf[4];

  auto bcount = [&](float T) -> int {
    int lc = 0;
#pragma unroll
    for (int it = 0; it < 12; ++it) lc += (v[it] > T) ? 1 : 0;
    for (int o = 32; o; o >>= 1) lc += __shfl_down(lc, o);
    __syncthreads();
    if ((tid & 63) == 0) redi[tid >> 6] = lc;
    __syncthreads();
    return redi[0] + redi[1] + redi[2] + redi[3];
  };

  float lo = Tmax - 128.0f;
  int cl = bcount(lo);
  for (int wd = 1; wd <= 5 && cl < 44; ++wd) { lo = Tmax - 128.0f * (float)(1 << wd); cl = bcount(lo); }
  float hi = Tmax, T = lo;
  int cT = cl;
  for (int i = 0; i < 26 && cT > NCAND_; ++i) {
    float mid = 0.5f * (lo + hi);
    int cm = bcount(mid);
    if (cm >= 44) { lo = mid; T = mid; cT = cm; } else hi = mid;
  }

  if (tid == 0) cnt_s = 0;
  __syncthreads();
#pragma unroll
  for (int it = 0; it < 12; ++it) {
    if (v[it] > T) {
      int pos = atomicAdd(&cnt_s, 1);
      if (pos < NCAND_) {
        int m = tid + 256 * it;
        int g = m / 12, j = m - 12 * g;
        cv[pos] = v[it];
        ci[pos] = g + 256 * j;
      }
    }
  }
  __syncthreads();
  const int cnt = cnt_s < NCAND_ ? cnt_s : NCAND_;

  // ---- Phase B: wave 0 extracts top-40 by (f32 val desc, idx asc) ----
  if (tid < 64) {
    float mv = (tid < cnt) ? cv[tid] : -1e30f;
    int   mi = (tid < cnt) ? ci[tid] : (1 << 30);
    int used = 0;
    for (int r = 0; r < TOPK_; ++r) {
      float bv = used ? -1e30f : mv;
      int   bi = used ? (1 << 30) : mi;
      int   bl = tid;
      for (int o = 32; o; o >>= 1) {
        float ov = __shfl_down(bv, o);
        int   oi = __shfl_down(bi, o);
        int   ol = __shfl_down(bl, o);
        if (ov > bv || (ov == bv && oi < bi)) { bv = ov; bi = oi; bl = ol; }
      }
      bv = __shfl(bv, 0); bi = __shfl(bi, 0); bl = __shfl(bl, 0);
      if (tid == 0) { sv[r] = bv; si[r] = (bi < L_) ? bi : 0; }
      if (tid == bl) used = 1;
    }
  }
  __syncthreads();

  // ---- Phase C: exact f64 ac for top-RFN_ (8 threads per candidate),
  //      reading f32 Q/K from global (L1/L2-hot: just streamed above) ----
  {
    const int r8 = tid >> 3, sub = tid & 7;
    const int R = cnt < RFN_ ? cnt : RFN_;
    if (r8 < R) {
      const int tau = si[r8];
      double a = 0.0;
#pragma unroll 4
      for (int u = 0; u < 384; ++u) {
        int t = sub + 8 * u;
        int qi = t + tau; qi -= (qi >= L_) ? L_ : 0;
        a = fma((double)Qp[qi], (double)Kp[t], a);
      }
      a += __shfl_down(a, 4, 8);
      a += __shfl_down(a, 2, 8);
      a += __shfl_down(a, 1, 8);
      if (sub == 0) refv[r8] = a;
    }
  }
  __syncthreads();

  // ---- Phase D: wave 0 sorts refined (f64) -> ranks 0..R-1; rest f32 order
  double* out_v = top_vals + (size_t)(c0 + c) * TOPK_;
  int*    out_i = top_idx  + (size_t)(c0 + c) * TOPK_;
  if (tid < 64) {
    const int R = cnt < RFN_ ? cnt : RFN_;
    double dv = (tid < R) ? refv[tid] : -1e300;
    int    di = (tid < R) ? si[tid]   : (1 << 30);
    int used = 0;
    for (int r = 0; r < R; ++r) {
      double bv = used ? -1e300 : dv;
      int    bi = used ? (1 << 30) : di;
      int    bl = tid;
      for (int o = 32; o; o >>= 1) {
        double ov = __shfl_down(bv, o);
        int    oi = __shfl_down(bi, o);
        int    ol = __shfl_down(bl, o);
        if (ov > bv || (ov == bv && oi < bi)) { bv = ov; bi = oi; bl = ol; }
      }
      bv = __shfl(bv, 0); bi = __shfl(bi, 0); bl = __shfl(bl, 0);
      if (tid == 0) { out_v[r] = bv; out_i[r] = (bi < L_) ? bi : 0; }
      if (tid == bl) used = 1;
    }
    if (tid >= R && tid < TOPK_) {
      out_v[tid] = (double)sv[tid];
      out_i[tid] = si[tid];
    }
  }
}

// ---------------------------------------------------------------------------
__global__ __launch_bounds__(256) void shifts_kernel(const int* __restrict__ top_idx,
                                                     int* __restrict__ shifts) {
  const int k = blockIdx.x;
  __shared__ double sred[256];
  double s = 0.0;
  for (int c = threadIdx.x; c < CH_; c += 256) s += (double)top_idx[(size_t)c * TOPK_ + k];
  sred[threadIdx.x] = s;
  __syncthreads();
  for (int o = 128; o > 0; o >>= 1) {
    if (threadIdx.x < o) sred[threadIdx.x] += sred[threadIdx.x + o];
    __syncthreads();
  }
  if (threadIdx.x == 0) shifts[k] = (int)((float)(sred[0] / (double)CH_));
}

__global__ __launch_bounds__(256) void softmax_kernel(const double* __restrict__ top_vals,
                                                      float* __restrict__ weights) {
  const int c = blockIdx.x * 256 + threadIdx.x;
  const double* v = top_vals + (size_t)c * TOPK_;
  double m = v[0];
  for (int k = 1; k < TOPK_; ++k) m = fmax(m, v[k]);
  double sum = 0.0;
  for (int k = 0; k < TOPK_; ++k) sum += exp(v[k] - m);
  double inv = 1.0 / sum;
  for (int k = 0; k < TOPK_; ++k)
    weights[(size_t)c * TOPK_ + k] = (float)(exp(v[k] - m) * inv);
}

__global__ __launch_bounds__(256) void agg_kernel(float* __restrict__ Vc,
                                                  const float* __restrict__ weights,
                                                  const int* __restrict__ shifts) {
  const int c = blockIdx.x;
  __shared__ float v_s[L_];
  __shared__ float w_s[TOPK_];
  __shared__ int   s_s[TOPK_];
  for (int i = threadIdx.x; i < L_; i += 256) v_s[i] = Vc[(size_t)c * L_ + i];
  if (threadIdx.x < TOPK_) {
    w_s[threadIdx.x] = weights[(size_t)c * TOPK_ + threadIdx.x];
    s_s[threadIdx.x] = shifts[threadIdx.x];
  }
  __syncthreads();
  for (int t = threadIdx.x; t < L_; t += 256) {
    float sum = 0.0f;
#pragma unroll
    for (int k = 0; k < TOPK_; ++k) {
      int idx = t + s_s[k];
      if (idx >= L_) idx -= L_;
      sum = fmaf(w_s[k], v_s[idx], sum);
    }
    Vc[(size_t)c * L_ + t] = sum;
  }
}

__global__ __launch_bounds__(256) void out_gemm_kernel(const float* __restrict__ agg,
                                                       const float* __restrict__ Wo,
                                                       const float* __restrict__ bo,
                                                       float* __restrict__ out) {
  __shared__ float As[64][65];
  __shared__ float Bs[64][65];
  const int t0 = blockIdx.x * 64;
  const int i0 = blockIdx.y * 64;
  const int b  = blockIdx.z;
  const int tid = threadIdx.x;
  const int tx = tid & 15, ty = tid >> 4;

  float acc[4][4];
#pragma unroll
  for (int r = 0; r < 4; ++r)
#pragma unroll
    for (int s = 0; s < 4; ++s) acc[r][s] = 0.0f;

  for (int j0 = 0; j0 < D_; j0 += 64) {
#pragma unroll
    for (int p = 0; p < 4; ++p) {
      int flat = p * 256 + tid;
      int row = flat >> 4, c4 = (flat & 15) << 2;
      float4 av = *(const float4*)(agg + (size_t)(b * D_ + j0 + row) * L_ + t0 + c4);
      As[row][c4 + 0] = av.x; As[row][c4 + 1] = av.y;
      As[row][c4 + 2] = av.z; As[row][c4 + 3] = av.w;
      float4 wv = *(const float4*)(Wo + (size_t)(i0 + row) * D_ + j0 + c4);
      Bs[row][c4 + 0] = wv.x; Bs[row][c4 + 1] = wv.y;
      Bs[row][c4 + 2] = wv.z; Bs[row][c4 + 3] = wv.w;
    }
    __syncthreads();
#pragma unroll 4
    for (int kk = 0; kk < 64; ++kk) {
      float a[4], w4[4];
#pragma unroll
      for (int r = 0; r < 4; ++r) a[r] = As[kk][4 * ty + r];
#pragma unroll
      for (int s = 0; s < 4; ++s) w4[s] = Bs[4 * tx + s][kk];
#pragma unroll
      for (int r = 0; r < 4; ++r)
#pragma unroll
        for (int s = 0; s < 4; ++s)
          acc[r][s] = fmaf(a[r], w4[s], acc[r][s]);
    }
    __syncthreads();
  }
#pragma unroll
  for (int r = 0; r < 4; ++r) {
    int t = t0 + 4 * ty + r;
#pragma unroll
    for (int s = 0; s < 4; ++s) {
      int i = i0 + 4 * tx + s;
      out[((size_t)b * L_ + t) * D_ + i] = acc[r][s] + bo[i];
    }
  }
}

// ---------------------------------------------------------------------------
extern "C" void kernel_launch(void* const* d_in, const int* in_sizes, int n_in,
                              void* d_out, int out_size, void* d_ws, size_t ws_size,
                              hipStream_t stream) {
  const float* query = (const float*)d_in[0];
  const float* key   = (const float*)d_in[1];
  const float* value = (const float*)d_in[2];
  const float* Wq = (const float*)d_in[3];
  const float* bq = (const float*)d_in[4];
  const float* Wk = (const float*)d_in[5];
  const float* bk = (const float*)d_in[6];
  const float* Wv = (const float*)d_in[7];
  const float* bvp = (const float*)d_in[8];
  const float* Wo = (const float*)d_in[9];
  const float* bo = (const float*)d_in[10];
  float* out = (float*)d_out;
  char* ws = (char*)d_ws;

  auto al = [](size_t x) { return (x + 255) & ~(size_t)255; };
  size_t off = 0;
  const size_t tv_off = off; off = al(off + (size_t)CH_ * TOPK_ * 8);
  const size_t ti_off = off; off = al(off + (size_t)CH_ * TOPK_ * 4);
  const size_t w_off  = off; off = al(off + (size_t)CH_ * TOPK_ * 4);
  const size_t sh_off = off; off = al(off + (size_t)TOPK_ * 4);
  const size_t small_end = off;                       // ~5.3 MB

  const size_t QK1   = (size_t)D_ * L_ * 4;           // 6.29 MB (f32, one batch, one tensor)
  const size_t PBQK  = al(2 * QK1);                   // ~12.6 MB per batch
  const size_t AGG_BYTES    = (size_t)CH_ * L_ * 4;   // 96 MB
  const size_t BOUNCE_BYTES = (size_t)D_ * L_ * 4;    // 6 MB

  int nb; bool bounce;
  if (ws_size >= small_end + AGG_BYTES + PBQK) {
    bounce = false;
    size_t n = (ws_size - small_end - AGG_BYTES) / PBQK;
    nb = (int)(n > 16 ? 16 : n);
  } else {
    bounce = true;
    size_t rem = (ws_size > small_end + BOUNCE_BYTES) ? (ws_size - small_end - BOUNCE_BYTES) : 0;
    size_t n = rem / PBQK; nb = (int)(n > 16 ? 16 : n);
    if (nb < 1) nb = 1;
  }

  double* top_vals = (double*)(ws + tv_off);
  int*    top_idx  = (int*)(ws + ti_off);
  float*  weights  = (float*)(ws + w_off);
  int*    shifts   = (int*)(ws + sh_off);

  float* VcAgg;
  float* bounce_buf = nullptr;
  size_t qk_off;
  if (!bounce) {
    VcAgg = (float*)(ws + small_end);
    qk_off = small_end + al(AGG_BYTES);
  } else {
    bounce_buf = (float*)(ws + small_end);
    qk_off = small_end + al(BOUNCE_BYTES);
    VcAgg = (float*)d_out;
  }
  float* Qc = (float*)(ws + qk_off);
  float* Kc = (float*)(ws + qk_off + al((size_t)nb * QK1));

  dim3 blk(256);
  for (int b0 = 0; b0 < B_; b0 += nb) {
    int nbb = (B_ - b0 < nb) ? (B_ - b0) : nb;
    dim3 g(L_ / 64, D_ / 64, nbb);
    proj_kernel<<<g, blk, 0, stream>>>(query + (size_t)b0 * L_ * D_, Wq, bq, Qc);
    proj_kernel<<<g, blk, 0, stream>>>(key   + (size_t)b0 * L_ * D_, Wk, bk, Kc);
    cand_refine_kernel<<<nbb * D_, blk, 0, stream>>>(Qc, Kc, top_vals, top_idx, b0 * D_);
  }
  shifts_kernel<<<TOPK_, blk, 0, stream>>>(top_idx, shifts);
  softmax_kernel<<<CH_ / 256, blk, 0, stream>>>(top_vals, weights);

  {
    dim3 g(L_ / 64, D_ / 64, B_);
    proj_kernel<<<g, blk, 0, stream>>>(value, Wv, bvp, VcAgg);
  }
  agg_kernel<<<CH_, blk, 0, stream>>>(VcAgg, weights, shifts);

  if (!bounce) {
    dim3 g(L_ / 64, D_ / 64, B_);
    out_gemm_kernel<<<g, blk, 0, stream>>>(VcAgg, Wo, bo, out);
  } else {
    for (int b = 0; b < B_; ++b) {
      hipMemcpyAsync(bounce_buf, VcAgg + (size_t)b * D_ * L_, BOUNCE_BYTES,
                     hipMemcpyDeviceToDevice, stream);
      dim3 g(L_ / 64, D_ / 64, 1);
      out_gemm_kernel<<<g, blk, 0, stream>>>(bounce_buf, Wo, bo, out + (size_t)b * L_ * D_);
    }
  }
  (void)in_sizes; (void)n_in; (void)out_size;
}

// Round 7
// 2101.585 us; speedup vs baseline: 2.7942x; 1.3493x over previous
//
#include <hip/hip_runtime.h>
#include <hip/hip_bf16.h>
#include <math.h>

#define B_ 16
#define L_ 3072
#define D_ 512
#define CH_ (B_ * D_)   // 8192 channels
#define TOPK_ 40
#define NCAND_ 64       // candidate slots per channel (all refined in f64)
#define CFLOOR_ 52      // candidate count floor (12-rank cushion over 40)

typedef unsigned short ushort_t;
typedef unsigned int uint_t;
typedef __attribute__((ext_vector_type(8))) short bh8;   // 8 bf16 (4 VGPRs)
typedef __attribute__((ext_vector_type(4))) float f4;    // 4 f32 acc
typedef __attribute__((ext_vector_type(4))) int i4;      // 16B vector

__device__ __forceinline__ uint_t cvt_pk_bf16(float a, float b) {
  uint_t r;
  asm("v_cvt_pk_bf16_f32 %0, %1, %2" : "=v"(r) : "v"(a), "v"(b));
  return r;  // lo ushort = bf16(a), hi ushort = bf16(b)
}

__device__ __forceinline__ ushort_t f32_to_bf16(float f) {
  uint_t b = __builtin_bit_cast(uint_t, f);
  uint_t r = (b + 0x7FFFu + ((b >> 16) & 1u)) >> 16;
  return (ushort_t)r;
}

// ---------------------------------------------------------------------------
// f32-VALU projection GEMM (SELECTION-CRITICAL path; round-4 proven config).
// P[c][t] = sum_j X[b][t][j] * W[i][j] + bias[i]. grid (L/64, D/64, nb).
// DO NOT alter accumulation order: Qc/Kc bits anchor the passing selection.
// ---------------------------------------------------------------------------
__global__ __launch_bounds__(256) void proj_kernel(const float* __restrict__ X,
                                                   const float* __restrict__ W,
                                                   const float* __restrict__ bias,
                                                   float* __restrict__ P) {
  __shared__ float Xs[64][65];
  __shared__ float Ws[64][65];
  const int t0 = blockIdx.x * 64;
  const int i0 = blockIdx.y * 64;
  const int b  = blockIdx.z;
  const int tid = threadIdx.x;
  const int tx = tid & 15, ty = tid >> 4;

  float acc[4][4];
#pragma unroll
  for (int r = 0; r < 4; ++r)
#pragma unroll
    for (int s = 0; s < 4; ++s) acc[r][s] = 0.0f;

  for (int j0 = 0; j0 < D_; j0 += 64) {
#pragma unroll
    for (int p = 0; p < 4; ++p) {
      int flat = p * 256 + tid;
      int row = flat >> 4, c4 = (flat & 15) << 2;
      float4 xv = *(const float4*)(X + ((size_t)b * L_ + t0 + row) * D_ + j0 + c4);
      Xs[row][c4 + 0] = xv.x; Xs[row][c4 + 1] = xv.y;
      Xs[row][c4 + 2] = xv.z; Xs[row][c4 + 3] = xv.w;
      float4 wv = *(const float4*)(W + (size_t)(i0 + row) * D_ + j0 + c4);
      Ws[row][c4 + 0] = wv.x; Ws[row][c4 + 1] = wv.y;
      Ws[row][c4 + 2] = wv.z; Ws[row][c4 + 3] = wv.w;
    }
    __syncthreads();
#pragma unroll 4
    for (int kk = 0; kk < 64; ++kk) {
      float a[4], w4[4];
#pragma unroll
      for (int r = 0; r < 4; ++r) a[r] = Xs[4 * ty + r][kk];
#pragma unroll
      for (int s = 0; s < 4; ++s) w4[s] = Ws[4 * tx + s][kk];
#pragma unroll
      for (int r = 0; r < 4; ++r)
#pragma unroll
        for (int s = 0; s < 4; ++s)
          acc[r][s] = fmaf(a[r], w4[s], acc[r][s]);
    }
    __syncthreads();
  }
#pragma unroll
  for (int s = 0; s < 4; ++s) {
    int i = i0 + 4 * tx + s;
    float bia = bias[i];
#pragma unroll
    for (int r = 0; r < 4; ++r) {
      int t = t0 + 4 * ty + r;
      P[(size_t)(b * D_ + i) * L_ + t] = acc[r][s] + bia;
    }
  }
}

// ---------------------------------------------------------------------------
// MFMA GEMM, 128x128 tile, 4 waves — LINEAR path only (V proj, out GEMM).
// NPASS=3: split-bf16 (hi/lo) -> ~1e-5 rel accuracy, fine for linear path.
// ATR: A staged transposed from Asrc[k*L_ + m]. BIAS_N: bias indexed by n.
// ---------------------------------------------------------------------------
template <int NPASS, int BK, int ST>
__device__ __forceinline__ void stage_rows(const float* __restrict__ g0,
                                           ushort_t* __restrict__ Hh,
                                           ushort_t* __restrict__ Hl,
                                           int tid) {
  const int row = tid >> 1;
  const int cb = (tid & 1) * (BK / 2);
  const float* g = g0 + (size_t)row * 512 + cb;
  ushort_t* lh = Hh + row * ST + cb;
  ushort_t* ll = Hl + row * ST + cb;
#pragma unroll
  for (int p = 0; p < BK / 8; ++p) {
    float4 v = *(const float4*)(g + 4 * p);
    uint_t h01 = cvt_pk_bf16(v.x, v.y);
    uint_t h23 = cvt_pk_bf16(v.z, v.w);
    *(uint2*)(lh + 4 * p) = make_uint2(h01, h23);
    if (NPASS == 3) {
      float x0 = __builtin_bit_cast(float, h01 << 16);
      float x1 = __builtin_bit_cast(float, h01 & 0xFFFF0000u);
      float x2 = __builtin_bit_cast(float, h23 << 16);
      float x3 = __builtin_bit_cast(float, h23 & 0xFFFF0000u);
      uint_t l01 = cvt_pk_bf16(v.x - x0, v.y - x1);
      uint_t l23 = cvt_pk_bf16(v.z - x2, v.w - x3);
      *(uint2*)(ll + 4 * p) = make_uint2(l01, l23);
    }
  }
}

template <int NPASS, bool ATR, bool BIAS_N>
__global__ __launch_bounds__(256) void gemm_mfma(const float* __restrict__ Ap,
                                                 const float* __restrict__ Bp,
                                                 const float* __restrict__ bias,
                                                 float* __restrict__ Cp,
                                                 long aBS, long bBS, long cBS,
                                                 int cld) {
  constexpr int BK = (NPASS == 3) ? 32 : 64;
  constexpr int ST = (NPASS == 3) ? 40 : 72;  // ushort stride; *2 bytes %16==0
  __shared__ ushort_t Ah[128 * ST];
  __shared__ ushort_t Bh[128 * ST];
  __shared__ ushort_t Al[(NPASS == 3) ? 128 * ST : 8];
  __shared__ ushort_t Bl[(NPASS == 3) ? 128 * ST : 8];

  const float* Asrc = Ap + (size_t)blockIdx.z * aBS;
  const float* Bsrc = Bp + (size_t)blockIdx.z * bBS;
  float* Cb = Cp + (size_t)blockIdx.z * cBS;
  const int n0 = blockIdx.x * 128, m0 = blockIdx.y * 128;
  const int tid = threadIdx.x;
  const int lane = tid & 63, w = tid >> 6;
  const int wr = w >> 1, wc = w & 1;
  const int lj = lane & 15, lg = lane >> 4;

  f4 acc[4][4];
#pragma unroll
  for (int fm = 0; fm < 4; ++fm)
#pragma unroll
    for (int fn = 0; fn < 4; ++fn) acc[fm][fn] = (f4){0.f, 0.f, 0.f, 0.f};

  for (int kc = 0; kc < 512; kc += BK) {
    if (!ATR) {
      stage_rows<NPASS, BK, ST>(Asrc + (size_t)m0 * 512 + kc, Ah, Al, tid);
    } else {
      constexpr int TPC = 256 / BK;   // threads per k-column
      constexpr int TC  = 128 / TPC;  // t's per thread
      const int jl = tid / TPC, ts = tid % TPC;
      const float* g = Asrc + (size_t)(kc + jl) * L_ + m0 + ts * TC;
#pragma unroll
      for (int p = 0; p < TC / 4; ++p) {
        float4 v = *(const float4*)(g + 4 * p);
        uint_t h01 = cvt_pk_bf16(v.x, v.y);
        uint_t h23 = cvt_pk_bf16(v.z, v.w);
        int t = ts * TC + 4 * p;
        Ah[(t + 0) * ST + jl] = (ushort_t)(h01 & 0xFFFFu);
        Ah[(t + 1) * ST + jl] = (ushort_t)(h01 >> 16);
        Ah[(t + 2) * ST + jl] = (ushort_t)(h23 & 0xFFFFu);
        Ah[(t + 3) * ST + jl] = (ushort_t)(h23 >> 16);
        if (NPASS == 3) {
          float x0 = __builtin_bit_cast(float, h01 << 16);
          float x1 = __builtin_bit_cast(float, h01 & 0xFFFF0000u);
          float x2 = __builtin_bit_cast(float, h23 << 16);
          float x3 = __builtin_bit_cast(float, h23 & 0xFFFF0000u);
          uint_t l01 = cvt_pk_bf16(v.x - x0, v.y - x1);
          uint_t l23 = cvt_pk_bf16(v.z - x2, v.w - x3);
          Al[(t + 0) * ST + jl] = (ushort_t)(l01 & 0xFFFFu);
          Al[(t + 1) * ST + jl] = (ushort_t)(l01 >> 16);
          Al[(t + 2) * ST + jl] = (ushort_t)(l23 & 0xFFFFu);
          Al[(t + 3) * ST + jl] = (ushort_t)(l23 >> 16);
        }
      }
    }
    stage_rows<NPASS, BK, ST>(Bsrc + (size_t)n0 * 512 + kc, Bh, Bl, tid);
    __syncthreads();

#pragma unroll
    for (int ks = 0; ks < BK / 32; ++ks) {
      const int kk = ks * 32 + 8 * lg;
      bh8 af[4], bf[4];
#pragma unroll
      for (int f = 0; f < 4; ++f)
        af[f] = *(const bh8*)&Ah[(64 * wr + 16 * f + lj) * ST + kk];
#pragma unroll
      for (int f = 0; f < 4; ++f)
        bf[f] = *(const bh8*)&Bh[(64 * wc + 16 * f + lj) * ST + kk];
#pragma unroll
      for (int fm = 0; fm < 4; ++fm)
#pragma unroll
        for (int fn = 0; fn < 4; ++fn)
          acc[fm][fn] = __builtin_amdgcn_mfma_f32_16x16x32_bf16(af[fm], bf[fn],
                                                                acc[fm][fn], 0, 0, 0);
      if (NPASS == 3) {
        bh8 bl_[4];
#pragma unroll
        for (int f = 0; f < 4; ++f)
          bl_[f] = *(const bh8*)&Bl[(64 * wc + 16 * f + lj) * ST + kk];
#pragma unroll
        for (int fm = 0; fm < 4; ++fm)
#pragma unroll
          for (int fn = 0; fn < 4; ++fn)
            acc[fm][fn] = __builtin_amdgcn_mfma_f32_16x16x32_bf16(af[fm], bl_[fn],
                                                                  acc[fm][fn], 0, 0, 0);
        bh8 al_[4];
#pragma unroll
        for (int f = 0; f < 4; ++f)
          al_[f] = *(const bh8*)&Al[(64 * wr + 16 * f + lj) * ST + kk];
#pragma unroll
        for (int fm = 0; fm < 4; ++fm)
#pragma unroll
          for (int fn = 0; fn < 4; ++fn)
            acc[fm][fn] = __builtin_amdgcn_mfma_f32_16x16x32_bf16(al_[fm], bf[fn],
                                                                  acc[fm][fn], 0, 0, 0);
      }
    }
    __syncthreads();
  }

#pragma unroll
  for (int fm = 0; fm < 4; ++fm) {
    const int mrow = m0 + 64 * wr + 16 * fm + 4 * lg;
#pragma unroll
    for (int fn = 0; fn < 4; ++fn) {
      const int ncol = n0 + 64 * wc + 16 * fn + lj;
      const float bn = BIAS_N ? bias[ncol] : 0.0f;
#pragma unroll
      for (int r = 0; r < 4; ++r) {
        float val = acc[fm][fn][r] + (BIAS_N ? bn : bias[mrow + r]);
        Cb[(size_t)(mrow + r) * cld + ncol] = val;
      }
    }
  }
}

// ---------------------------------------------------------------------------
// FUSED MFMA autocorrelation + candidate selection + FULL f64 refinement +
// exact top-40. One block (4 waves) per channel.
// ---------------------------------------------------------------------------
template <int P>
__device__ __forceinline__ void ac_kloop(const ushort_t* q_s, const ushort_t* k_s,
                                         int abase, int bstat, int jvalid,
                                         f4 acc[4]) {
  for (int t0 = 0; t0 < L_; t0 += 32) {
    i4 w0 = *(const i4*)&q_s[abase + t0];
    i4 w1 = *(const i4*)&q_s[abase + t0 + 8];
    uint_t w[8] = { (uint_t)w0.x, (uint_t)w0.y, (uint_t)w0.z, (uint_t)w0.w,
                    (uint_t)w1.x, (uint_t)w1.y, (uint_t)w1.z, (uint_t)w1.w };
    int koff = jvalid ? (bstat + t0) : 5888;
    bh8 Bf = *(const bh8*)&k_s[koff];
#pragma unroll
    for (int e = 0; e < 4; ++e) {
      const int ro = (e >> 1) + 2 * P;
      const int sh = (e & 1) * 16;
      uint_t a0 = (uint_t)((((unsigned long long)w[ro + 1] << 32) | w[ro + 0]) >> sh);
      uint_t a1 = (uint_t)((((unsigned long long)w[ro + 2] << 32) | w[ro + 1]) >> sh);
      uint_t a2 = (uint_t)((((unsigned long long)w[ro + 3] << 32) | w[ro + 2]) >> sh);
      uint_t a3 = (uint_t)((((unsigned long long)w[ro + 4] << 32) | w[ro + 3]) >> sh);
      i4 ai = { (int)a0, (int)a1, (int)a2, (int)a3 };
      bh8 Af = __builtin_bit_cast(bh8, ai);
      acc[e] = __builtin_amdgcn_mfma_f32_16x16x32_bf16(Af, Bf, acc[e], 0, 0, 0);
    }
  }
}

__global__ __launch_bounds__(256) void cand_refine_kernel(const float* __restrict__ Q,
                                                          const float* __restrict__ K,
                                                          double* __restrict__ top_vals,
                                                          int* __restrict__ top_idx,
                                                          int c0) {
  __shared__ ushort_t q_s[3456];       // q[x mod L] bf16
  __shared__ ushort_t k_s[5896];       // k[(x-2816) mod L] bf16 + zero slot
  __shared__ float ac_s[L_];
  __shared__ float redf[8];
  __shared__ int   redi[4];
  __shared__ int   cnt_s;
  __shared__ float cv[NCAND_];
  __shared__ int   ci[NCAND_];
  __shared__ double refv[NCAND_];
  const int c = blockIdx.x;
  const int tid = threadIdx.x;
  const float* Qp = Q + (size_t)c * L_;
  const float* Kp = K + (size_t)c * L_;

  for (int x8 = tid; x8 < 432; x8 += 256) {
    int x = x8 * 8; int src = x - (x >= L_ ? L_ : 0);
    float4 f0 = *(const float4*)(Qp + src);
    float4 f1 = *(const float4*)(Qp + src + 4);
    i4 pk = { (int)((uint_t)f32_to_bf16(f0.x) | ((uint_t)f32_to_bf16(f0.y) << 16)),
              (int)((uint_t)f32_to_bf16(f0.z) | ((uint_t)f32_to_bf16(f0.w) << 16)),
              (int)((uint_t)f32_to_bf16(f1.x) | ((uint_t)f32_to_bf16(f1.y) << 16)),
              (int)((uint_t)f32_to_bf16(f1.z) | ((uint_t)f32_to_bf16(f1.w) << 16)) };
    *(i4*)&q_s[x] = pk;
  }
  for (int x8 = tid; x8 < 736; x8 += 256) {
    int x = x8 * 8; int src = x - 2816 + (x < 2816 ? L_ : 0);
    float4 f0 = *(const float4*)(Kp + src);
    float4 f1 = *(const float4*)(Kp + src + 4);
    i4 pk = { (int)((uint_t)f32_to_bf16(f0.x) | ((uint_t)f32_to_bf16(f0.y) << 16)),
              (int)((uint_t)f32_to_bf16(f0.z) | ((uint_t)f32_to_bf16(f0.w) << 16)),
              (int)((uint_t)f32_to_bf16(f1.x) | ((uint_t)f32_to_bf16(f1.y) << 16)),
              (int)((uint_t)f32_to_bf16(f1.z) | ((uint_t)f32_to_bf16(f1.w) << 16)) };
    *(i4*)&k_s[x] = pk;
  }
  if (tid < 8) k_s[5888 + tid] = 0;
  __syncthreads();

  const int lane = tid & 63, fg = tid >> 6;
  const int lg = lane >> 4, lj = lane & 15;
  const int abase = 8 * lg + 16 * lj + 8 * (fg >> 1);
  const int jvalid = (lj < 12) ? 1 : 0;
  const int bstat = 2816 + 8 * lg - 256 * lj;

  f4 acc[4];
#pragma unroll
  for (int e = 0; e < 4; ++e) acc[e] = (f4){0.f, 0.f, 0.f, 0.f};

  if (fg & 1) ac_kloop<1>(q_s, k_s, abase, bstat, jvalid, acc);
  else        ac_kloop<0>(q_s, k_s, abase, bstat, jvalid, acc);

  if (jvalid) {
#pragma unroll
    for (int e = 0; e < 4; ++e) {
      int f = 4 * fg + e;
#pragma unroll
      for (int r = 0; r < 4; ++r) {
        int g = f + 16 * (4 * lg + r);      // fine lag in [0,256)
        ac_s[lj + 12 * g] = acc[e][r];      // tau = g + 256*lj
      }
    }
  }
  __syncthreads();

  float v[12];
#pragma unroll
  for (int it = 0; it < 12; ++it) v[it] = ac_s[tid + 256 * it];

  // block max
  float lm = v[0];
#pragma unroll
  for (int it = 1; it < 12; ++it) lm = fmaxf(lm, v[it]);
  for (int o = 32; o; o >>= 1) lm = fmaxf(lm, __shfl_down(lm, o));
  if ((tid & 63) == 0) redf[tid >> 6] = lm;
  __syncthreads();
  if (tid == 0) redf[4] = fmaxf(fmaxf(redf[0], redf[1]), fmaxf(redf[2], redf[3]));
  __syncthreads();
  const float Tmax = redf[4];

  auto bcount = [&](float T) -> int {
    int lc = 0;
#pragma unroll
    for (int it = 0; it < 12; ++it) lc += (v[it] > T) ? 1 : 0;
    for (int o = 32; o; o >>= 1) lc += __shfl_down(lc, o);
    __syncthreads();
    if ((tid & 63) == 0) redi[tid >> 6] = lc;
    __syncthreads();
    return redi[0] + redi[1] + redi[2] + redi[3];
  };

  float lo = Tmax - 128.0f;
  int cl = bcount(lo);
  for (int wd = 1; wd <= 5 && cl < CFLOOR_; ++wd) {
    lo = Tmax - 128.0f * (float)(1 << wd); cl = bcount(lo);
  }
  float hi = Tmax, T = lo;
  int cT = cl;
  for (int i = 0; i < 26 && cT > NCAND_; ++i) {
    float mid = 0.5f * (lo + hi);
    int cm = bcount(mid);
    if (cm >= CFLOOR_) { lo = mid; T = mid; cT = cm; } else hi = mid;
  }

  if (tid == 0) cnt_s = 0;
  __syncthreads();
#pragma unroll
  for (int it = 0; it < 12; ++it) {
    if (v[it] > T) {
      int pos = atomicAdd(&cnt_s, 1);
      if (pos < NCAND_) {
        int m = tid + 256 * it;
        int g = m / 12, j = m - 12 * g;
        cv[pos] = v[it];
        ci[pos] = g + 256 * j;
      }
    }
  }
  __syncthreads();
  const int cnt = cnt_s < NCAND_ ? cnt_s : NCAND_;

  // ---- Phase C: exact f64 ac for ALL candidates, one WAVE per candidate ----
  for (int r = fg; r < cnt; r += 4) {
    const int tau = ci[r];
    double a = 0.0;
#pragma unroll 4
    for (int u = 0; u < 48; ++u) {
      int t = lane + 64 * u;
      int qi = t + tau; qi -= (qi >= L_) ? L_ : 0;
      a = fma((double)Qp[qi], (double)Kp[t], a);
    }
#pragma unroll
    for (int o = 32; o; o >>= 1) a += __shfl_down(a, o);
    if (lane == 0) refv[r] = a;
  }
  __syncthreads();

  // ---- Phase D: wave 0 sorts all refined (f64 desc, idx asc) -> top-40 ----
  double* out_v = top_vals + (size_t)(c0 + c) * TOPK_;
  int*    out_i = top_idx  + (size_t)(c0 + c) * TOPK_;
  if (tid < 64) {
    double dv = (tid < cnt) ? refv[tid] : -1e300;
    int    di = (tid < cnt) ? ci[tid]   : (1 << 30);
    int used = 0;
    for (int r = 0; r < TOPK_; ++r) {
      double bv = used ? -1e300 : dv;
      int    bi = used ? (1 << 30) : di;
      int    bl = tid;
      for (int o = 32; o; o >>= 1) {
        double ov = __shfl_down(bv, o);
        int    oi = __shfl_down(bi, o);
        int    ol = __shfl_down(bl, o);
        if (ov > bv || (ov == bv && oi < bi)) { bv = ov; bi = oi; bl = ol; }
      }
      bv = __shfl(bv, 0); bi = __shfl(bi, 0); bl = __shfl(bl, 0);
      if (tid == 0) { out_v[r] = bv; out_i[r] = (bi < L_) ? bi : 0; }
      if (tid == bl) used = 1;
    }
  }
}

// ---------------------------------------------------------------------------
__global__ __launch_bounds__(256) void shifts_kernel(const int* __restrict__ top_idx,
                                                     int* __restrict__ shifts) {
  const int k = blockIdx.x;
  __shared__ double sred[256];
  double s = 0.0;
  for (int c = threadIdx.x; c < CH_; c += 256) s += (double)top_idx[(size_t)c * TOPK_ + k];
  sred[threadIdx.x] = s;
  __syncthreads();
  for (int o = 128; o > 0; o >>= 1) {
    if (threadIdx.x < o) sred[threadIdx.x] += sred[threadIdx.x + o];
    __syncthreads();
  }
  if (threadIdx.x == 0) shifts[k] = (int)((float)(sred[0] / (double)CH_));
}

__global__ __launch_bounds__(256) void softmax_kernel(const double* __restrict__ top_vals,
                                                      float* __restrict__ weights) {
  const int c = blockIdx.x * 256 + threadIdx.x;
  const double* v = top_vals + (size_t)c * TOPK_;
  double m = v[0];
  for (int k = 1; k < TOPK_; ++k) m = fmax(m, v[k]);
  double sum = 0.0;
  for (int k = 0; k < TOPK_; ++k) sum += exp(v[k] - m);
  double inv = 1.0 / sum;
  for (int k = 0; k < TOPK_; ++k)
    weights[(size_t)c * TOPK_ + k] = (float)(exp(v[k] - m) * inv);
}

__global__ __launch_bounds__(256) void agg_kernel(float* __restrict__ Vc,
                                                  const float* __restrict__ weights,
                                                  const int* __restrict__ shifts) {
  const int c = blockIdx.x;
  __shared__ float v_s[L_];
  __shared__ float w_s[TOPK_];
  __shared__ int   s_s[TOPK_];
  for (int i = threadIdx.x; i < L_; i += 256) v_s[i] = Vc[(size_t)c * L_ + i];
  if (threadIdx.x < TOPK_) {
    w_s[threadIdx.x] = weights[(size_t)c * TOPK_ + threadIdx.x];
    s_s[threadIdx.x] = shifts[threadIdx.x];
  }
  __syncthreads();
  for (int t = threadIdx.x; t < L_; t += 256) {
    float sum = 0.0f;
#pragma unroll
    for (int k = 0; k < TOPK_; ++k) {
      int idx = t + s_s[k];
      if (idx >= L_) idx -= L_;
      sum = fmaf(w_s[k], v_s[idx], sum);
    }
    Vc[(size_t)c * L_ + t] = sum;
  }
}

// ---------------------------------------------------------------------------
extern "C" void kernel_launch(void* const* d_in, const int* in_sizes, int n_in,
                              void* d_out, int out_size, void* d_ws, size_t ws_size,
                              hipStream_t stream) {
  const float* query = (const float*)d_in[0];
  const float* key   = (const float*)d_in[1];
  const float* value = (const float*)d_in[2];
  const float* Wq = (const float*)d_in[3];
  const float* bq = (const float*)d_in[4];
  const float* Wk = (const float*)d_in[5];
  const float* bk = (const float*)d_in[6];
  const float* Wv = (const float*)d_in[7];
  const float* bvp = (const float*)d_in[8];
  const float* Wo = (const float*)d_in[9];
  const float* bo = (const float*)d_in[10];
  float* out = (float*)d_out;
  char* ws = (char*)d_ws;

  auto al = [](size_t x) { return (x + 255) & ~(size_t)255; };
  size_t off = 0;
  const size_t tv_off = off; off = al(off + (size_t)CH_ * TOPK_ * 8);
  const size_t ti_off = off; off = al(off + (size_t)CH_ * TOPK_ * 4);
  const size_t w_off  = off; off = al(off + (size_t)CH_ * TOPK_ * 4);
  const size_t sh_off = off; off = al(off + (size_t)TOPK_ * 4);
  const size_t small_end = off;                       // ~5.3 MB

  const size_t QK1   = (size_t)D_ * L_ * 4;           // 6.29 MB f32, one batch
  const size_t PBQK  = al(2 * QK1);                   // ~12.6 MB per batch
  const size_t AGG_BYTES    = (size_t)CH_ * L_ * 4;   // 96 MB
  const size_t BOUNCE_BYTES = (size_t)D_ * L_ * 4;    // 6 MB

  int nb; bool bounce;
  if (ws_size >= small_end + AGG_BYTES + PBQK) {
    bounce = false;
    size_t n = (ws_size - small_end - AGG_BYTES) / PBQK;
    nb = (int)(n > 16 ? 16 : n);
  } else {
    bounce = true;
    size_t rem = (ws_size > small_end + BOUNCE_BYTES) ? (ws_size - small_end - BOUNCE_BYTES) : 0;
    size_t n = rem / PBQK; nb = (int)(n > 16 ? 16 : n);
    if (nb < 1) nb = 1;
  }

  double* top_vals = (double*)(ws + tv_off);
  int*    top_idx  = (int*)(ws + ti_off);
  float*  weights  = (float*)(ws + w_off);
  int*    shifts   = (int*)(ws + sh_off);

  float* VcAgg;
  float* bounce_buf = nullptr;
  size_t qk_off;
  if (!bounce) {
    VcAgg = (float*)(ws + small_end);
    qk_off = small_end + al(AGG_BYTES);
  } else {
    bounce_buf = (float*)(ws + small_end);
    qk_off = small_end + al(BOUNCE_BYTES);
    VcAgg = (float*)d_out;
  }
  float* Qc = (float*)(ws + qk_off);
  float* Kc = (float*)(ws + qk_off + al((size_t)nb * QK1));

  dim3 blk(256);
  const long bXS = (long)L_ * D_;   // batch stride of inputs / out
  const long cQS = (long)D_ * L_;   // batch stride of channel-major tensors

  for (int b0 = 0; b0 < B_; b0 += nb) {
    int nbb = (B_ - b0 < nb) ? (B_ - b0) : nb;
    dim3 g(L_ / 64, D_ / 64, nbb);
    proj_kernel<<<g, blk, 0, stream>>>(query + (size_t)b0 * L_ * D_, Wq, bq, Qc);
    proj_kernel<<<g, blk, 0, stream>>>(key   + (size_t)b0 * L_ * D_, Wk, bk, Kc);
    cand_refine_kernel<<<nbb * D_, blk, 0, stream>>>(Qc, Kc, top_vals, top_idx, b0 * D_);
  }
  shifts_kernel<<<TOPK_, blk, 0, stream>>>(top_idx, shifts);
  softmax_kernel<<<CH_ / 256, blk, 0, stream>>>(top_vals, weights);

  {
    dim3 gp(L_ / 128, D_ / 128, B_);
    gemm_mfma<3, false, false><<<gp, blk, 0, stream>>>(
        Wv, value, bvp, VcAgg, 0, bXS, cQS, L_);
  }
  agg_kernel<<<CH_, blk, 0, stream>>>(VcAgg, weights, shifts);

  if (!bounce) {
    dim3 go(D_ / 128, L_ / 128, B_);    // (4, 24, 16)
    gemm_mfma<3, true, true><<<go, blk, 0, stream>>>(
        VcAgg, Wo, bo, out, cQS, 0, bXS, D_);
  } else {
    for (int b = 0; b < B_; ++b) {
      hipMemcpyAsync(bounce_buf, VcAgg + (size_t)b * D_ * L_, BOUNCE_BYTES,
                     hipMemcpyDeviceToDevice, stream);
      dim3 go(D_ / 128, L_ / 128, 1);
      gemm_mfma<3, true, true><<<go, blk, 0, stream>>>(
          bounce_buf, Wo, bo, out + (size_t)b * L_ * D_, 0, 0, 0, D_);
    }
  }
  (void)in_sizes; (void)n_in; (void)out_size;
}

// Round 8
// 1698.428 us; speedup vs baseline: 3.4574x; 1.2374x over previous
//
#include <hip/hip_runtime.h>
#include <hip/hip_bf16.h>
#include <math.h>

#define B_ 16
#define L_ 3072
#define D_ 512
#define CH_ (B_ * D_)   // 8192 channels
#define TOPK_ 40
#define NCAND_ 64       // candidate slots per channel (all refined in f64)
#define CFLOOR_ 52      // candidate count floor (12-rank cushion over 40)

typedef unsigned short ushort_t;
typedef unsigned int uint_t;
typedef __attribute__((ext_vector_type(8))) short bh8;   // 8 bf16 (4 VGPRs)
typedef __attribute__((ext_vector_type(4))) float f4;    // 4 f32 acc
typedef __attribute__((ext_vector_type(4))) int i4;      // 16B vector

__device__ __forceinline__ uint_t cvt_pk_bf16(float a, float b) {
  uint_t r;
  asm("v_cvt_pk_bf16_f32 %0, %1, %2" : "=v"(r) : "v"(a), "v"(b));
  return r;  // lo ushort = bf16(a), hi ushort = bf16(b)
}

// LDS byte-address swizzles (involutions; preserve 16B alignment)
__device__ __forceinline__ int swzq(int b) { return b ^ (((b >> 7) & 3) << 4); }
__device__ __forceinline__ int swzk(int b) { return b ^ (((b >> 9) & 7) << 4); }

// ---------------------------------------------------------------------------
// f32-VALU projection GEMM, 128x128 tile, 8x8 per thread (SELECTION path).
// P[c][t] = sum_j X[b][t][j]*W[i][j] + bias[i]. Per-output product order is
// ascending j with fmaf chain -> BIT-IDENTICAL to the round-4/7 proven proj.
// LDS layout [kk][row] (transposed) so fragment reads are b128.
// ---------------------------------------------------------------------------
__global__ __launch_bounds__(256) void proj_kernel(const float* __restrict__ X,
                                                   const float* __restrict__ W,
                                                   const float* __restrict__ bias,
                                                   float* __restrict__ P) {
  __shared__ float Xs[32 * 132];
  __shared__ float Ws[32 * 132];
  const int t0 = blockIdx.x * 128;
  const int i0 = blockIdx.y * 128;
  const int b  = blockIdx.z;
  const int tid = threadIdx.x;
  const int tx = tid & 15, ty = tid >> 4;

  float acc[8][8];
#pragma unroll
  for (int r = 0; r < 8; ++r)
#pragma unroll
    for (int s = 0; s < 8; ++s) acc[r][s] = 0.0f;

  for (int j0 = 0; j0 < D_; j0 += 32) {
    {
      const int row = tid >> 1, jh = (tid & 1) * 16;
      const float* gx = X + ((size_t)b * L_ + t0 + row) * D_ + j0 + jh;
      const float* gw = W + (size_t)(i0 + row) * D_ + j0 + jh;
#pragma unroll
      for (int p = 0; p < 4; ++p) {
        float4 xv = *(const float4*)(gx + 4 * p);
        float4 wv = *(const float4*)(gw + 4 * p);
        int kk = jh + 4 * p;
        Xs[(kk + 0) * 132 + row] = xv.x;
        Xs[(kk + 1) * 132 + row] = xv.y;
        Xs[(kk + 2) * 132 + row] = xv.z;
        Xs[(kk + 3) * 132 + row] = xv.w;
        Ws[(kk + 0) * 132 + row] = wv.x;
        Ws[(kk + 1) * 132 + row] = wv.y;
        Ws[(kk + 2) * 132 + row] = wv.z;
        Ws[(kk + 3) * 132 + row] = wv.w;
      }
    }
    __syncthreads();
#pragma unroll 4
    for (int kk = 0; kk < 32; ++kk) {
      float a8[8], w8[8];
      *(float4*)&a8[0] = *(const float4*)&Xs[kk * 132 + 8 * ty];
      *(float4*)&a8[4] = *(const float4*)&Xs[kk * 132 + 8 * ty + 4];
      *(float4*)&w8[0] = *(const float4*)&Ws[kk * 132 + 8 * tx];
      *(float4*)&w8[4] = *(const float4*)&Ws[kk * 132 + 8 * tx + 4];
#pragma unroll
      for (int r = 0; r < 8; ++r)
#pragma unroll
        for (int s = 0; s < 8; ++s)
          acc[r][s] = fmaf(a8[r], w8[s], acc[r][s]);
    }
    __syncthreads();
  }
#pragma unroll
  for (int s = 0; s < 8; ++s) {
    const int i = i0 + 8 * tx + s;
    const float bia = bias[i];
    float* dst = P + (size_t)(b * D_ + i) * L_ + t0 + 8 * ty;
    float4 v0 = { acc[0][s] + bia, acc[1][s] + bia, acc[2][s] + bia, acc[3][s] + bia };
    float4 v1 = { acc[4][s] + bia, acc[5][s] + bia, acc[6][s] + bia, acc[7][s] + bia };
    *(float4*)dst = v0;
    *(float4*)(dst + 4) = v1;
  }
}

// ---------------------------------------------------------------------------
// MFMA GEMM, 128x128 tile, 4 waves — LINEAR path only (V proj, out GEMM).
// NPASS=3: split-bf16 (hi/lo) -> ~1e-5 rel accuracy, fine for linear path.
// ---------------------------------------------------------------------------
template <int NPASS, int BK, int ST>
__device__ __forceinline__ void stage_rows(const float* __restrict__ g0,
                                           ushort_t* __restrict__ Hh,
                                           ushort_t* __restrict__ Hl,
                                           int tid) {
  const int row = tid >> 1;
  const int cb = (tid & 1) * (BK / 2);
  const float* g = g0 + (size_t)row * 512 + cb;
  ushort_t* lh = Hh + row * ST + cb;
  ushort_t* ll = Hl + row * ST + cb;
#pragma unroll
  for (int p = 0; p < BK / 8; ++p) {
    float4 v = *(const float4*)(g + 4 * p);
    uint_t h01 = cvt_pk_bf16(v.x, v.y);
    uint_t h23 = cvt_pk_bf16(v.z, v.w);
    *(uint2*)(lh + 4 * p) = make_uint2(h01, h23);
    if (NPASS == 3) {
      float x0 = __builtin_bit_cast(float, h01 << 16);
      float x1 = __builtin_bit_cast(float, h01 & 0xFFFF0000u);
      float x2 = __builtin_bit_cast(float, h23 << 16);
      float x3 = __builtin_bit_cast(float, h23 & 0xFFFF0000u);
      uint_t l01 = cvt_pk_bf16(v.x - x0, v.y - x1);
      uint_t l23 = cvt_pk_bf16(v.z - x2, v.w - x3);
      *(uint2*)(ll + 4 * p) = make_uint2(l01, l23);
    }
  }
}

template <int NPASS, bool ATR, bool BIAS_N>
__global__ __launch_bounds__(256) void gemm_mfma(const float* __restrict__ Ap,
                                                 const float* __restrict__ Bp,
                                                 const float* __restrict__ bias,
                                                 float* __restrict__ Cp,
                                                 long aBS, long bBS, long cBS,
                                                 int cld) {
  constexpr int BK = (NPASS == 3) ? 32 : 64;
  constexpr int ST = (NPASS == 3) ? 40 : 72;
  __shared__ ushort_t Ah[128 * ST];
  __shared__ ushort_t Bh[128 * ST];
  __shared__ ushort_t Al[(NPASS == 3) ? 128 * ST : 8];
  __shared__ ushort_t Bl[(NPASS == 3) ? 128 * ST : 8];

  const float* Asrc = Ap + (size_t)blockIdx.z * aBS;
  const float* Bsrc = Bp + (size_t)blockIdx.z * bBS;
  float* Cb = Cp + (size_t)blockIdx.z * cBS;
  const int n0 = blockIdx.x * 128, m0 = blockIdx.y * 128;
  const int tid = threadIdx.x;
  const int lane = tid & 63, w = tid >> 6;
  const int wr = w >> 1, wc = w & 1;
  const int lj = lane & 15, lg = lane >> 4;

  f4 acc[4][4];
#pragma unroll
  for (int fm = 0; fm < 4; ++fm)
#pragma unroll
    for (int fn = 0; fn < 4; ++fn) acc[fm][fn] = (f4){0.f, 0.f, 0.f, 0.f};

  for (int kc = 0; kc < 512; kc += BK) {
    if (!ATR) {
      stage_rows<NPASS, BK, ST>(Asrc + (size_t)m0 * 512 + kc, Ah, Al, tid);
    } else {
      constexpr int TPC = 256 / BK;
      constexpr int TC  = 128 / TPC;
      const int jl = tid / TPC, ts = tid % TPC;
      const float* g = Asrc + (size_t)(kc + jl) * L_ + m0 + ts * TC;
#pragma unroll
      for (int p = 0; p < TC / 4; ++p) {
        float4 v = *(const float4*)(g + 4 * p);
        uint_t h01 = cvt_pk_bf16(v.x, v.y);
        uint_t h23 = cvt_pk_bf16(v.z, v.w);
        int t = ts * TC + 4 * p;
        Ah[(t + 0) * ST + jl] = (ushort_t)(h01 & 0xFFFFu);
        Ah[(t + 1) * ST + jl] = (ushort_t)(h01 >> 16);
        Ah[(t + 2) * ST + jl] = (ushort_t)(h23 & 0xFFFFu);
        Ah[(t + 3) * ST + jl] = (ushort_t)(h23 >> 16);
        if (NPASS == 3) {
          float x0 = __builtin_bit_cast(float, h01 << 16);
          float x1 = __builtin_bit_cast(float, h01 & 0xFFFF0000u);
          float x2 = __builtin_bit_cast(float, h23 << 16);
          float x3 = __builtin_bit_cast(float, h23 & 0xFFFF0000u);
          uint_t l01 = cvt_pk_bf16(v.x - x0, v.y - x1);
          uint_t l23 = cvt_pk_bf16(v.z - x2, v.w - x3);
          Al[(t + 0) * ST + jl] = (ushort_t)(l01 & 0xFFFFu);
          Al[(t + 1) * ST + jl] = (ushort_t)(l01 >> 16);
          Al[(t + 2) * ST + jl] = (ushort_t)(l23 & 0xFFFFu);
          Al[(t + 3) * ST + jl] = (ushort_t)(l23 >> 16);
        }
      }
    }
    stage_rows<NPASS, BK, ST>(Bsrc + (size_t)n0 * 512 + kc, Bh, Bl, tid);
    __syncthreads();

#pragma unroll
    for (int ks = 0; ks < BK / 32; ++ks) {
      const int kk = ks * 32 + 8 * lg;
      bh8 af[4], bf[4];
#pragma unroll
      for (int f = 0; f < 4; ++f)
        af[f] = *(const bh8*)&Ah[(64 * wr + 16 * f + lj) * ST + kk];
#pragma unroll
      for (int f = 0; f < 4; ++f)
        bf[f] = *(const bh8*)&Bh[(64 * wc + 16 * f + lj) * ST + kk];
#pragma unroll
      for (int fm = 0; fm < 4; ++fm)
#pragma unroll
        for (int fn = 0; fn < 4; ++fn)
          acc[fm][fn] = __builtin_amdgcn_mfma_f32_16x16x32_bf16(af[fm], bf[fn],
                                                                acc[fm][fn], 0, 0, 0);
      if (NPASS == 3) {
        bh8 bl_[4];
#pragma unroll
        for (int f = 0; f < 4; ++f)
          bl_[f] = *(const bh8*)&Bl[(64 * wc + 16 * f + lj) * ST + kk];
#pragma unroll
        for (int fm = 0; fm < 4; ++fm)
#pragma unroll
          for (int fn = 0; fn < 4; ++fn)
            acc[fm][fn] = __builtin_amdgcn_mfma_f32_16x16x32_bf16(af[fm], bl_[fn],
                                                                  acc[fm][fn], 0, 0, 0);
        bh8 al_[4];
#pragma unroll
        for (int f = 0; f < 4; ++f)
          al_[f] = *(const bh8*)&Al[(64 * wr + 16 * f + lj) * ST + kk];
#pragma unroll
        for (int fm = 0; fm < 4; ++fm)
#pragma unroll
          for (int fn = 0; fn < 4; ++fn)
            acc[fm][fn] = __builtin_amdgcn_mfma_f32_16x16x32_bf16(al_[fm], bf[fn],
                                                                  acc[fm][fn], 0, 0, 0);
      }
    }
    __syncthreads();
  }

#pragma unroll
  for (int fm = 0; fm < 4; ++fm) {
    const int mrow = m0 + 64 * wr + 16 * fm + 4 * lg;
#pragma unroll
    for (int fn = 0; fn < 4; ++fn) {
      const int ncol = n0 + 64 * wc + 16 * fn + lj;
      const float bn = BIAS_N ? bias[ncol] : 0.0f;
#pragma unroll
      for (int r = 0; r < 4; ++r) {
        float val = acc[fm][fn][r] + (BIAS_N ? bn : bias[mrow + r]);
        Cb[(size_t)(mrow + r) * cld + ncol] = val;
      }
    }
  }
}

// ---------------------------------------------------------------------------
// FUSED MFMA autocorrelation + candidate selection + FULL f64 refinement +
// exact top-40. One block (4 waves) per channel.
// LDS swizzled (k: 16-way -> 2-way; q: 4-way -> 2-way bank conflicts).
// Phase C refines from an LDS f32 copy (reusing dead bf16/ac regions);
// f64 sum partition identical to round 7 -> refv bit-identical.
// ---------------------------------------------------------------------------
template <int P>
__device__ __forceinline__ void ac_kloop(const char* __restrict__ qb,
                                         const char* __restrict__ kb,
                                         int abyte, int bbyte, int jvalid,
                                         f4 acc[4]) {
  for (int t0b = 0; t0b < 2 * L_; t0b += 64) {
    const int a0 = abyte + t0b;
    const int a1 = a0 + 16;
    i4 w0 = *(const i4*)(qb + swzq(a0));
    i4 w1 = *(const i4*)(qb + swzq(a1));
    uint_t w[8] = { (uint_t)w0.x, (uint_t)w0.y, (uint_t)w0.z, (uint_t)w0.w,
                    (uint_t)w1.x, (uint_t)w1.y, (uint_t)w1.z, (uint_t)w1.w };
    const int bb = jvalid ? (bbyte + t0b) : 11776;
    bh8 Bf = *(const bh8*)(kb + swzk(bb));
#pragma unroll
    for (int e = 0; e < 4; ++e) {
      const int ro = (e >> 1) + 2 * P;
      const int sh = (e & 1) * 16;
      uint_t a0v = (uint_t)((((unsigned long long)w[ro + 1] << 32) | w[ro + 0]) >> sh);
      uint_t a1v = (uint_t)((((unsigned long long)w[ro + 2] << 32) | w[ro + 1]) >> sh);
      uint_t a2v = (uint_t)((((unsigned long long)w[ro + 3] << 32) | w[ro + 2]) >> sh);
      uint_t a3v = (uint_t)((((unsigned long long)w[ro + 4] << 32) | w[ro + 3]) >> sh);
      i4 ai = { (int)a0v, (int)a1v, (int)a2v, (int)a3v };
      bh8 Af = __builtin_bit_cast(bh8, ai);
      acc[e] = __builtin_amdgcn_mfma_f32_16x16x32_bf16(Af, Bf, acc[e], 0, 0, 0);
    }
  }
}

__global__ __launch_bounds__(256) void cand_refine_kernel(const float* __restrict__ Q,
                                                          const float* __restrict__ K,
                                                          double* __restrict__ top_vals,
                                                          int* __restrict__ top_idx,
                                                          int c0) {
  // phase A: [0,6912) q bf16 (swizzled) | [6912,18816) k bf16 (swizzled) |
  //          [18816,31104) ac f32
  // phase C: [0,12288) q f32 | [12288,24576) k f32   (A regions dead)
  __shared__ __align__(16) char smem[31104];
  __shared__ float redf[8];
  __shared__ int   redi[4];
  __shared__ int   cnt_s;
  __shared__ float cv[NCAND_];
  __shared__ int   ci[NCAND_];
  __shared__ double refv[NCAND_];
  char* kbase = smem + 6912;
  float* ac_s = (float*)(smem + 18816);
  const int c = blockIdx.x;
  const int tid = threadIdx.x;
  const float* Qp = Q + (size_t)c * L_;
  const float* Kp = K + (size_t)c * L_;

  // ---- Phase A staging: f32 -> bf16 (cvt_pk), swizzled stores ----
  for (int x8 = tid; x8 < 432; x8 += 256) {
    int x = x8 * 8; int src = x - (x >= L_ ? L_ : 0);
    float4 f0 = *(const float4*)(Qp + src);
    float4 f1 = *(const float4*)(Qp + src + 4);
    i4 pk = { (int)cvt_pk_bf16(f0.x, f0.y), (int)cvt_pk_bf16(f0.z, f0.w),
              (int)cvt_pk_bf16(f1.x, f1.y), (int)cvt_pk_bf16(f1.z, f1.w) };
    *(i4*)(smem + swzq(16 * x8)) = pk;
  }
  for (int x8 = tid; x8 < 736; x8 += 256) {
    int x = x8 * 8; int src = x - 2816 + (x < 2816 ? L_ : 0);
    float4 f0 = *(const float4*)(Kp + src);
    float4 f1 = *(const float4*)(Kp + src + 4);
    i4 pk = { (int)cvt_pk_bf16(f0.x, f0.y), (int)cvt_pk_bf16(f0.z, f0.w),
              (int)cvt_pk_bf16(f1.x, f1.y), (int)cvt_pk_bf16(f1.z, f1.w) };
    *(i4*)(kbase + swzk(16 * x8)) = pk;
  }
  if (tid == 0) *(i4*)(kbase + swzk(11776)) = (i4){0, 0, 0, 0};  // zero slot
  __syncthreads();

  const int lane = tid & 63, fg = tid >> 6;
  const int lg = lane >> 4, lj = lane & 15;
  const int abyte = 16 * lg + 32 * lj + 16 * (fg >> 1);
  const int jvalid = (lj < 12) ? 1 : 0;
  const int bbyte = 5632 + 16 * lg - 512 * lj;

  f4 acc[4];
#pragma unroll
  for (int e = 0; e < 4; ++e) acc[e] = (f4){0.f, 0.f, 0.f, 0.f};

  if (fg & 1) ac_kloop<1>(smem, kbase, abyte, bbyte, jvalid, acc);
  else        ac_kloop<0>(smem, kbase, abyte, bbyte, jvalid, acc);

  if (jvalid) {
#pragma unroll
    for (int e = 0; e < 4; ++e) {
      int f = 4 * fg + e;
#pragma unroll
      for (int r = 0; r < 4; ++r) {
        int g = f + 16 * (4 * lg + r);      // fine lag in [0,256)
        ac_s[lj + 12 * g] = acc[e][r];      // tau = g + 256*lj
      }
    }
  }
  __syncthreads();

  float v[12];
#pragma unroll
  for (int it = 0; it < 12; ++it) v[it] = ac_s[tid + 256 * it];

  // block max
  float lm = v[0];
#pragma unroll
  for (int it = 1; it < 12; ++it) lm = fmaxf(lm, v[it]);
  for (int o = 32; o; o >>= 1) lm = fmaxf(lm, __shfl_down(lm, o));
  if ((tid & 63) == 0) redf[tid >> 6] = lm;
  __syncthreads();
  if (tid == 0) redf[4] = fmaxf(fmaxf(redf[0], redf[1]), fmaxf(redf[2], redf[3]));
  __syncthreads();
  const float Tmax = redf[4];

  auto bcount = [&](float T) -> int {
    int lc = 0;
#pragma unroll
    for (int it = 0; it < 12; ++it) lc += (v[it] > T) ? 1 : 0;
    for (int o = 32; o; o >>= 1) lc += __shfl_down(lc, o);
    __syncthreads();
    if ((tid & 63) == 0) redi[tid >> 6] = lc;
    __syncthreads();
    return redi[0] + redi[1] + redi[2] + redi[3];
  };

  float lo = Tmax - 128.0f;
  int cl = bcount(lo);
  for (int wd = 1; wd <= 5 && cl < CFLOOR_; ++wd) {
    lo = Tmax - 128.0f * (float)(1 << wd); cl = bcount(lo);
  }
  float hi = Tmax, T = lo;
  int cT = cl;
  for (int i = 0; i < 26 && cT > NCAND_; ++i) {
    float mid = 0.5f * (lo + hi);
    int cm = bcount(mid);
    if (cm >= CFLOOR_) { lo = mid; T = mid; cT = cm; } else hi = mid;
  }

  if (tid == 0) cnt_s = 0;
  __syncthreads();
#pragma unroll
  for (int it = 0; it < 12; ++it) {
    if (v[it] > T) {
      int pos = atomicAdd(&cnt_s, 1);
      if (pos < NCAND_) {
        int m = tid + 256 * it;
        int g = m / 12, j = m - 12 * g;
        cv[pos] = v[it];
        ci[pos] = g + 256 * j;
      }
    }
  }
  __syncthreads();
  const int cnt = cnt_s < NCAND_ ? cnt_s : NCAND_;

  // ---- Phase C staging: f32 q/k into reused LDS (A regions dead) ----
  float* qf = (float*)smem;
  float* kf = (float*)(smem + 12288);
  for (int i4i = tid * 4; i4i < L_; i4i += 1024) {
    *(float4*)&qf[i4i] = *(const float4*)(Qp + i4i);
    *(float4*)&kf[i4i] = *(const float4*)(Kp + i4i);
  }
  __syncthreads();

  // ---- Phase C: exact f64 ac for ALL candidates, one WAVE per candidate ----
  // (t = lane + 64u partition + shfl tree identical to round 7 -> bit-equal)
  for (int r = fg; r < cnt; r += 4) {
    const int tau = ci[r];
    double a = 0.0;
#pragma unroll 4
    for (int u = 0; u < 48; ++u) {
      int t = lane + 64 * u;
      int qi = t + tau; qi -= (qi >= L_) ? L_ : 0;
      a = fma((double)qf[qi], (double)kf[t], a);
    }
#pragma unroll
    for (int o = 32; o; o >>= 1) a += __shfl_down(a, o);
    if (lane == 0) refv[r] = a;
  }
  __syncthreads();

  // ---- Phase D: wave 0 sorts all refined (f64 desc, idx asc) -> top-40 ----
  double* out_v = top_vals + (size_t)(c0 + c) * TOPK_;
  int*    out_i = top_idx  + (size_t)(c0 + c) * TOPK_;
  if (tid < 64) {
    double dv = (tid < cnt) ? refv[tid] : -1e300;
    int    di = (tid < cnt) ? ci[tid]   : (1 << 30);
    int used = 0;
    for (int r = 0; r < TOPK_; ++r) {
      double bv = used ? -1e300 : dv;
      int    bi = used ? (1 << 30) : di;
      int    bl = tid;
      for (int o = 32; o; o >>= 1) {
        double ov = __shfl_down(bv, o);
        int    oi = __shfl_down(bi, o);
        int    ol = __shfl_down(bl, o);
        if (ov > bv || (ov == bv && oi < bi)) { bv = ov; bi = oi; bl = ol; }
      }
      bv = __shfl(bv, 0); bi = __shfl(bi, 0); bl = __shfl(bl, 0);
      if (tid == 0) { out_v[r] = bv; out_i[r] = (bi < L_) ? bi : 0; }
      if (tid == bl) used = 1;
    }
  }
}

// ---------------------------------------------------------------------------
__global__ __launch_bounds__(256) void shifts_kernel(const int* __restrict__ top_idx,
                                                     int* __restrict__ shifts) {
  const int k = blockIdx.x;
  __shared__ double sred[256];
  double s = 0.0;
  for (int c = threadIdx.x; c < CH_; c += 256) s += (double)top_idx[(size_t)c * TOPK_ + k];
  sred[threadIdx.x] = s;
  __syncthreads();
  for (int o = 128; o > 0; o >>= 1) {
    if (threadIdx.x < o) sred[threadIdx.x] += sred[threadIdx.x + o];
    __syncthreads();
  }
  if (threadIdx.x == 0) shifts[k] = (int)((float)(sred[0] / (double)CH_));
}

__global__ __launch_bounds__(256) void softmax_kernel(const double* __restrict__ top_vals,
                                                      float* __restrict__ weights) {
  const int c = blockIdx.x * 256 + threadIdx.x;
  const double* v = top_vals + (size_t)c * TOPK_;
  double m = v[0];
  for (int k = 1; k < TOPK_; ++k) m = fmax(m, v[k]);
  double sum = 0.0;
  for (int k = 0; k < TOPK_; ++k) sum += exp(v[k] - m);
  double inv = 1.0 / sum;
  for (int k = 0; k < TOPK_; ++k)
    weights[(size_t)c * TOPK_ + k] = (float)(exp(v[k] - m) * inv);
}

__global__ __launch_bounds__(256) void agg_kernel(float* __restrict__ Vc,
                                                  const float* __restrict__ weights,
                                                  const int* __restrict__ shifts) {
  const int c = blockIdx.x;
  __shared__ float v_s[L_];
  __shared__ float w_s[TOPK_];
  __shared__ int   s_s[TOPK_];
  for (int i = threadIdx.x; i < L_; i += 256) v_s[i] = Vc[(size_t)c * L_ + i];
  if (threadIdx.x < TOPK_) {
    w_s[threadIdx.x] = weights[(size_t)c * TOPK_ + threadIdx.x];
    s_s[threadIdx.x] = shifts[threadIdx.x];
  }
  __syncthreads();
  for (int t = threadIdx.x; t < L_; t += 256) {
    float sum = 0.0f;
#pragma unroll
    for (int k = 0; k < TOPK_; ++k) {
      int idx = t + s_s[k];
      if (idx >= L_) idx -= L_;
      sum = fmaf(w_s[k], v_s[idx], sum);
    }
    Vc[(size_t)c * L_ + t] = sum;
  }
}

// ---------------------------------------------------------------------------
extern "C" void kernel_launch(void* const* d_in, const int* in_sizes, int n_in,
                              void* d_out, int out_size, void* d_ws, size_t ws_size,
                              hipStream_t stream) {
  const float* query = (const float*)d_in[0];
  const float* key   = (const float*)d_in[1];
  const float* value = (const float*)d_in[2];
  const float* Wq = (const float*)d_in[3];
  const float* bq = (const float*)d_in[4];
  const float* Wk = (const float*)d_in[5];
  const float* bk = (const float*)d_in[6];
  const float* Wv = (const float*)d_in[7];
  const float* bvp = (const float*)d_in[8];
  const float* Wo = (const float*)d_in[9];
  const float* bo = (const float*)d_in[10];
  float* out = (float*)d_out;
  char* ws = (char*)d_ws;

  auto al = [](size_t x) { return (x + 255) & ~(size_t)255; };
  size_t off = 0;
  const size_t tv_off = off; off = al(off + (size_t)CH_ * TOPK_ * 8);
  const size_t ti_off = off; off = al(off + (size_t)CH_ * TOPK_ * 4);
  const size_t w_off  = off; off = al(off + (size_t)CH_ * TOPK_ * 4);
  const size_t sh_off = off; off = al(off + (size_t)TOPK_ * 4);
  const size_t small_end = off;                       // ~5.3 MB

  const size_t QK1   = (size_t)D_ * L_ * 4;           // 6.29 MB f32, one batch
  const size_t PBQK  = al(2 * QK1);                   // ~12.6 MB per batch
  const size_t AGG_BYTES    = (size_t)CH_ * L_ * 4;   // 96 MB
  const size_t BOUNCE_BYTES = (size_t)D_ * L_ * 4;    // 6 MB

  int nb; bool bounce;
  if (ws_size >= small_end + AGG_BYTES + PBQK) {
    bounce = false;
    size_t n = (ws_size - small_end - AGG_BYTES) / PBQK;
    nb = (int)(n > 16 ? 16 : n);
  } else {
    bounce = true;
    size_t rem = (ws_size > small_end + BOUNCE_BYTES) ? (ws_size - small_end - BOUNCE_BYTES) : 0;
    size_t n = rem / PBQK; nb = (int)(n > 16 ? 16 : n);
    if (nb < 1) nb = 1;
  }

  double* top_vals = (double*)(ws + tv_off);
  int*    top_idx  = (int*)(ws + ti_off);
  float*  weights  = (float*)(ws + w_off);
  int*    shifts   = (int*)(ws + sh_off);

  float* VcAgg;
  float* bounce_buf = nullptr;
  size_t qk_off;
  if (!bounce) {
    VcAgg = (float*)(ws + small_end);
    qk_off = small_end + al(AGG_BYTES);
  } else {
    bounce_buf = (float*)(ws + small_end);
    qk_off = small_end + al(BOUNCE_BYTES);
    VcAgg = (float*)d_out;
  }
  float* Qc = (float*)(ws + qk_off);
  float* Kc = (float*)(ws + qk_off + al((size_t)nb * QK1));

  dim3 blk(256);
  const long bXS = (long)L_ * D_;   // batch stride of inputs / out
  const long cQS = (long)D_ * L_;   // batch stride of channel-major tensors

  for (int b0 = 0; b0 < B_; b0 += nb) {
    int nbb = (B_ - b0 < nb) ? (B_ - b0) : nb;
    dim3 g(L_ / 128, D_ / 128, nbb);
    proj_kernel<<<g, blk, 0, stream>>>(query + (size_t)b0 * L_ * D_, Wq, bq, Qc);
    proj_kernel<<<g, blk, 0, stream>>>(key   + (size_t)b0 * L_ * D_, Wk, bk, Kc);
    cand_refine_kernel<<<nbb * D_, blk, 0, stream>>>(Qc, Kc, top_vals, top_idx, b0 * D_);
  }
  shifts_kernel<<<TOPK_, blk, 0, stream>>>(top_idx, shifts);
  softmax_kernel<<<CH_ / 256, blk, 0, stream>>>(top_vals, weights);

  {
    dim3 gp(L_ / 128, D_ / 128, B_);
    gemm_mfma<3, false, false><<<gp, blk, 0, stream>>>(
        Wv, value, bvp, VcAgg, 0, bXS, cQS, L_);
  }
  agg_kernel<<<CH_, blk, 0, stream>>>(VcAgg, weights, shifts);

  if (!bounce) {
    dim3 go(D_ / 128, L_ / 128, B_);    // (4, 24, 16)
    gemm_mfma<3, true, true><<<go, blk, 0, stream>>>(
        VcAgg, Wo, bo, out, cQS, 0, bXS, D_);
  } else {
    for (int b = 0; b < B_; ++b) {
      hipMemcpyAsync(bounce_buf, VcAgg + (size_t)b * D_ * L_, BOUNCE_BYTES,
                     hipMemcpyDeviceToDevice, stream);
      dim3 go(D_ / 128, L_ / 128, 1);
      gemm_mfma<3, true, true><<<go, blk, 0, stream>>>(
          bounce_buf, Wo, bo, out + (size_t)b * L_ * D_, 0, 0, 0, D_);
    }
  }
  (void)in_sizes; (void)n_in; (void)out_size;
}

// Round 9
// 1675.686 us; speedup vs baseline: 3.5043x; 1.0136x over previous
//
#include <hip/hip_runtime.h>
#include <hip/hip_bf16.h>
#include <math.h>

#define B_ 16
#define L_ 3072
#define D_ 512
#define CH_ (B_ * D_)   // 8192 channels
#define TOPK_ 40
#define NCAND_ 64       // candidate slots per channel
#define CFLOOR_ 52      // candidate count floor
#define RFN_ 28         // candidates refined exactly in f64 (rounds 3/4 proved 24 suffices)

typedef unsigned short ushort_t;
typedef unsigned int uint_t;
typedef __attribute__((ext_vector_type(8))) short bh8;   // 8 bf16 (4 VGPRs)
typedef __attribute__((ext_vector_type(4))) float f4;    // 4 f32 acc
typedef __attribute__((ext_vector_type(4))) int i4;      // 16B vector

__device__ __forceinline__ uint_t cvt_pk_bf16(float a, float b) {
  uint_t r;
  asm("v_cvt_pk_bf16_f32 %0, %1, %2" : "=v"(r) : "v"(a), "v"(b));
  return r;  // lo ushort = bf16(a), hi ushort = bf16(b)
}

// LDS byte-address swizzles (involutions; preserve 16B alignment)
__device__ __forceinline__ int swzq(int b) { return b ^ (((b >> 7) & 3) << 4); }
__device__ __forceinline__ int swzk(int b) { return b ^ (((b >> 9) & 7) << 4); }

// ---------------------------------------------------------------------------
// f32-VALU projection GEMM, 128x128 tile, 8x8 per thread (SELECTION path).
// Per-output product order ascending j with fmaf chain -> bit-identical to
// the round-4/7 proven projection. LDS layout [kk][row] for b128 reads.
// ---------------------------------------------------------------------------
__global__ __launch_bounds__(256) void proj_kernel(const float* __restrict__ X,
                                                   const float* __restrict__ W,
                                                   const float* __restrict__ bias,
                                                   float* __restrict__ P) {
  __shared__ float Xs[32 * 132];
  __shared__ float Ws[32 * 132];
  const int t0 = blockIdx.x * 128;
  const int i0 = blockIdx.y * 128;
  const int b  = blockIdx.z;
  const int tid = threadIdx.x;
  const int tx = tid & 15, ty = tid >> 4;

  float acc[8][8];
#pragma unroll
  for (int r = 0; r < 8; ++r)
#pragma unroll
    for (int s = 0; s < 8; ++s) acc[r][s] = 0.0f;

  for (int j0 = 0; j0 < D_; j0 += 32) {
    {
      const int row = tid >> 1, jh = (tid & 1) * 16;
      const float* gx = X + ((size_t)b * L_ + t0 + row) * D_ + j0 + jh;
      const float* gw = W + (size_t)(i0 + row) * D_ + j0 + jh;
#pragma unroll
      for (int p = 0; p < 4; ++p) {
        float4 xv = *(const float4*)(gx + 4 * p);
        float4 wv = *(const float4*)(gw + 4 * p);
        int kk = jh + 4 * p;
        Xs[(kk + 0) * 132 + row] = xv.x;
        Xs[(kk + 1) * 132 + row] = xv.y;
        Xs[(kk + 2) * 132 + row] = xv.z;
        Xs[(kk + 3) * 132 + row] = xv.w;
        Ws[(kk + 0) * 132 + row] = wv.x;
        Ws[(kk + 1) * 132 + row] = wv.y;
        Ws[(kk + 2) * 132 + row] = wv.z;
        Ws[(kk + 3) * 132 + row] = wv.w;
      }
    }
    __syncthreads();
#pragma unroll 4
    for (int kk = 0; kk < 32; ++kk) {
      float a8[8], w8[8];
      *(float4*)&a8[0] = *(const float4*)&Xs[kk * 132 + 8 * ty];
      *(float4*)&a8[4] = *(const float4*)&Xs[kk * 132 + 8 * ty + 4];
      *(float4*)&w8[0] = *(const float4*)&Ws[kk * 132 + 8 * tx];
      *(float4*)&w8[4] = *(const float4*)&Ws[kk * 132 + 8 * tx + 4];
#pragma unroll
      for (int r = 0; r < 8; ++r)
#pragma unroll
        for (int s = 0; s < 8; ++s)
          acc[r][s] = fmaf(a8[r], w8[s], acc[r][s]);
    }
    __syncthreads();
  }
#pragma unroll
  for (int s = 0; s < 8; ++s) {
    const int i = i0 + 8 * tx + s;
    const float bia = bias[i];
    float* dst = P + (size_t)(b * D_ + i) * L_ + t0 + 8 * ty;
    float4 v0 = { acc[0][s] + bia, acc[1][s] + bia, acc[2][s] + bia, acc[3][s] + bia };
    float4 v1 = { acc[4][s] + bia, acc[5][s] + bia, acc[6][s] + bia, acc[7][s] + bia };
    *(float4*)dst = v0;
    *(float4*)(dst + 4) = v1;
  }
}

// ---------------------------------------------------------------------------
// MFMA GEMM, 128x128 tile, 4 waves — LINEAR path (V proj, out GEMM).
// NPASS=1 (plain bf16): round-4 PROVEN config for V/out (absmax floor).
// ---------------------------------------------------------------------------
template <int NPASS, int BK, int ST>
__device__ __forceinline__ void stage_rows(const float* __restrict__ g0,
                                           ushort_t* __restrict__ Hh,
                                           ushort_t* __restrict__ Hl,
                                           int tid) {
  const int row = tid >> 1;
  const int cb = (tid & 1) * (BK / 2);
  const float* g = g0 + (size_t)row * 512 + cb;
  ushort_t* lh = Hh + row * ST + cb;
  ushort_t* ll = Hl + row * ST + cb;
#pragma unroll
  for (int p = 0; p < BK / 8; ++p) {
    float4 v = *(const float4*)(g + 4 * p);
    uint_t h01 = cvt_pk_bf16(v.x, v.y);
    uint_t h23 = cvt_pk_bf16(v.z, v.w);
    *(uint2*)(lh + 4 * p) = make_uint2(h01, h23);
    if (NPASS == 3) {
      float x0 = __builtin_bit_cast(float, h01 << 16);
      float x1 = __builtin_bit_cast(float, h01 & 0xFFFF0000u);
      float x2 = __builtin_bit_cast(float, h23 << 16);
      float x3 = __builtin_bit_cast(float, h23 & 0xFFFF0000u);
      uint_t l01 = cvt_pk_bf16(v.x - x0, v.y - x1);
      uint_t l23 = cvt_pk_bf16(v.z - x2, v.w - x3);
      *(uint2*)(ll + 4 * p) = make_uint2(l01, l23);
    }
  }
}

template <int NPASS, bool ATR, bool BIAS_N>
__global__ __launch_bounds__(256) void gemm_mfma(const float* __restrict__ Ap,
                                                 const float* __restrict__ Bp,
                                                 const float* __restrict__ bias,
                                                 float* __restrict__ Cp,
                                                 long aBS, long bBS, long cBS,
                                                 int cld) {
  constexpr int BK = (NPASS == 3) ? 32 : 64;
  constexpr int ST = (NPASS == 3) ? 40 : 72;
  __shared__ ushort_t Ah[128 * ST];
  __shared__ ushort_t Bh[128 * ST];
  __shared__ ushort_t Al[(NPASS == 3) ? 128 * ST : 8];
  __shared__ ushort_t Bl[(NPASS == 3) ? 128 * ST : 8];

  const float* Asrc = Ap + (size_t)blockIdx.z * aBS;
  const float* Bsrc = Bp + (size_t)blockIdx.z * bBS;
  float* Cb = Cp + (size_t)blockIdx.z * cBS;
  const int n0 = blockIdx.x * 128, m0 = blockIdx.y * 128;
  const int tid = threadIdx.x;
  const int lane = tid & 63, w = tid >> 6;
  const int wr = w >> 1, wc = w & 1;
  const int lj = lane & 15, lg = lane >> 4;

  f4 acc[4][4];
#pragma unroll
  for (int fm = 0; fm < 4; ++fm)
#pragma unroll
    for (int fn = 0; fn < 4; ++fn) acc[fm][fn] = (f4){0.f, 0.f, 0.f, 0.f};

  for (int kc = 0; kc < 512; kc += BK) {
    if (!ATR) {
      stage_rows<NPASS, BK, ST>(Asrc + (size_t)m0 * 512 + kc, Ah, Al, tid);
    } else {
      constexpr int TPC = 256 / BK;
      constexpr int TC  = 128 / TPC;
      const int jl = tid / TPC, ts = tid % TPC;
      const float* g = Asrc + (size_t)(kc + jl) * L_ + m0 + ts * TC;
#pragma unroll
      for (int p = 0; p < TC / 4; ++p) {
        float4 v = *(const float4*)(g + 4 * p);
        uint_t h01 = cvt_pk_bf16(v.x, v.y);
        uint_t h23 = cvt_pk_bf16(v.z, v.w);
        int t = ts * TC + 4 * p;
        Ah[(t + 0) * ST + jl] = (ushort_t)(h01 & 0xFFFFu);
        Ah[(t + 1) * ST + jl] = (ushort_t)(h01 >> 16);
        Ah[(t + 2) * ST + jl] = (ushort_t)(h23 & 0xFFFFu);
        Ah[(t + 3) * ST + jl] = (ushort_t)(h23 >> 16);
        if (NPASS == 3) {
          float x0 = __builtin_bit_cast(float, h01 << 16);
          float x1 = __builtin_bit_cast(float, h01 & 0xFFFF0000u);
          float x2 = __builtin_bit_cast(float, h23 << 16);
          float x3 = __builtin_bit_cast(float, h23 & 0xFFFF0000u);
          uint_t l01 = cvt_pk_bf16(v.x - x0, v.y - x1);
          uint_t l23 = cvt_pk_bf16(v.z - x2, v.w - x3);
          Al[(t + 0) * ST + jl] = (ushort_t)(l01 & 0xFFFFu);
          Al[(t + 1) * ST + jl] = (ushort_t)(l01 >> 16);
          Al[(t + 2) * ST + jl] = (ushort_t)(l23 & 0xFFFFu);
          Al[(t + 3) * ST + jl] = (ushort_t)(l23 >> 16);
        }
      }
    }
    stage_rows<NPASS, BK, ST>(Bsrc + (size_t)n0 * 512 + kc, Bh, Bl, tid);
    __syncthreads();

#pragma unroll
    for (int ks = 0; ks < BK / 32; ++ks) {
      const int kk = ks * 32 + 8 * lg;
      bh8 af[4], bf[4];
#pragma unroll
      for (int f = 0; f < 4; ++f)
        af[f] = *(const bh8*)&Ah[(64 * wr + 16 * f + lj) * ST + kk];
#pragma unroll
      for (int f = 0; f < 4; ++f)
        bf[f] = *(const bh8*)&Bh[(64 * wc + 16 * f + lj) * ST + kk];
#pragma unroll
      for (int fm = 0; fm < 4; ++fm)
#pragma unroll
        for (int fn = 0; fn < 4; ++fn)
          acc[fm][fn] = __builtin_amdgcn_mfma_f32_16x16x32_bf16(af[fm], bf[fn],
                                                                acc[fm][fn], 0, 0, 0);
      if (NPASS == 3) {
        bh8 bl_[4];
#pragma unroll
        for (int f = 0; f < 4; ++f)
          bl_[f] = *(const bh8*)&Bl[(64 * wc + 16 * f + lj) * ST + kk];
#pragma unroll
        for (int fm = 0; fm < 4; ++fm)
#pragma unroll
          for (int fn = 0; fn < 4; ++fn)
            acc[fm][fn] = __builtin_amdgcn_mfma_f32_16x16x32_bf16(af[fm], bl_[fn],
                                                                  acc[fm][fn], 0, 0, 0);
        bh8 al_[4];
#pragma unroll
        for (int f = 0; f < 4; ++f)
          al_[f] = *(const bh8*)&Al[(64 * wr + 16 * f + lj) * ST + kk];
#pragma unroll
        for (int fm = 0; fm < 4; ++fm)
#pragma unroll
          for (int fn = 0; fn < 4; ++fn)
            acc[fm][fn] = __builtin_amdgcn_mfma_f32_16x16x32_bf16(al_[fm], bf[fn],
                                                                  acc[fm][fn], 0, 0, 0);
      }
    }
    __syncthreads();
  }

#pragma unroll
  for (int fm = 0; fm < 4; ++fm) {
    const int mrow = m0 + 64 * wr + 16 * fm + 4 * lg;
#pragma unroll
    for (int fn = 0; fn < 4; ++fn) {
      const int ncol = n0 + 64 * wc + 16 * fn + lj;
      const float bn = BIAS_N ? bias[ncol] : 0.0f;
#pragma unroll
      for (int r = 0; r < 4; ++r) {
        float val = acc[fm][fn][r] + (BIAS_N ? bn : bias[mrow + r]);
        Cb[(size_t)(mrow + r) * cld + ncol] = val;
      }
    }
  }
}

// ---------------------------------------------------------------------------
// FUSED MFMA autocorrelation + candidate selection + f64 refinement + top-40.
// q-swizzle hoisted: swzq(a + 512m) = swzq(a) + 512m (512-steps never touch
// bits <=8), so 16 swizzled bases are precomputed and the inner loop adds a
// 512-multiple — bit-identical addresses, ~10 fewer VALU/iter.
// Phase B (f32 top-40 sort, wave 0) overlaps phase-C f32 LDS staging (waves
// 1-3). Phase C refines only top-RFN_=28 (rounds 3/4 proved 24 suffices).
// ---------------------------------------------------------------------------
template <int P>
__device__ __forceinline__ void ac_kloop(const char* __restrict__ qb,
                                         const char* __restrict__ kb,
                                         int abyte, int bbyte, int jvalid,
                                         f4 acc[4]) {
  int aswz[16];
#pragma unroll
  for (int u = 0; u < 8; ++u) {
    aswz[2 * u]     = swzq(abyte + 64 * u);
    aswz[2 * u + 1] = swzq(abyte + 64 * u + 16);
  }
  for (int t512 = 0; t512 < 2 * L_; t512 += 512) {
#pragma unroll
    for (int u = 0; u < 8; ++u) {
      i4 w0 = *(const i4*)(qb + t512 + aswz[2 * u]);
      i4 w1 = *(const i4*)(qb + t512 + aswz[2 * u + 1]);
      uint_t w[8] = { (uint_t)w0.x, (uint_t)w0.y, (uint_t)w0.z, (uint_t)w0.w,
                      (uint_t)w1.x, (uint_t)w1.y, (uint_t)w1.z, (uint_t)w1.w };
      const int bb = jvalid ? swzk(bbyte + t512 + 64 * u) : swzk(11776);
      bh8 Bf = *(const bh8*)(kb + bb);
#pragma unroll
      for (int e = 0; e < 4; ++e) {
        const int ro = (e >> 1) + 2 * P;
        const int sh = (e & 1) * 16;
        uint_t a0v = (uint_t)((((unsigned long long)w[ro + 1] << 32) | w[ro + 0]) >> sh);
        uint_t a1v = (uint_t)((((unsigned long long)w[ro + 2] << 32) | w[ro + 1]) >> sh);
        uint_t a2v = (uint_t)((((unsigned long long)w[ro + 3] << 32) | w[ro + 2]) >> sh);
        uint_t a3v = (uint_t)((((unsigned long long)w[ro + 4] << 32) | w[ro + 3]) >> sh);
        i4 ai = { (int)a0v, (int)a1v, (int)a2v, (int)a3v };
        bh8 Af = __builtin_bit_cast(bh8, ai);
        acc[e] = __builtin_amdgcn_mfma_f32_16x16x32_bf16(Af, Bf, acc[e], 0, 0, 0);
      }
    }
  }
}

__global__ __launch_bounds__(256) void cand_refine_kernel(const float* __restrict__ Q,
                                                          const float* __restrict__ K,
                                                          double* __restrict__ top_vals,
                                                          int* __restrict__ top_idx,
                                                          int c0) {
  // phase A: [0,6912) q bf16 (swz) | [6912,18816) k bf16 (swz) | [18816,31104) ac f32
  // phase C: [0,12288) q f32 | [12288,24576) k f32   (A regions dead)
  __shared__ __align__(16) char smem[31104];
  __shared__ float redf[8];
  __shared__ int   redi[4];
  __shared__ int   cnt_s;
  __shared__ float cv[NCAND_];
  __shared__ int   ci[NCAND_];
  __shared__ float sv[TOPK_];
  __shared__ int   si[TOPK_];
  __shared__ double refv[RFN_];
  char* kbase = smem + 6912;
  float* ac_s = (float*)(smem + 18816);
  const int c = blockIdx.x;
  const int tid = threadIdx.x;
  const float* Qp = Q + (size_t)c * L_;
  const float* Kp = K + (size_t)c * L_;

  // ---- Phase A staging: f32 -> bf16 (cvt_pk), swizzled stores ----
  for (int x8 = tid; x8 < 432; x8 += 256) {
    int x = x8 * 8; int src = x - (x >= L_ ? L_ : 0);
    float4 f0 = *(const float4*)(Qp + src);
    float4 f1 = *(const float4*)(Qp + src + 4);
    i4 pk = { (int)cvt_pk_bf16(f0.x, f0.y), (int)cvt_pk_bf16(f0.z, f0.w),
              (int)cvt_pk_bf16(f1.x, f1.y), (int)cvt_pk_bf16(f1.z, f1.w) };
    *(i4*)(smem + swzq(16 * x8)) = pk;
  }
  for (int x8 = tid; x8 < 736; x8 += 256) {
    int x = x8 * 8; int src = x - 2816 + (x < 2816 ? L_ : 0);
    float4 f0 = *(const float4*)(Kp + src);
    float4 f1 = *(const float4*)(Kp + src + 4);
    i4 pk = { (int)cvt_pk_bf16(f0.x, f0.y), (int)cvt_pk_bf16(f0.z, f0.w),
              (int)cvt_pk_bf16(f1.x, f1.y), (int)cvt_pk_bf16(f1.z, f1.w) };
    *(i4*)(kbase + swzk(16 * x8)) = pk;
  }
  if (tid == 0) *(i4*)(kbase + swzk(11776)) = (i4){0, 0, 0, 0};  // zero slot
  __syncthreads();

  const int lane = tid & 63, fg = tid >> 6;
  const int lg = lane >> 4, lj = lane & 15;
  const int abyte = 16 * lg + 32 * lj + 16 * (fg >> 1);
  const int jvalid = (lj < 12) ? 1 : 0;
  const int bbyte = 5632 + 16 * lg - 512 * lj;

  f4 acc[4];
#pragma unroll
  for (int e = 0; e < 4; ++e) acc[e] = (f4){0.f, 0.f, 0.f, 0.f};

  if (fg & 1) ac_kloop<1>(smem, kbase, abyte, jvalid ? bbyte : 0, jvalid, acc);
  else        ac_kloop<0>(smem, kbase, abyte, jvalid ? bbyte : 0, jvalid, acc);

  if (jvalid) {
#pragma unroll
    for (int e = 0; e < 4; ++e) {
      int f = 4 * fg + e;
#pragma unroll
      for (int r = 0; r < 4; ++r) {
        int g = f + 16 * (4 * lg + r);      // fine lag in [0,256)
        ac_s[lj + 12 * g] = acc[e][r];      // tau = g + 256*lj
      }
    }
  }
  __syncthreads();

  float v[12];
#pragma unroll
  for (int it = 0; it < 12; ++it) v[it] = ac_s[tid + 256 * it];

  // block max
  float lm = v[0];
#pragma unroll
  for (int it = 1; it < 12; ++it) lm = fmaxf(lm, v[it]);
  for (int o = 32; o; o >>= 1) lm = fmaxf(lm, __shfl_down(lm, o));
  if ((tid & 63) == 0) redf[tid >> 6] = lm;
  __syncthreads();
  if (tid == 0) redf[4] = fmaxf(fmaxf(redf[0], redf[1]), fmaxf(redf[2], redf[3]));
  __syncthreads();
  const float Tmax = redf[4];

  auto bcount = [&](float T) -> int {
    int lc = 0;
#pragma unroll
    for (int it = 0; it < 12; ++it) lc += (v[it] > T) ? 1 : 0;
    for (int o = 32; o; o >>= 1) lc += __shfl_down(lc, o);
    __syncthreads();
    if ((tid & 63) == 0) redi[tid >> 6] = lc;
    __syncthreads();
    return redi[0] + redi[1] + redi[2] + redi[3];
  };

  float lo = Tmax - 128.0f;
  int cl = bcount(lo);
  for (int wd = 1; wd <= 5 && cl < CFLOOR_; ++wd) {
    lo = Tmax - 128.0f * (float)(1 << wd); cl = bcount(lo);
  }
  float hi = Tmax, T = lo;
  int cT = cl;
  for (int i = 0; i < 26 && cT > NCAND_; ++i) {
    float mid = 0.5f * (lo + hi);
    int cm = bcount(mid);
    if (cm >= CFLOOR_) { lo = mid; T = mid; cT = cm; } else hi = mid;
  }

  if (tid == 0) cnt_s = 0;
  __syncthreads();
#pragma unroll
  for (int it = 0; it < 12; ++it) {
    if (v[it] > T) {
      int pos = atomicAdd(&cnt_s, 1);
      if (pos < NCAND_) {
        int m = tid + 256 * it;
        int g = m / 12, j = m - 12 * g;
        cv[pos] = v[it];
        ci[pos] = g + 256 * j;
      }
    }
  }
  __syncthreads();
  const int cnt = cnt_s < NCAND_ ? cnt_s : NCAND_;

  // ---- Phase B (wave 0: f32 top-40 sort) || C-staging (waves 1-3) ----
  float* qf = (float*)smem;
  float* kf = (float*)(smem + 12288);
  if (tid >= 64) {
    for (int i = (tid - 64) * 4; i < L_; i += 768) {
      *(float4*)&qf[i] = *(const float4*)(Qp + i);
      *(float4*)&kf[i] = *(const float4*)(Kp + i);
    }
  } else {
    float mv = (tid < cnt) ? cv[tid] : -1e30f;
    int   mi = (tid < cnt) ? ci[tid] : (1 << 30);
    int used = 0;
    for (int r = 0; r < TOPK_; ++r) {
      float bv = used ? -1e30f : mv;
      int   bi = used ? (1 << 30) : mi;
      int   bl = tid;
      for (int o = 32; o; o >>= 1) {
        float ov = __shfl_down(bv, o);
        int   oi = __shfl_down(bi, o);
        int   ol = __shfl_down(bl, o);
        if (ov > bv || (ov == bv && oi < bi)) { bv = ov; bi = oi; bl = ol; }
      }
      bv = __shfl(bv, 0); bi = __shfl(bi, 0); bl = __shfl(bl, 0);
      if (tid == 0) { sv[r] = bv; si[r] = (bi < L_) ? bi : 0; }
      if (tid == bl) used = 1;
    }
  }
  __syncthreads();

  // ---- Phase C: exact f64 ac for top-RFN_, one WAVE per candidate, LDS ----
  const int R = cnt < RFN_ ? cnt : RFN_;
  for (int r = fg; r < R; r += 4) {
    const int tau = si[r];
    double a = 0.0;
#pragma unroll 4
    for (int u = 0; u < 48; ++u) {
      int t = lane + 64 * u;
      int qi = t + tau; qi -= (qi >= L_) ? L_ : 0;
      a = fma((double)qf[qi], (double)kf[t], a);
    }
#pragma unroll
    for (int o = 32; o; o >>= 1) a += __shfl_down(a, o);
    if (lane == 0) refv[r] = a;
  }
  __syncthreads();

  // ---- Phase D: wave 0 sorts refined (f64 desc, idx asc) -> ranks 0..R-1;
  //      ranks R..39 from f32 order (rounds 3/4 proven harmless) ----
  double* out_v = top_vals + (size_t)(c0 + c) * TOPK_;
  int*    out_i = top_idx  + (size_t)(c0 + c) * TOPK_;
  if (tid < 64) {
    double dv = (tid < R) ? refv[tid] : -1e300;
    int    di = (tid < R) ? si[tid]   : (1 << 30);
    int used = 0;
    for (int r = 0; r < R; ++r) {
      double bv = used ? -1e300 : dv;
      int    bi = used ? (1 << 30) : di;
      int    bl = tid;
      for (int o = 32; o; o >>= 1) {
        double ov = __shfl_down(bv, o);
        int    oi = __shfl_down(bi, o);
        int    ol = __shfl_down(bl, o);
        if (ov > bv || (ov == bv && oi < bi)) { bv = ov; bi = oi; bl = ol; }
      }
      bv = __shfl(bv, 0); bi = __shfl(bi, 0); bl = __shfl(bl, 0);
      if (tid == 0) { out_v[r] = bv; out_i[r] = (bi < L_) ? bi : 0; }
      if (tid == bl) used = 1;
    }
    if (tid >= R && tid < TOPK_) {
      out_v[tid] = (double)sv[tid];
      out_i[tid] = si[tid];
    }
  }
}

// ---------------------------------------------------------------------------
__global__ __launch_bounds__(256) void shifts_kernel(const int* __restrict__ top_idx,
                                                     int* __restrict__ shifts) {
  const int k = blockIdx.x;
  __shared__ double sred[256];
  double s = 0.0;
  for (int c = threadIdx.x; c < CH_; c += 256) s += (double)top_idx[(size_t)c * TOPK_ + k];
  sred[threadIdx.x] = s;
  __syncthreads();
  for (int o = 128; o > 0; o >>= 1) {
    if (threadIdx.x < o) sred[threadIdx.x] += sred[threadIdx.x + o];
    __syncthreads();
  }
  if (threadIdx.x == 0) shifts[k] = (int)((float)(sred[0] / (double)CH_));
}

__global__ __launch_bounds__(256) void softmax_kernel(const double* __restrict__ top_vals,
                                                      float* __restrict__ weights) {
  const int c = blockIdx.x * 256 + threadIdx.x;
  const double* v = top_vals + (size_t)c * TOPK_;
  double m = v[0];
  for (int k = 1; k < TOPK_; ++k) m = fmax(m, v[k]);
  double sum = 0.0;
  for (int k = 0; k < TOPK_; ++k) sum += exp(v[k] - m);
  double inv = 1.0 / sum;
  for (int k = 0; k < TOPK_; ++k)
    weights[(size_t)c * TOPK_ + k] = (float)(exp(v[k] - m) * inv);
}

__global__ __launch_bounds__(256) void agg_kernel(float* __restrict__ Vc,
                                                  const float* __restrict__ weights,
                                                  const int* __restrict__ shifts) {
  const int c = blockIdx.x;
  __shared__ float v_s[L_];
  __shared__ float w_s[TOPK_];
  __shared__ int   s_s[TOPK_];
  for (int i = threadIdx.x; i < L_; i += 256) v_s[i] = Vc[(size_t)c * L_ + i];
  if (threadIdx.x < TOPK_) {
    w_s[threadIdx.x] = weights[(size_t)c * TOPK_ + threadIdx.x];
    s_s[threadIdx.x] = shifts[threadIdx.x];
  }
  __syncthreads();
  for (int t = threadIdx.x; t < L_; t += 256) {
    float sum = 0.0f;
#pragma unroll
    for (int k = 0; k < TOPK_; ++k) {
      int idx = t + s_s[k];
      if (idx >= L_) idx -= L_;
      sum = fmaf(w_s[k], v_s[idx], sum);
    }
    Vc[(size_t)c * L_ + t] = sum;
  }
}

// ---------------------------------------------------------------------------
extern "C" void kernel_launch(void* const* d_in, const int* in_sizes, int n_in,
                              void* d_out, int out_size, void* d_ws, size_t ws_size,
                              hipStream_t stream) {
  const float* query = (const float*)d_in[0];
  const float* key   = (const float*)d_in[1];
  const float* value = (const float*)d_in[2];
  const float* Wq = (const float*)d_in[3];
  const float* bq = (const float*)d_in[4];
  const float* Wk = (const float*)d_in[5];
  const float* bk = (const float*)d_in[6];
  const float* Wv = (const float*)d_in[7];
  const float* bvp = (const float*)d_in[8];
  const float* Wo = (const float*)d_in[9];
  const float* bo = (const float*)d_in[10];
  float* out = (float*)d_out;
  char* ws = (char*)d_ws;

  auto al = [](size_t x) { return (x + 255) & ~(size_t)255; };
  size_t off = 0;
  const size_t tv_off = off; off = al(off + (size_t)CH_ * TOPK_ * 8);
  const size_t ti_off = off; off = al(off + (size_t)CH_ * TOPK_ * 4);
  const size_t w_off  = off; off = al(off + (size_t)CH_ * TOPK_ * 4);
  const size_t sh_off = off; off = al(off + (size_t)TOPK_ * 4);
  const size_t small_end = off;                       // ~5.3 MB

  const size_t QK1   = (size_t)D_ * L_ * 4;           // 6.29 MB f32, one batch
  const size_t PBQK  = al(2 * QK1);                   // ~12.6 MB per batch
  const size_t AGG_BYTES    = (size_t)CH_ * L_ * 4;   // 96 MB
  const size_t BOUNCE_BYTES = (size_t)D_ * L_ * 4;    // 6 MB

  int nb; bool bounce;
  if (ws_size >= small_end + AGG_BYTES + PBQK) {
    bounce = false;
    size_t n = (ws_size - small_end - AGG_BYTES) / PBQK;
    nb = (int)(n > 16 ? 16 : n);
  } else {
    bounce = true;
    size_t rem = (ws_size > small_end + BOUNCE_BYTES) ? (ws_size - small_end - BOUNCE_BYTES) : 0;
    size_t n = rem / PBQK; nb = (int)(n > 16 ? 16 : n);
    if (nb < 1) nb = 1;
  }

  double* top_vals = (double*)(ws + tv_off);
  int*    top_idx  = (int*)(ws + ti_off);
  float*  weights  = (float*)(ws + w_off);
  int*    shifts   = (int*)(ws + sh_off);

  float* VcAgg;
  float* bounce_buf = nullptr;
  size_t qk_off;
  if (!bounce) {
    VcAgg = (float*)(ws + small_end);
    qk_off = small_end + al(AGG_BYTES);
  } else {
    bounce_buf = (float*)(ws + small_end);
    qk_off = small_end + al(BOUNCE_BYTES);
    VcAgg = (float*)d_out;
  }
  float* Qc = (float*)(ws + qk_off);
  float* Kc = (float*)(ws + qk_off + al((size_t)nb * QK1));

  dim3 blk(256);
  const long bXS = (long)L_ * D_;   // batch stride of inputs / out
  const long cQS = (long)D_ * L_;   // batch stride of channel-major tensors

  for (int b0 = 0; b0 < B_; b0 += nb) {
    int nbb = (B_ - b0 < nb) ? (B_ - b0) : nb;
    dim3 g(L_ / 128, D_ / 128, nbb);
    proj_kernel<<<g, blk, 0, stream>>>(query + (size_t)b0 * L_ * D_, Wq, bq, Qc);
    proj_kernel<<<g, blk, 0, stream>>>(key   + (size_t)b0 * L_ * D_, Wk, bk, Kc);
    cand_refine_kernel<<<nbb * D_, blk, 0, stream>>>(Qc, Kc, top_vals, top_idx, b0 * D_);
  }
  shifts_kernel<<<TOPK_, blk, 0, stream>>>(top_idx, shifts);
  softmax_kernel<<<CH_ / 256, blk, 0, stream>>>(top_vals, weights);

  {
    dim3 gp(L_ / 128, D_ / 128, B_);
    gemm_mfma<1, false, false><<<gp, blk, 0, stream>>>(
        Wv, value, bvp, VcAgg, 0, bXS, cQS, L_);
  }
  agg_kernel<<<CH_, blk, 0, stream>>>(VcAgg, weights, shifts);

  if (!bounce) {
    dim3 go(D_ / 128, L_ / 128, B_);    // (4, 24, 16)
    gemm_mfma<1, true, true><<<go, blk, 0, stream>>>(
        VcAgg, Wo, bo, out, cQS, 0, bXS, D_);
  } else {
    for (int b = 0; b < B_; ++b) {
      hipMemcpyAsync(bounce_buf, VcAgg + (size_t)b * D_ * L_, BOUNCE_BYTES,
                     hipMemcpyDeviceToDevice, stream);
      dim3 go(D_ / 128, L_ / 128, 1);
      gemm_mfma<1, true, true><<<go, blk, 0, stream>>>(
          bounce_buf, Wo, bo, out + (size_t)b * L_ * D_, 0, 0, 0, D_);
    }
  }
  (void)in_sizes; (void)n_in; (void)out_size;
}

// Round 11
// 1626.213 us; speedup vs baseline: 3.6109x; 1.0304x over previous
//
#include <hip/hip_runtime.h>
#include <hip/hip_bf16.h>
#include <math.h>

#define B_ 16
#define L_ 3072
#define D_ 512
#define CH_ (B_ * D_)   // 8192 channels
#define TOPK_ 40
#define NCAND_ 64       // candidate slots per channel
#define CFLOOR_ 52      // candidate count floor
#define RFN_ 28         // candidates refined exactly in f64

typedef unsigned short ushort_t;
typedef unsigned int uint_t;
typedef __attribute__((ext_vector_type(8))) short bh8;   // 8 bf16 (4 VGPRs)
typedef __attribute__((ext_vector_type(4))) float f4;    // 4 f32 acc
typedef __attribute__((ext_vector_type(4))) int i4;      // 16B vector

__device__ __forceinline__ uint_t cvt_pk_bf16(float a, float b) {
  uint_t r;
  asm("v_cvt_pk_bf16_f32 %0, %1, %2" : "=v"(r) : "v"(a), "v"(b));
  return r;  // lo ushort = bf16(a), hi ushort = bf16(b)
}

// LDS byte-address swizzles (involutions; preserve 16B alignment)
__device__ __forceinline__ int swzq(int b) { return b ^ (((b >> 7) & 3) << 4); }
__device__ __forceinline__ int swzk(int b) { return b ^ (((b >> 9) & 7) << 4); }

// ---------------------------------------------------------------------------
// f32-VALU projection GEMM, 128x128 tile, 8x8 per thread (SELECTION path).
// Per-output product order ascending j with fmaf chain -> BIT-IDENTICAL
// Qc/Kc to rounds 4/7/9 (only physical LDS placement changed).
// Layout idx = 140*kk + row + 4*(row>>5): offset range [0,139] < 140 ->
// injective (ROUND-10 BUG: stride 136 < 139 collided rows 124-127 with the
// next slab's rows 0-3). b128 reads: each bank-start has 2 lanes -> 2-way
// conflict (free).
// ---------------------------------------------------------------------------
__device__ __forceinline__ int xidx(int kk, int row) {
  return kk * 140 + row + ((row >> 5) << 2);
}

__global__ __launch_bounds__(256) void proj_kernel(const float* __restrict__ X,
                                                   const float* __restrict__ W,
                                                   const float* __restrict__ bias,
                                                   float* __restrict__ P) {
  __shared__ float Xs[4480];
  __shared__ float Ws[4480];
  const int t0 = blockIdx.x * 128;
  const int i0 = blockIdx.y * 128;
  const int b  = blockIdx.z;
  const int tid = threadIdx.x;
  const int tx = tid & 15, ty = tid >> 4;

  float acc[8][8];
#pragma unroll
  for (int r = 0; r < 8; ++r)
#pragma unroll
    for (int s = 0; s < 8; ++s) acc[r][s] = 0.0f;

  for (int j0 = 0; j0 < D_; j0 += 32) {
    {
      const int row = tid >> 1, jh = (tid & 1) * 16;
      const float* gx = X + ((size_t)b * L_ + t0 + row) * D_ + j0 + jh;
      const float* gw = W + (size_t)(i0 + row) * D_ + j0 + jh;
#pragma unroll
      for (int p = 0; p < 4; ++p) {
        float4 xv = *(const float4*)(gx + 4 * p);
        float4 wv = *(const float4*)(gw + 4 * p);
        int kk = jh + 4 * p;
        Xs[xidx(kk + 0, row)] = xv.x;
        Xs[xidx(kk + 1, row)] = xv.y;
        Xs[xidx(kk + 2, row)] = xv.z;
        Xs[xidx(kk + 3, row)] = xv.w;
        Ws[xidx(kk + 0, row)] = wv.x;
        Ws[xidx(kk + 1, row)] = wv.y;
        Ws[xidx(kk + 2, row)] = wv.z;
        Ws[xidx(kk + 3, row)] = wv.w;
      }
    }
    __syncthreads();
#pragma unroll 4
    for (int kk = 0; kk < 32; ++kk) {
      float a8[8], w8[8];
      *(float4*)&a8[0] = *(const float4*)&Xs[xidx(kk, 8 * ty)];
      *(float4*)&a8[4] = *(const float4*)&Xs[xidx(kk, 8 * ty) + 4];
      *(float4*)&w8[0] = *(const float4*)&Ws[xidx(kk, 8 * tx)];
      *(float4*)&w8[4] = *(const float4*)&Ws[xidx(kk, 8 * tx) + 4];
#pragma unroll
      for (int r = 0; r < 8; ++r)
#pragma unroll
        for (int s = 0; s < 8; ++s)
          acc[r][s] = fmaf(a8[r], w8[s], acc[r][s]);
    }
    __syncthreads();
  }
#pragma unroll
  for (int s = 0; s < 8; ++s) {
    const int i = i0 + 8 * tx + s;
    const float bia = bias[i];
    float* dst = P + (size_t)(b * D_ + i) * L_ + t0 + 8 * ty;
    float4 v0 = { acc[0][s] + bia, acc[1][s] + bia, acc[2][s] + bia, acc[3][s] + bia };
    float4 v1 = { acc[4][s] + bia, acc[5][s] + bia, acc[6][s] + bia, acc[7][s] + bia };
    *(float4*)dst = v0;
    *(float4*)(dst + 4) = v1;
  }
}

// ---------------------------------------------------------------------------
// MFMA GEMM, 128x128 tile, 4 waves — LINEAR path (V proj, out GEMM).
// NPASS=1 (plain bf16): round-4/8 PROVEN config (absmax floor).
// ---------------------------------------------------------------------------
template <int NPASS, int BK, int ST>
__device__ __forceinline__ void stage_rows(const float* __restrict__ g0,
                                           ushort_t* __restrict__ Hh,
                                           ushort_t* __restrict__ Hl,
                                           int tid) {
  const int row = tid >> 1;
  const int cb = (tid & 1) * (BK / 2);
  const float* g = g0 + (size_t)row * 512 + cb;
  ushort_t* lh = Hh + row * ST + cb;
  ushort_t* ll = Hl + row * ST + cb;
#pragma unroll
  for (int p = 0; p < BK / 8; ++p) {
    float4 v = *(const float4*)(g + 4 * p);
    uint_t h01 = cvt_pk_bf16(v.x, v.y);
    uint_t h23 = cvt_pk_bf16(v.z, v.w);
    *(uint2*)(lh + 4 * p) = make_uint2(h01, h23);
    if (NPASS == 3) {
      float x0 = __builtin_bit_cast(float, h01 << 16);
      float x1 = __builtin_bit_cast(float, h01 & 0xFFFF0000u);
      float x2 = __builtin_bit_cast(float, h23 << 16);
      float x3 = __builtin_bit_cast(float, h23 & 0xFFFF0000u);
      uint_t l01 = cvt_pk_bf16(v.x - x0, v.y - x1);
      uint_t l23 = cvt_pk_bf16(v.z - x2, v.w - x3);
      *(uint2*)(ll + 4 * p) = make_uint2(l01, l23);
    }
  }
}

template <int NPASS, bool ATR, bool BIAS_N>
__global__ __launch_bounds__(256) void gemm_mfma(const float* __restrict__ Ap,
                                                 const float* __restrict__ Bp,
                                                 const float* __restrict__ bias,
                                                 float* __restrict__ Cp,
                                                 long aBS, long bBS, long cBS,
                                                 int cld) {
  constexpr int BK = (NPASS == 3) ? 32 : 64;
  constexpr int ST = (NPASS == 3) ? 40 : 72;
  __shared__ ushort_t Ah[128 * ST];
  __shared__ ushort_t Bh[128 * ST];
  __shared__ ushort_t Al[(NPASS == 3) ? 128 * ST : 8];
  __shared__ ushort_t Bl[(NPASS == 3) ? 128 * ST : 8];

  const float* Asrc = Ap + (size_t)blockIdx.z * aBS;
  const float* Bsrc = Bp + (size_t)blockIdx.z * bBS;
  float* Cb = Cp + (size_t)blockIdx.z * cBS;
  const int n0 = blockIdx.x * 128, m0 = blockIdx.y * 128;
  const int tid = threadIdx.x;
  const int lane = tid & 63, w = tid >> 6;
  const int wr = w >> 1, wc = w & 1;
  const int lj = lane & 15, lg = lane >> 4;

  f4 acc[4][4];
#pragma unroll
  for (int fm = 0; fm < 4; ++fm)
#pragma unroll
    for (int fn = 0; fn < 4; ++fn) acc[fm][fn] = (f4){0.f, 0.f, 0.f, 0.f};

  for (int kc = 0; kc < 512; kc += BK) {
    if (!ATR) {
      stage_rows<NPASS, BK, ST>(Asrc + (size_t)m0 * 512 + kc, Ah, Al, tid);
    } else {
      constexpr int TPC = 256 / BK;
      constexpr int TC  = 128 / TPC;
      const int jl = tid / TPC, ts = tid % TPC;
      const float* g = Asrc + (size_t)(kc + jl) * L_ + m0 + ts * TC;
#pragma unroll
      for (int p = 0; p < TC / 4; ++p) {
        float4 v = *(const float4*)(g + 4 * p);
        uint_t h01 = cvt_pk_bf16(v.x, v.y);
        uint_t h23 = cvt_pk_bf16(v.z, v.w);
        int t = ts * TC + 4 * p;
        Ah[(t + 0) * ST + jl] = (ushort_t)(h01 & 0xFFFFu);
        Ah[(t + 1) * ST + jl] = (ushort_t)(h01 >> 16);
        Ah[(t + 2) * ST + jl] = (ushort_t)(h23 & 0xFFFFu);
        Ah[(t + 3) * ST + jl] = (ushort_t)(h23 >> 16);
        if (NPASS == 3) {
          float x0 = __builtin_bit_cast(float, h01 << 16);
          float x1 = __builtin_bit_cast(float, h01 & 0xFFFF0000u);
          float x2 = __builtin_bit_cast(float, h23 << 16);
          float x3 = __builtin_bit_cast(float, h23 & 0xFFFF0000u);
          uint_t l01 = cvt_pk_bf16(v.x - x0, v.y - x1);
          uint_t l23 = cvt_pk_bf16(v.z - x2, v.w - x3);
          Al[(t + 0) * ST + jl] = (ushort_t)(l01 & 0xFFFFu);
          Al[(t + 1) * ST + jl] = (ushort_t)(l01 >> 16);
          Al[(t + 2) * ST + jl] = (ushort_t)(l23 & 0xFFFFu);
          Al[(t + 3) * ST + jl] = (ushort_t)(l23 >> 16);
        }
      }
    }
    stage_rows<NPASS, BK, ST>(Bsrc + (size_t)n0 * 512 + kc, Bh, Bl, tid);
    __syncthreads();

#pragma unroll
    for (int ks = 0; ks < BK / 32; ++ks) {
      const int kk = ks * 32 + 8 * lg;
      bh8 af[4], bf[4];
#pragma unroll
      for (int f = 0; f < 4; ++f)
        af[f] = *(const bh8*)&Ah[(64 * wr + 16 * f + lj) * ST + kk];
#pragma unroll
      for (int f = 0; f < 4; ++f)
        bf[f] = *(const bh8*)&Bh[(64 * wc + 16 * f + lj) * ST + kk];
#pragma unroll
      for (int fm = 0; fm < 4; ++fm)
#pragma unroll
        for (int fn = 0; fn < 4; ++fn)
          acc[fm][fn] = __builtin_amdgcn_mfma_f32_16x16x32_bf16(af[fm], bf[fn],
                                                                acc[fm][fn], 0, 0, 0);
      if (NPASS == 3) {
        bh8 bl_[4];
#pragma unroll
        for (int f = 0; f < 4; ++f)
          bl_[f] = *(const bh8*)&Bl[(64 * wc + 16 * f + lj) * ST + kk];
#pragma unroll
        for (int fm = 0; fm < 4; ++fm)
#pragma unroll
          for (int fn = 0; fn < 4; ++fn)
            acc[fm][fn] = __builtin_amdgcn_mfma_f32_16x16x32_bf16(af[fm], bl_[fn],
                                                                  acc[fm][fn], 0, 0, 0);
        bh8 al_[4];
#pragma unroll
        for (int f = 0; f < 4; ++f)
          al_[f] = *(const bh8*)&Al[(64 * wr + 16 * f + lj) * ST + kk];
#pragma unroll
        for (int fm = 0; fm < 4; ++fm)
#pragma unroll
          for (int fn = 0; fn < 4; ++fn)
            acc[fm][fn] = __builtin_amdgcn_mfma_f32_16x16x32_bf16(al_[fm], bf[fn],
                                                                  acc[fm][fn], 0, 0, 0);
      }
    }
    __syncthreads();
  }

#pragma unroll
  for (int fm = 0; fm < 4; ++fm) {
    const int mrow = m0 + 64 * wr + 16 * fm + 4 * lg;
#pragma unroll
    for (int fn = 0; fn < 4; ++fn) {
      const int ncol = n0 + 64 * wc + 16 * fn + lj;
      const float bn = BIAS_N ? bias[ncol] : 0.0f;
#pragma unroll
      for (int r = 0; r < 4; ++r) {
        float val = acc[fm][fn][r] + (BIAS_N ? bn : bias[mrow + r]);
        Cb[(size_t)(mrow + r) * cld + ncol] = val;
      }
    }
  }
}

// ---------------------------------------------------------------------------
// FUSED MFMA autocorrelation + candidate selection + f64 refinement + top-40.
// Fully-unrolled kloop: q addrs = precomputed swizzled bases + compile-time
// ds-offset; k addrs = per-t512 XOR-hoisted bases (== swzk algebraically:
// bbyte%512<=48, 64u<=448 -> no carry into bit 9, and +128*(u>>1) commutes
// with the bits-[6:4] XOR). Invalid lanes (lj>=12) alias lj=0's B-reads;
// their D-columns are discarded -> ac for j<12 bit-identical to round 9.
// LDS overlay: ac (12KB) over dead q/k; qf/kf (24KB) over all -> 24.6KB.
// ---------------------------------------------------------------------------
template <int P>
__device__ __forceinline__ void ac_kloop(const char* __restrict__ qb,
                                         const char* __restrict__ kb,
                                         const int* __restrict__ aswz,
                                         int bbyte, f4 acc[4]) {
#pragma unroll
  for (int it = 0; it < 12; ++it) {
    const int t512 = it * 512;
    const int b512 = bbyte + t512;
    const int msk = ((b512 >> 9) & 7) << 4;
    const int e0 = b512 ^ msk;
    const int e1 = (b512 + 64) ^ msk;
#pragma unroll
    for (int u = 0; u < 8; ++u) {
      i4 w0 = *(const i4*)(qb + (aswz[2 * u] + t512));
      i4 w1 = *(const i4*)(qb + (aswz[2 * u + 1] + t512));
      uint_t w[8] = { (uint_t)w0.x, (uint_t)w0.y, (uint_t)w0.z, (uint_t)w0.w,
                      (uint_t)w1.x, (uint_t)w1.y, (uint_t)w1.z, (uint_t)w1.w };
      const int bb = ((u & 1) ? e1 : e0) + 128 * (u >> 1);
      bh8 Bf = *(const bh8*)(kb + bb);
#pragma unroll
      for (int e = 0; e < 4; ++e) {
        const int ro = (e >> 1) + 2 * P;
        const int sh = (e & 1) * 16;
        uint_t a0v = (uint_t)((((unsigned long long)w[ro + 1] << 32) | w[ro + 0]) >> sh);
        uint_t a1v = (uint_t)((((unsigned long long)w[ro + 2] << 32) | w[ro + 1]) >> sh);
        uint_t a2v = (uint_t)((((unsigned long long)w[ro + 3] << 32) | w[ro + 2]) >> sh);
        uint_t a3v = (uint_t)((((unsigned long long)w[ro + 4] << 32) | w[ro + 3]) >> sh);
        i4 ai = { (int)a0v, (int)a1v, (int)a2v, (int)a3v };
        bh8 Af = __builtin_bit_cast(bh8, ai);
        acc[e] = __builtin_amdgcn_mfma_f32_16x16x32_bf16(Af, Bf, acc[e], 0, 0, 0);
      }
    }
  }
}

__global__ __launch_bounds__(256) void cand_refine_kernel(const float* __restrict__ Q,
                                                          const float* __restrict__ K,
                                                          double* __restrict__ top_vals,
                                                          int* __restrict__ top_idx,
                                                          int c0) {
  // phase A: [0,6912) q bf16 (swz) | [6912,18688) k bf16 (swz)
  // post-kloop: ac f32 at [0,12288) (q/k dead after barrier)
  // phase C:   qf f32 [0,12288) | kf f32 [12288,24576) (ac dead)
  __shared__ __align__(16) char smem[24576];
  __shared__ float redf[8];
  __shared__ int   redi[4];
  __shared__ int   cnt_s;
  __shared__ float cv[NCAND_];
  __shared__ int   ci[NCAND_];
  __shared__ float sv[TOPK_];
  __shared__ int   si[TOPK_];
  __shared__ double refv[RFN_];
  char* kbase = smem + 6912;
  float* ac_s = (float*)smem;
  const int c = blockIdx.x;
  const int tid = threadIdx.x;
  const float* Qp = Q + (size_t)c * L_;
  const float* Kp = K + (size_t)c * L_;

  // ---- Phase A staging: f32 -> bf16 (cvt_pk), swizzled stores ----
  for (int x8 = tid; x8 < 432; x8 += 256) {
    int x = x8 * 8; int src = x - (x >= L_ ? L_ : 0);
    float4 f0 = *(const float4*)(Qp + src);
    float4 f1 = *(const float4*)(Qp + src + 4);
    i4 pk = { (int)cvt_pk_bf16(f0.x, f0.y), (int)cvt_pk_bf16(f0.z, f0.w),
              (int)cvt_pk_bf16(f1.x, f1.y), (int)cvt_pk_bf16(f1.z, f1.w) };
    *(i4*)(smem + swzq(16 * x8)) = pk;
  }
  for (int x8 = tid; x8 < 736; x8 += 256) {
    int x = x8 * 8; int src = x - 2816 + (x < 2816 ? L_ : 0);
    float4 f0 = *(const float4*)(Kp + src);
    float4 f1 = *(const float4*)(Kp + src + 4);
    i4 pk = { (int)cvt_pk_bf16(f0.x, f0.y), (int)cvt_pk_bf16(f0.z, f0.w),
              (int)cvt_pk_bf16(f1.x, f1.y), (int)cvt_pk_bf16(f1.z, f1.w) };
    *(i4*)(kbase + swzk(16 * x8)) = pk;
  }
  __syncthreads();

  const int lane = tid & 63, fg = tid >> 6;
  const int lg = lane >> 4, lj = lane & 15;
  const int abyte = 16 * lg + 32 * lj + 16 * (fg >> 1);
  const int jvalid = (lj < 12) ? 1 : 0;
  const int bbyte = 5632 + 16 * lg - (jvalid ? 512 * lj : 0);

  int aswz[16];
#pragma unroll
  for (int u = 0; u < 8; ++u) {
    aswz[2 * u]     = swzq(abyte + 64 * u);
    aswz[2 * u + 1] = swzq(abyte + 64 * u + 16);
  }

  f4 acc[4];
#pragma unroll
  for (int e = 0; e < 4; ++e) acc[e] = (f4){0.f, 0.f, 0.f, 0.f};

  if (fg & 1) ac_kloop<1>(smem, kbase, aswz, bbyte, acc);
  else        ac_kloop<0>(smem, kbase, aswz, bbyte, acc);

  __syncthreads();   // all kloop q/k reads done before ac overlays them

  if (jvalid) {
#pragma unroll
    for (int e = 0; e < 4; ++e) {
      int f = 4 * fg + e;
#pragma unroll
      for (int r = 0; r < 4; ++r) {
        int g = f + 16 * (4 * lg + r);      // fine lag in [0,256)
        ac_s[lj + 12 * g] = acc[e][r];      // tau = g + 256*lj
      }
    }
  }
  __syncthreads();

  float v[12];
#pragma unroll
  for (int it = 0; it < 12; ++it) v[it] = ac_s[tid + 256 * it];

  // block max
  float lm = v[0];
#pragma unroll
  for (int it = 1; it < 12; ++it) lm = fmaxf(lm, v[it]);
  for (int o = 32; o; o >>= 1) lm = fmaxf(lm, __shfl_down(lm, o));
  if ((tid & 63) == 0) redf[tid >> 6] = lm;
  __syncthreads();
  if (tid == 0) redf[4] = fmaxf(fmaxf(redf[0], redf[1]), fmaxf(redf[2], redf[3]));
  __syncthreads();
  const float Tmax = redf[4];

  auto bcount = [&](float T) -> int {
    int lc = 0;
#pragma unroll
    for (int it = 0; it < 12; ++it) lc += (v[it] > T) ? 1 : 0;
    for (int o = 32; o; o >>= 1) lc += __shfl_down(lc, o);
    __syncthreads();
    if ((tid & 63) == 0) redi[tid >> 6] = lc;
    __syncthreads();
    return redi[0] + redi[1] + redi[2] + redi[3];
  };

  float lo = Tmax - 128.0f;
  int cl = bcount(lo);
  for (int wd = 1; wd <= 5 && cl < CFLOOR_; ++wd) {
    lo = Tmax - 128.0f * (float)(1 << wd); cl = bcount(lo);
  }
  float hi = Tmax, T = lo;
  int cT = cl;
  for (int i = 0; i < 26 && cT > NCAND_; ++i) {
    float mid = 0.5f * (lo + hi);
    int cm = bcount(mid);
    if (cm >= CFLOOR_) { lo = mid; T = mid; cT = cm; } else hi = mid;
  }

  if (tid == 0) cnt_s = 0;
  __syncthreads();
#pragma unroll
  for (int it = 0; it < 12; ++it) {
    if (v[it] > T) {
      int pos = atomicAdd(&cnt_s, 1);
      if (pos < NCAND_) {
        int m = tid + 256 * it;
        int g = m / 12, j = m - 12 * g;
        cv[pos] = v[it];
        ci[pos] = g + 256 * j;
      }
    }
  }
  __syncthreads();
  const int cnt = cnt_s < NCAND_ ? cnt_s : NCAND_;

  // ---- Phase B (wave 0: f32 top-40 sort) || C-staging (waves 1-3) ----
  float* qf = (float*)smem;
  float* kf = (float*)(smem + 12288);
  if (tid >= 64) {
    for (int i = (tid - 64) * 4; i < L_; i += 768) {
      *(float4*)&qf[i] = *(const float4*)(Qp + i);
      *(float4*)&kf[i] = *(const float4*)(Kp + i);
    }
  } else {
    float mv = (tid < cnt) ? cv[tid] : -1e30f;
    int   mi = (tid < cnt) ? ci[tid] : (1 << 30);
    int used = 0;
    for (int r = 0; r < TOPK_; ++r) {
      float bv = used ? -1e30f : mv;
      int   bi = used ? (1 << 30) : mi;
      int   bl = tid;
      for (int o = 32; o; o >>= 1) {
        float ov = __shfl_down(bv, o);
        int   oi = __shfl_down(bi, o);
        int   ol = __shfl_down(bl, o);
        if (ov > bv || (ov == bv && oi < bi)) { bv = ov; bi = oi; bl = ol; }
      }
      bv = __shfl(bv, 0); bi = __shfl(bi, 0); bl = __shfl(bl, 0);
      if (tid == 0) { sv[r] = bv; si[r] = (bi < L_) ? bi : 0; }
      if (tid == bl) used = 1;
    }
  }
  __syncthreads();

  // ---- Phase C: exact f64 ac for top-RFN_, one WAVE per candidate, LDS ----
  const int R = cnt < RFN_ ? cnt : RFN_;
  for (int r = fg; r < R; r += 4) {
    const int tau = si[r];
    double a = 0.0;
#pragma unroll 4
    for (int u = 0; u < 48; ++u) {
      int t = lane + 64 * u;
      int qi = t + tau; qi -= (qi >= L_) ? L_ : 0;
      a = fma((double)qf[qi], (double)kf[t], a);
    }
#pragma unroll
    for (int o = 32; o; o >>= 1) a += __shfl_down(a, o);
    if (lane == 0) refv[r] = a;
  }
  __syncthreads();

  // ---- Phase D: wave 0 sorts refined (f64 desc, idx asc) -> ranks 0..R-1;
  //      ranks R..39 from f32 order (rounds 3/4 proven harmless) ----
  double* out_v = top_vals + (size_t)(c0 + c) * TOPK_;
  int*    out_i = top_idx  + (size_t)(c0 + c) * TOPK_;
  if (tid < 64) {
    double dv = (tid < R) ? refv[tid] : -1e300;
    int    di = (tid < R) ? si[tid]   : (1 << 30);
    int used = 0;
    for (int r = 0; r < R; ++r) {
      double bv = used ? -1e300 : dv;
      int    bi = used ? (1 << 30) : di;
      int    bl = tid;
      for (int o = 32; o; o >>= 1) {
        double ov = __shfl_down(bv, o);
        int    oi = __shfl_down(bi, o);
        int    ol = __shfl_down(bl, o);
        if (ov > bv || (ov == bv && oi < bi)) { bv = ov; bi = oi; bl = ol; }
      }
      bv = __shfl(bv, 0); bi = __shfl(bi, 0); bl = __shfl(bl, 0);
      if (tid == 0) { out_v[r] = bv; out_i[r] = (bi < L_) ? bi : 0; }
      if (tid == bl) used = 1;
    }
    if (tid >= R && tid < TOPK_) {
      out_v[tid] = (double)sv[tid];
      out_i[tid] = si[tid];
    }
  }
}

// ---------------------------------------------------------------------------
__global__ __launch_bounds__(256) void shifts_kernel(const int* __restrict__ top_idx,
                                                     int* __restrict__ shifts) {
  const int k = blockIdx.x;
  __shared__ double sred[256];
  double s = 0.0;
  for (int c = threadIdx.x; c < CH_; c += 256) s += (double)top_idx[(size_t)c * TOPK_ + k];
  sred[threadIdx.x] = s;
  __syncthreads();
  for (int o = 128; o > 0; o >>= 1) {
    if (threadIdx.x < o) sred[threadIdx.x] += sred[threadIdx.x + o];
    __syncthreads();
  }
  if (threadIdx.x == 0) shifts[k] = (int)((float)(sred[0] / (double)CH_));
}

__global__ __launch_bounds__(256) void softmax_kernel(const double* __restrict__ top_vals,
                                                      float* __restrict__ weights) {
  const int c = blockIdx.x * 256 + threadIdx.x;
  const double* v = top_vals + (size_t)c * TOPK_;
  double m = v[0];
  for (int k = 1; k < TOPK_; ++k) m = fmax(m, v[k]);
  double sum = 0.0;
  for (int k = 0; k < TOPK_; ++k) sum += exp(v[k] - m);
  double inv = 1.0 / sum;
  for (int k = 0; k < TOPK_; ++k)
    weights[(size_t)c * TOPK_ + k] = (float)(exp(v[k] - m) * inv);
}

// agg[c][t] = sum_k w[c][k] * V[c][(t+shift[k]) mod L], in place.
// 4 outputs per thread; wrap-free inner reads via 4-float LDS pad.
__global__ __launch_bounds__(256) void agg_kernel(float* __restrict__ Vc,
                                                  const float* __restrict__ weights,
                                                  const int* __restrict__ shifts) {
  const int c = blockIdx.x;
  __shared__ float v_s[L_ + 4];
  __shared__ float w_s[TOPK_];
  __shared__ int   s_s[TOPK_];
  float* row = Vc + (size_t)c * L_;
  for (int i = threadIdx.x * 4; i < L_; i += 1024)
    *(float4*)&v_s[i] = *(const float4*)(row + i);
  if (threadIdx.x < TOPK_) {
    w_s[threadIdx.x] = weights[(size_t)c * TOPK_ + threadIdx.x];
    s_s[threadIdx.x] = shifts[threadIdx.x];
  }
  __syncthreads();
  if (threadIdx.x < 4) v_s[L_ + threadIdx.x] = v_s[threadIdx.x];
  __syncthreads();
  for (int t = threadIdx.x * 4; t < L_; t += 1024) {
    float s0 = 0.f, s1 = 0.f, s2 = 0.f, s3 = 0.f;
#pragma unroll
    for (int k = 0; k < TOPK_; ++k) {
      int idx = t + s_s[k];
      if (idx >= L_) idx -= L_;
      const float w = w_s[k];
      s0 = fmaf(w, v_s[idx],     s0);
      s1 = fmaf(w, v_s[idx + 1], s1);
      s2 = fmaf(w, v_s[idx + 2], s2);
      s3 = fmaf(w, v_s[idx + 3], s3);
    }
    float4 o = { s0, s1, s2, s3 };
    *(float4*)(row + t) = o;
  }
}

// ---------------------------------------------------------------------------
extern "C" void kernel_launch(void* const* d_in, const int* in_sizes, int n_in,
                              void* d_out, int out_size, void* d_ws, size_t ws_size,
                              hipStream_t stream) {
  const float* query = (const float*)d_in[0];
  const float* key   = (const float*)d_in[1];
  const float* value = (const float*)d_in[2];
  const float* Wq = (const float*)d_in[3];
  const float* bq = (const float*)d_in[4];
  const float* Wk = (const float*)d_in[5];
  const float* bk = (const float*)d_in[6];
  const float* Wv = (const float*)d_in[7];
  const float* bvp = (const float*)d_in[8];
  const float* Wo = (const float*)d_in[9];
  const float* bo = (const float*)d_in[10];
  float* out = (float*)d_out;
  char* ws = (char*)d_ws;

  auto al = [](size_t x) { return (x + 255) & ~(size_t)255; };
  size_t off = 0;
  const size_t tv_off = off; off = al(off + (size_t)CH_ * TOPK_ * 8);
  const size_t ti_off = off; off = al(off + (size_t)CH_ * TOPK_ * 4);
  const size_t w_off  = off; off = al(off + (size_t)CH_ * TOPK_ * 4);
  const size_t sh_off = off; off = al(off + (size_t)TOPK_ * 4);
  const size_t small_end = off;                       // ~5.3 MB

  const size_t QK1   = (size_t)D_ * L_ * 4;           // 6.29 MB f32, one batch
  const size_t PBQK  = al(2 * QK1);                   // ~12.6 MB per batch
  const size_t AGG_BYTES    = (size_t)CH_ * L_ * 4;   // 96 MB
  const size_t BOUNCE_BYTES = (size_t)D_ * L_ * 4;    // 6 MB

  int nb; bool bounce;
  if (ws_size >= small_end + AGG_BYTES + PBQK) {
    bounce = false;
    size_t n = (ws_size - small_end - AGG_BYTES) / PBQK;
    nb = (int)(n > 16 ? 16 : n);
  } else {
    bounce = true;
    size_t rem = (ws_size > small_end + BOUNCE_BYTES) ? (ws_size - small_end - BOUNCE_BYTES) : 0;
    size_t n = rem / PBQK; nb = (int)(n > 16 ? 16 : n);
    if (nb < 1) nb = 1;
  }

  double* top_vals = (double*)(ws + tv_off);
  int*    top_idx  = (int*)(ws + ti_off);
  float*  weights  = (float*)(ws + w_off);
  int*    shifts   = (int*)(ws + sh_off);

  float* VcAgg;
  float* bounce_buf = nullptr;
  size_t qk_off;
  if (!bounce) {
    VcAgg = (float*)(ws + small_end);
    qk_off = small_end + al(AGG_BYTES);
  } else {
    bounce_buf = (float*)(ws + small_end);
    qk_off = small_end + al(BOUNCE_BYTES);
    VcAgg = (float*)d_out;
  }
  float* Qc = (float*)(ws + qk_off);
  float* Kc = (float*)(ws + qk_off + al((size_t)nb * QK1));

  dim3 blk(256);
  const long bXS = (long)L_ * D_;   // batch stride of inputs / out
  const long cQS = (long)D_ * L_;   // batch stride of channel-major tensors

  for (int b0 = 0; b0 < B_; b0 += nb) {
    int nbb = (B_ - b0 < nb) ? (B_ - b0) : nb;
    dim3 g(L_ / 128, D_ / 128, nbb);
    proj_kernel<<<g, blk, 0, stream>>>(query + (size_t)b0 * L_ * D_, Wq, bq, Qc);
    proj_kernel<<<g, blk, 0, stream>>>(key   + (size_t)b0 * L_ * D_, Wk, bk, Kc);
    cand_refine_kernel<<<nbb * D_, blk, 0, stream>>>(Qc, Kc, top_vals, top_idx, b0 * D_);
  }
  shifts_kernel<<<TOPK_, blk, 0, stream>>>(top_idx, shifts);
  softmax_kernel<<<CH_ / 256, blk, 0, stream>>>(top_vals, weights);

  {
    dim3 gp(L_ / 128, D_ / 128, B_);
    gemm_mfma<1, false, false><<<gp, blk, 0, stream>>>(
        Wv, value, bvp, VcAgg, 0, bXS, cQS, L_);
  }
  agg_kernel<<<CH_, blk, 0, stream>>>(VcAgg, weights, shifts);

  if (!bounce) {
    dim3 go(D_ / 128, L_ / 128, B_);    // (4, 24, 16)
    gemm_mfma<1, true, true><<<go, blk, 0, stream>>>(
        VcAgg, Wo, bo, out, cQS, 0, bXS, D_);
  } else {
    for (int b = 0; b < B_; ++b) {
      hipMemcpyAsync(bounce_buf, VcAgg + (size_t)b * D_ * L_, BOUNCE_BYTES,
                     hipMemcpyDeviceToDevice, stream);
      dim3 go(D_ / 128, L_ / 128, 1);
      gemm_mfma<1, true, true><<<go, blk, 0, stream>>>(
          bounce_buf, Wo, bo, out + (size_t)b * L_ * D_, 0, 0, 0, D_);
    }
  }
  (void)in_sizes; (void)n_in; (void)out_size;
}

// Round 12
// 1398.740 us; speedup vs baseline: 4.1982x; 1.1626x over previous
//
#include <hip/hip_runtime.h>
#include <hip/hip_bf16.h>
#include <math.h>

#define B_ 16
#define L_ 3072
#define D_ 512
#define CH_ (B_ * D_)   // 8192 channels
#define TOPK_ 40
#define NCAND_ 64       // candidate slots per channel
#define CFLOOR_ 52      // candidate count floor (>= RFN_ always)
#define RFN_ 24         // candidates refined exactly in f64 (rounds 3/4 proven)

typedef unsigned short ushort_t;
typedef unsigned int uint_t;
typedef __attribute__((ext_vector_type(8))) short bh8;   // 8 bf16 (4 VGPRs)
typedef __attribute__((ext_vector_type(4))) float f4;    // 4 f32 acc
typedef __attribute__((ext_vector_type(4))) int i4;      // 16B vector

__device__ __forceinline__ uint_t cvt_pk_bf16(float a, float b) {
  uint_t r;
  asm("v_cvt_pk_bf16_f32 %0, %1, %2" : "=v"(r) : "v"(a), "v"(b));
  return r;  // lo ushort = bf16(a), hi ushort = bf16(b)
}

// LDS byte-address swizzles (involutions; preserve 16B alignment)
__device__ __forceinline__ int swzq(int b) { return b ^ (((b >> 7) & 3) << 4); }
__device__ __forceinline__ int swzk(int b) { return b ^ (((b >> 9) & 7) << 4); }

// ---------------------------------------------------------------------------
// f32-VALU projection GEMM for Q AND K in one dispatch (z-split), 128x128
// tile, 8x8 per thread. Per-output product order ascending j with fmaf chain
// -> Qc/Kc BIT-IDENTICAL to rounds 4/7/11 (only launch shape changed).
// LDS layout idx = 140*kk + row + 4*(row>>5): injective (offset<140), 2-way
// bank conflicts on b128 reads (free).
// ---------------------------------------------------------------------------
__device__ __forceinline__ int xidx(int kk, int row) {
  return kk * 140 + row + ((row >> 5) << 2);
}

__global__ __launch_bounds__(256) void proj_qk_kernel(const float* __restrict__ Xq,
                                                      const float* __restrict__ Xk,
                                                      const float* __restrict__ Wq_,
                                                      const float* __restrict__ Wk_,
                                                      const float* __restrict__ bq_,
                                                      const float* __restrict__ bk_,
                                                      float* __restrict__ Pq,
                                                      float* __restrict__ Pk,
                                                      int nbb) {
  __shared__ float Xs[4480];
  __shared__ float Ws[4480];
  const int z = blockIdx.z;
  const bool isK = (z >= nbb);
  const float* X    = isK ? Xk : Xq;
  const float* W    = isK ? Wk_ : Wq_;
  const float* bias = isK ? bk_ : bq_;
  float* P          = isK ? Pk : Pq;
  const int b  = isK ? (z - nbb) : z;
  const int t0 = blockIdx.x * 128;
  const int i0 = blockIdx.y * 128;
  const int tid = threadIdx.x;
  const int tx = tid & 15, ty = tid >> 4;

  float acc[8][8];
#pragma unroll
  for (int r = 0; r < 8; ++r)
#pragma unroll
    for (int s = 0; s < 8; ++s) acc[r][s] = 0.0f;

  for (int j0 = 0; j0 < D_; j0 += 32) {
    {
      const int row = tid >> 1, jh = (tid & 1) * 16;
      const float* gx = X + ((size_t)b * L_ + t0 + row) * D_ + j0 + jh;
      const float* gw = W + (size_t)(i0 + row) * D_ + j0 + jh;
#pragma unroll
      for (int p = 0; p < 4; ++p) {
        float4 xv = *(const float4*)(gx + 4 * p);
        float4 wv = *(const float4*)(gw + 4 * p);
        int kk = jh + 4 * p;
        Xs[xidx(kk + 0, row)] = xv.x;
        Xs[xidx(kk + 1, row)] = xv.y;
        Xs[xidx(kk + 2, row)] = xv.z;
        Xs[xidx(kk + 3, row)] = xv.w;
        Ws[xidx(kk + 0, row)] = wv.x;
        Ws[xidx(kk + 1, row)] = wv.y;
        Ws[xidx(kk + 2, row)] = wv.z;
        Ws[xidx(kk + 3, row)] = wv.w;
      }
    }
    __syncthreads();
#pragma unroll 4
    for (int kk = 0; kk < 32; ++kk) {
      float a8[8], w8[8];
      *(float4*)&a8[0] = *(const float4*)&Xs[xidx(kk, 8 * ty)];
      *(float4*)&a8[4] = *(const float4*)&Xs[xidx(kk, 8 * ty) + 4];
      *(float4*)&w8[0] = *(const float4*)&Ws[xidx(kk, 8 * tx)];
      *(float4*)&w8[4] = *(const float4*)&Ws[xidx(kk, 8 * tx) + 4];
#pragma unroll
      for (int r = 0; r < 8; ++r)
#pragma unroll
        for (int s = 0; s < 8; ++s)
          acc[r][s] = fmaf(a8[r], w8[s], acc[r][s]);
    }
    __syncthreads();
  }
#pragma unroll
  for (int s = 0; s < 8; ++s) {
    const int i = i0 + 8 * tx + s;
    const float bia = bias[i];
    float* dst = P + (size_t)(b * D_ + i) * L_ + t0 + 8 * ty;
    float4 v0 = { acc[0][s] + bia, acc[1][s] + bia, acc[2][s] + bia, acc[3][s] + bia };
    float4 v1 = { acc[4][s] + bia, acc[5][s] + bia, acc[6][s] + bia, acc[7][s] + bia };
    *(float4*)dst = v0;
    *(float4*)(dst + 4) = v1;
  }
}

// ---------------------------------------------------------------------------
// MFMA GEMM, 128x128 tile, 4 waves — LINEAR path (V proj, out GEMM).
// NPASS=1 (plain bf16): round-4/8 PROVEN config (absmax floor).
// ---------------------------------------------------------------------------
template <int NPASS, int BK, int ST>
__device__ __forceinline__ void stage_rows(const float* __restrict__ g0,
                                           ushort_t* __restrict__ Hh,
                                           ushort_t* __restrict__ Hl,
                                           int tid) {
  const int row = tid >> 1;
  const int cb = (tid & 1) * (BK / 2);
  const float* g = g0 + (size_t)row * 512 + cb;
  ushort_t* lh = Hh + row * ST + cb;
  ushort_t* ll = Hl + row * ST + cb;
#pragma unroll
  for (int p = 0; p < BK / 8; ++p) {
    float4 v = *(const float4*)(g + 4 * p);
    uint_t h01 = cvt_pk_bf16(v.x, v.y);
    uint_t h23 = cvt_pk_bf16(v.z, v.w);
    *(uint2*)(lh + 4 * p) = make_uint2(h01, h23);
    if (NPASS == 3) {
      float x0 = __builtin_bit_cast(float, h01 << 16);
      float x1 = __builtin_bit_cast(float, h01 & 0xFFFF0000u);
      float x2 = __builtin_bit_cast(float, h23 << 16);
      float x3 = __builtin_bit_cast(float, h23 & 0xFFFF0000u);
      uint_t l01 = cvt_pk_bf16(v.x - x0, v.y - x1);
      uint_t l23 = cvt_pk_bf16(v.z - x2, v.w - x3);
      *(uint2*)(ll + 4 * p) = make_uint2(l01, l23);
    }
  }
}

template <int NPASS, bool ATR, bool BIAS_N>
__global__ __launch_bounds__(256) void gemm_mfma(const float* __restrict__ Ap,
                                                 const float* __restrict__ Bp,
                                                 const float* __restrict__ bias,
                                                 float* __restrict__ Cp,
                                                 long aBS, long bBS, long cBS,
                                                 int cld) {
  constexpr int BK = (NPASS == 3) ? 32 : 64;
  constexpr int ST = (NPASS == 3) ? 40 : 72;
  __shared__ ushort_t Ah[128 * ST];
  __shared__ ushort_t Bh[128 * ST];
  __shared__ ushort_t Al[(NPASS == 3) ? 128 * ST : 8];
  __shared__ ushort_t Bl[(NPASS == 3) ? 128 * ST : 8];

  const float* Asrc = Ap + (size_t)blockIdx.z * aBS;
  const float* Bsrc = Bp + (size_t)blockIdx.z * bBS;
  float* Cb = Cp + (size_t)blockIdx.z * cBS;
  const int n0 = blockIdx.x * 128, m0 = blockIdx.y * 128;
  const int tid = threadIdx.x;
  const int lane = tid & 63, w = tid >> 6;
  const int wr = w >> 1, wc = w & 1;
  const int lj = lane & 15, lg = lane >> 4;

  f4 acc[4][4];
#pragma unroll
  for (int fm = 0; fm < 4; ++fm)
#pragma unroll
    for (int fn = 0; fn < 4; ++fn) acc[fm][fn] = (f4){0.f, 0.f, 0.f, 0.f};

  for (int kc = 0; kc < 512; kc += BK) {
    if (!ATR) {
      stage_rows<NPASS, BK, ST>(Asrc + (size_t)m0 * 512 + kc, Ah, Al, tid);
    } else {
      constexpr int TPC = 256 / BK;
      constexpr int TC  = 128 / TPC;
      const int jl = tid / TPC, ts = tid % TPC;
      const float* g = Asrc + (size_t)(kc + jl) * L_ + m0 + ts * TC;
#pragma unroll
      for (int p = 0; p < TC / 4; ++p) {
        float4 v = *(const float4*)(g + 4 * p);
        uint_t h01 = cvt_pk_bf16(v.x, v.y);
        uint_t h23 = cvt_pk_bf16(v.z, v.w);
        int t = ts * TC + 4 * p;
        Ah[(t + 0) * ST + jl] = (ushort_t)(h01 & 0xFFFFu);
        Ah[(t + 1) * ST + jl] = (ushort_t)(h01 >> 16);
        Ah[(t + 2) * ST + jl] = (ushort_t)(h23 & 0xFFFFu);
        Ah[(t + 3) * ST + jl] = (ushort_t)(h23 >> 16);
        if (NPASS == 3) {
          float x0 = __builtin_bit_cast(float, h01 << 16);
          float x1 = __builtin_bit_cast(float, h01 & 0xFFFF0000u);
          float x2 = __builtin_bit_cast(float, h23 << 16);
          float x3 = __builtin_bit_cast(float, h23 & 0xFFFF0000u);
          uint_t l01 = cvt_pk_bf16(v.x - x0, v.y - x1);
          uint_t l23 = cvt_pk_bf16(v.z - x2, v.w - x3);
          Al[(t + 0) * ST + jl] = (ushort_t)(l01 & 0xFFFFu);
          Al[(t + 1) * ST + jl] = (ushort_t)(l01 >> 16);
          Al[(t + 2) * ST + jl] = (ushort_t)(l23 & 0xFFFFu);
          Al[(t + 3) * ST + jl] = (ushort_t)(l23 >> 16);
        }
      }
    }
    stage_rows<NPASS, BK, ST>(Bsrc + (size_t)n0 * 512 + kc, Bh, Bl, tid);
    __syncthreads();

#pragma unroll
    for (int ks = 0; ks < BK / 32; ++ks) {
      const int kk = ks * 32 + 8 * lg;
      bh8 af[4], bf[4];
#pragma unroll
      for (int f = 0; f < 4; ++f)
        af[f] = *(const bh8*)&Ah[(64 * wr + 16 * f + lj) * ST + kk];
#pragma unroll
      for (int f = 0; f < 4; ++f)
        bf[f] = *(const bh8*)&Bh[(64 * wc + 16 * f + lj) * ST + kk];
#pragma unroll
      for (int fm = 0; fm < 4; ++fm)
#pragma unroll
        for (int fn = 0; fn < 4; ++fn)
          acc[fm][fn] = __builtin_amdgcn_mfma_f32_16x16x32_bf16(af[fm], bf[fn],
                                                                acc[fm][fn], 0, 0, 0);
      if (NPASS == 3) {
        bh8 bl_[4];
#pragma unroll
        for (int f = 0; f < 4; ++f)
          bl_[f] = *(const bh8*)&Bl[(64 * wc + 16 * f + lj) * ST + kk];
#pragma unroll
        for (int fm = 0; fm < 4; ++fm)
#pragma unroll
          for (int fn = 0; fn < 4; ++fn)
            acc[fm][fn] = __builtin_amdgcn_mfma_f32_16x16x32_bf16(af[fm], bl_[fn],
                                                                  acc[fm][fn], 0, 0, 0);
        bh8 al_[4];
#pragma unroll
        for (int f = 0; f < 4; ++f)
          al_[f] = *(const bh8*)&Al[(64 * wr + 16 * f + lj) * ST + kk];
#pragma unroll
        for (int fm = 0; fm < 4; ++fm)
#pragma unroll
          for (int fn = 0; fn < 4; ++fn)
            acc[fm][fn] = __builtin_amdgcn_mfma_f32_16x16x32_bf16(al_[fm], bf[fn],
                                                                  acc[fm][fn], 0, 0, 0);
      }
    }
    __syncthreads();
  }

#pragma unroll
  for (int fm = 0; fm < 4; ++fm) {
    const int mrow = m0 + 64 * wr + 16 * fm + 4 * lg;
#pragma unroll
    for (int fn = 0; fn < 4; ++fn) {
      const int ncol = n0 + 64 * wc + 16 * fn + lj;
      const float bn = BIAS_N ? bias[ncol] : 0.0f;
#pragma unroll
      for (int r = 0; r < 4; ++r) {
        float val = acc[fm][fn][r] + (BIAS_N ? bn : bias[mrow + r]);
        Cb[(size_t)(mrow + r) * cld + ncol] = val;
      }
    }
  }
}

// ---------------------------------------------------------------------------
// FUSED MFMA autocorrelation + candidate selection + f64 refinement + top-40.
// Round-12 changes (all selection-invariant):
//  - Phase C 2-wide: each lane takes t in {2*lane+128u, +1} (adjacent-pair
//    LDS reads), 24 iters; straddle via qf[L]=qf[0] pad. f64 re-partition
//    perturbs values at ~1e-13 (7 orders below the passing f32-level noise).
//  - RFN 24 (rounds 3/4 proven; cnt >= 52 always -> R constant).
//  - Rank-based sorts (phases B & D): same total order (v desc, idx asc)
//    -> bit-identical outputs; invalid lanes share rank >= cnt >= 52 >= 40.
// ---------------------------------------------------------------------------
template <int P>
__device__ __forceinline__ void ac_kloop(const char* __restrict__ qb,
                                         const char* __restrict__ kb,
                                         const int* __restrict__ aswz,
                                         int bbyte, f4 acc[4]) {
#pragma unroll
  for (int it = 0; it < 12; ++it) {
    const int t512 = it * 512;
    const int b512 = bbyte + t512;
    const int msk = ((b512 >> 9) & 7) << 4;
    const int e0 = b512 ^ msk;
    const int e1 = (b512 + 64) ^ msk;
#pragma unroll
    for (int u = 0; u < 8; ++u) {
      i4 w0 = *(const i4*)(qb + (aswz[2 * u] + t512));
      i4 w1 = *(const i4*)(qb + (aswz[2 * u + 1] + t512));
      uint_t w[8] = { (uint_t)w0.x, (uint_t)w0.y, (uint_t)w0.z, (uint_t)w0.w,
                      (uint_t)w1.x, (uint_t)w1.y, (uint_t)w1.z, (uint_t)w1.w };
      const int bb = ((u & 1) ? e1 : e0) + 128 * (u >> 1);
      bh8 Bf = *(const bh8*)(kb + bb);
#pragma unroll
      for (int e = 0; e < 4; ++e) {
        const int ro = (e >> 1) + 2 * P;
        const int sh = (e & 1) * 16;
        uint_t a0v = (uint_t)((((unsigned long long)w[ro + 1] << 32) | w[ro + 0]) >> sh);
        uint_t a1v = (uint_t)((((unsigned long long)w[ro + 2] << 32) | w[ro + 1]) >> sh);
        uint_t a2v = (uint_t)((((unsigned long long)w[ro + 3] << 32) | w[ro + 2]) >> sh);
        uint_t a3v = (uint_t)((((unsigned long long)w[ro + 4] << 32) | w[ro + 3]) >> sh);
        i4 ai = { (int)a0v, (int)a1v, (int)a2v, (int)a3v };
        bh8 Af = __builtin_bit_cast(bh8, ai);
        acc[e] = __builtin_amdgcn_mfma_f32_16x16x32_bf16(Af, Bf, acc[e], 0, 0, 0);
      }
    }
  }
}

__global__ __launch_bounds__(256) void cand_refine_kernel(const float* __restrict__ Q,
                                                          const float* __restrict__ K,
                                                          double* __restrict__ top_vals,
                                                          int* __restrict__ top_idx,
                                                          int c0) {
  // phase A: [0,6912) q bf16 (swz) | [6912,18688) k bf16 (swz)
  // post-kloop: ac f32 at [0,12288)
  // phase C:   qf f32 [0,12292) (incl. qf[L] pad) | kf f32 [12304,24592)
  __shared__ __align__(16) char smem[24608];
  __shared__ float redf[8];
  __shared__ int   redi[4];
  __shared__ int   cnt_s;
  __shared__ float cv[NCAND_];
  __shared__ int   ci[NCAND_];
  __shared__ float sv[TOPK_];
  __shared__ int   si[TOPK_];
  __shared__ double refv[RFN_];
  char* kbase = smem + 6912;
  float* ac_s = (float*)smem;
  const int c = blockIdx.x;
  const int tid = threadIdx.x;
  const float* Qp = Q + (size_t)c * L_;
  const float* Kp = K + (size_t)c * L_;

  // ---- Phase A staging: f32 -> bf16 (cvt_pk), swizzled stores ----
  for (int x8 = tid; x8 < 432; x8 += 256) {
    int x = x8 * 8; int src = x - (x >= L_ ? L_ : 0);
    float4 f0 = *(const float4*)(Qp + src);
    float4 f1 = *(const float4*)(Qp + src + 4);
    i4 pk = { (int)cvt_pk_bf16(f0.x, f0.y), (int)cvt_pk_bf16(f0.z, f0.w),
              (int)cvt_pk_bf16(f1.x, f1.y), (int)cvt_pk_bf16(f1.z, f1.w) };
    *(i4*)(smem + swzq(16 * x8)) = pk;
  }
  for (int x8 = tid; x8 < 736; x8 += 256) {
    int x = x8 * 8; int src = x - 2816 + (x < 2816 ? L_ : 0);
    float4 f0 = *(const float4*)(Kp + src);
    float4 f1 = *(const float4*)(Kp + src + 4);
    i4 pk = { (int)cvt_pk_bf16(f0.x, f0.y), (int)cvt_pk_bf16(f0.z, f0.w),
              (int)cvt_pk_bf16(f1.x, f1.y), (int)cvt_pk_bf16(f1.z, f1.w) };
    *(i4*)(kbase + swzk(16 * x8)) = pk;
  }
  __syncthreads();

  const int lane = tid & 63, fg = tid >> 6;
  const int lg = lane >> 4, lj = lane & 15;
  const int abyte = 16 * lg + 32 * lj + 16 * (fg >> 1);
  const int jvalid = (lj < 12) ? 1 : 0;
  const int bbyte = 5632 + 16 * lg - (jvalid ? 512 * lj : 0);

  int aswz[16];
#pragma unroll
  for (int u = 0; u < 8; ++u) {
    aswz[2 * u]     = swzq(abyte + 64 * u);
    aswz[2 * u + 1] = swzq(abyte + 64 * u + 16);
  }

  f4 acc[4];
#pragma unroll
  for (int e = 0; e < 4; ++e) acc[e] = (f4){0.f, 0.f, 0.f, 0.f};

  if (fg & 1) ac_kloop<1>(smem, kbase, aswz, bbyte, acc);
  else        ac_kloop<0>(smem, kbase, aswz, bbyte, acc);

  __syncthreads();   // all kloop q/k reads done before ac overlays them

  if (jvalid) {
#pragma unroll
    for (int e = 0; e < 4; ++e) {
      int f = 4 * fg + e;
#pragma unroll
      for (int r = 0; r < 4; ++r) {
        int g = f + 16 * (4 * lg + r);      // fine lag in [0,256)
        ac_s[lj + 12 * g] = acc[e][r];      // tau = g + 256*lj
      }
    }
  }
  __syncthreads();

  float v[12];
#pragma unroll
  for (int it = 0; it < 12; ++it) v[it] = ac_s[tid + 256 * it];

  // block max
  float lm = v[0];
#pragma unroll
  for (int it = 1; it < 12; ++it) lm = fmaxf(lm, v[it]);
  for (int o = 32; o; o >>= 1) lm = fmaxf(lm, __shfl_down(lm, o));
  if ((tid & 63) == 0) redf[tid >> 6] = lm;
  __syncthreads();
  if (tid == 0) redf[4] = fmaxf(fmaxf(redf[0], redf[1]), fmaxf(redf[2], redf[3]));
  __syncthreads();
  const float Tmax = redf[4];

  auto bcount = [&](float T) -> int {
    int lc = 0;
#pragma unroll
    for (int it = 0; it < 12; ++it) lc += (v[it] > T) ? 1 : 0;
    for (int o = 32; o; o >>= 1) lc += __shfl_down(lc, o);
    __syncthreads();
    if ((tid & 63) == 0) redi[tid >> 6] = lc;
    __syncthreads();
    return redi[0] + redi[1] + redi[2] + redi[3];
  };

  float lo = Tmax - 128.0f;
  int cl = bcount(lo);
  for (int wd = 1; wd <= 5 && cl < CFLOOR_; ++wd) {
    lo = Tmax - 128.0f * (float)(1 << wd); cl = bcount(lo);
  }
  float hi = Tmax, T = lo;
  int cT = cl;
  for (int i = 0; i < 26 && cT > NCAND_; ++i) {
    float mid = 0.5f * (lo + hi);
    int cm = bcount(mid);
    if (cm >= CFLOOR_) { lo = mid; T = mid; cT = cm; } else hi = mid;
  }

  if (tid == 0) cnt_s = 0;
  __syncthreads();
#pragma unroll
  for (int it = 0; it < 12; ++it) {
    if (v[it] > T) {
      int pos = atomicAdd(&cnt_s, 1);
      if (pos < NCAND_) {
        int m = tid + 256 * it;
        int g = m / 12, j = m - 12 * g;
        cv[pos] = v[it];
        ci[pos] = g + 256 * j;
      }
    }
  }
  __syncthreads();
  const int cnt = cnt_s < NCAND_ ? cnt_s : NCAND_;

  // ---- Phase B (wave 0: rank-based f32 top-40) || C-staging (waves 1-3) ---
  float* qf = (float*)smem;
  float* kf = (float*)(smem + 12304);
  if (tid >= 64) {
    for (int i = (tid - 64) * 4; i < L_; i += 768) {
      *(float4*)&qf[i] = *(const float4*)(Qp + i);
      *(float4*)&kf[i] = *(const float4*)(Kp + i);
    }
    if (tid == 64) qf[L_] = qf[0];   // circular pad for phase-C pair reads
  } else {
    float vi = (tid < cnt) ? cv[tid] : -1e30f;
    int   ii = (tid < cnt) ? ci[tid] : (1 << 30);
    int rank = 0;
#pragma unroll 8
    for (int j = 0; j < 64; ++j) {
      float vj = __shfl(vi, j);
      int   ij = __shfl(ii, j);
      rank += ((vj > vi) || (vj == vi && ij < ii)) ? 1 : 0;
    }
    if (rank < TOPK_) { sv[rank] = vi; si[rank] = (ii < L_) ? ii : 0; }
  }
  __syncthreads();

  // ---- Phase C: exact f64 ac for top-RFN_, one WAVE per candidate, 2-wide -
  for (int r = fg; r < RFN_; r += 4) {
    const int tau = si[r];
    double a = 0.0;
#pragma unroll 4
    for (int u = 0; u < 24; ++u) {
      int t = 2 * lane + 128 * u;
      int qi = t + tau; qi -= (qi >= L_) ? L_ : 0;
      float q0 = qf[qi], q1 = qf[qi + 1];
      float k0 = kf[t],  k1 = kf[t + 1];
      a = fma((double)q0, (double)k0, a);
      a = fma((double)q1, (double)k1, a);
    }
#pragma unroll
    for (int o = 32; o; o >>= 1) a += __shfl_down(a, o);
    if (lane == 0) refv[r] = a;
  }
  __syncthreads();

  // ---- Phase D: rank-based f64 sort of refined -> ranks 0..RFN_-1;
  //      ranks RFN_..39 from f32 order (rounds 3/4 proven harmless) ----
  double* out_v = top_vals + (size_t)(c0 + c) * TOPK_;
  int*    out_i = top_idx  + (size_t)(c0 + c) * TOPK_;
  if (tid < 64) {
    double dv = (tid < RFN_) ? refv[tid] : -1e300;
    int    di = (tid < RFN_) ? si[tid]   : (1 << 30);
    int rank = 0;
#pragma unroll 8
    for (int j = 0; j < RFN_; ++j) {
      double dj = __shfl(dv, j);
      int    ij = __shfl(di, j);
      rank += ((dj > dv) || (dj == dv && ij < di)) ? 1 : 0;
    }
    if (tid < RFN_) { out_v[rank] = dv; out_i[rank] = di; }
    if (tid >= RFN_ && tid < TOPK_) {
      out_v[tid] = (double)sv[tid];
      out_i[tid] = si[tid];
    }
  }
}

// ---------------------------------------------------------------------------
__global__ __launch_bounds__(256) void shifts_kernel(const int* __restrict__ top_idx,
                                                     int* __restrict__ shifts) {
  const int k = blockIdx.x;
  __shared__ double sred[256];
  double s = 0.0;
  for (int c = threadIdx.x; c < CH_; c += 256) s += (double)top_idx[(size_t)c * TOPK_ + k];
  sred[threadIdx.x] = s;
  __syncthreads();
  for (int o = 128; o > 0; o >>= 1) {
    if (threadIdx.x < o) sred[threadIdx.x] += sred[threadIdx.x + o];
    __syncthreads();
  }
  if (threadIdx.x == 0) shifts[k] = (int)((float)(sred[0] / (double)CH_));
}

__global__ __launch_bounds__(256) void softmax_kernel(const double* __restrict__ top_vals,
                                                      float* __restrict__ weights) {
  const int c = blockIdx.x * 256 + threadIdx.x;
  const double* v = top_vals + (size_t)c * TOPK_;
  double m = v[0];
  for (int k = 1; k < TOPK_; ++k) m = fmax(m, v[k]);
  double sum = 0.0;
  for (int k = 0; k < TOPK_; ++k) sum += exp(v[k] - m);
  double inv = 1.0 / sum;
  for (int k = 0; k < TOPK_; ++k)
    weights[(size_t)c * TOPK_ + k] = (float)(exp(v[k] - m) * inv);
}

// agg[c][t] = sum_k w[c][k] * V[c][(t+shift[k]) mod L], in place.
__global__ __launch_bounds__(256) void agg_kernel(float* __restrict__ Vc,
                                                  const float* __restrict__ weights,
                                                  const int* __restrict__ shifts) {
  const int c = blockIdx.x;
  __shared__ float v_s[L_ + 4];
  __shared__ float w_s[TOPK_];
  __shared__ int   s_s[TOPK_];
  float* row = Vc + (size_t)c * L_;
  for (int i = threadIdx.x * 4; i < L_; i += 1024)
    *(float4*)&v_s[i] = *(const float4*)(row + i);
  if (threadIdx.x < TOPK_) {
    w_s[threadIdx.x] = weights[(size_t)c * TOPK_ + threadIdx.x];
    s_s[threadIdx.x] = shifts[threadIdx.x];
  }
  __syncthreads();
  if (threadIdx.x < 4) v_s[L_ + threadIdx.x] = v_s[threadIdx.x];
  __syncthreads();
  for (int t = threadIdx.x * 4; t < L_; t += 1024) {
    float s0 = 0.f, s1 = 0.f, s2 = 0.f, s3 = 0.f;
#pragma unroll
    for (int k = 0; k < TOPK_; ++k) {
      int idx = t + s_s[k];
      if (idx >= L_) idx -= L_;
      const float w = w_s[k];
      s0 = fmaf(w, v_s[idx],     s0);
      s1 = fmaf(w, v_s[idx + 1], s1);
      s2 = fmaf(w, v_s[idx + 2], s2);
      s3 = fmaf(w, v_s[idx + 3], s3);
    }
    float4 o = { s0, s1, s2, s3 };
    *(float4*)(row + t) = o;
  }
}

// ---------------------------------------------------------------------------
extern "C" void kernel_launch(void* const* d_in, const int* in_sizes, int n_in,
                              void* d_out, int out_size, void* d_ws, size_t ws_size,
                              hipStream_t stream) {
  const float* query = (const float*)d_in[0];
  const float* key   = (const float*)d_in[1];
  const float* value = (const float*)d_in[2];
  const float* Wq = (const float*)d_in[3];
  const float* bq = (const float*)d_in[4];
  const float* Wk = (const float*)d_in[5];
  const float* bk = (const float*)d_in[6];
  const float* Wv = (const float*)d_in[7];
  const float* bvp = (const float*)d_in[8];
  const float* Wo = (const float*)d_in[9];
  const float* bo = (const float*)d_in[10];
  float* out = (float*)d_out;
  char* ws = (char*)d_ws;

  auto al = [](size_t x) { return (x + 255) & ~(size_t)255; };
  size_t off = 0;
  const size_t tv_off = off; off = al(off + (size_t)CH_ * TOPK_ * 8);
  const size_t ti_off = off; off = al(off + (size_t)CH_ * TOPK_ * 4);
  const size_t w_off  = off; off = al(off + (size_t)CH_ * TOPK_ * 4);
  const size_t sh_off = off; off = al(off + (size_t)TOPK_ * 4);
  const size_t small_end = off;                       // ~5.3 MB

  const size_t QK1   = (size_t)D_ * L_ * 4;           // 6.29 MB f32, one batch
  const size_t PBQK  = al(2 * QK1);                   // ~12.6 MB per batch
  const size_t AGG_BYTES    = (size_t)CH_ * L_ * 4;   // 96 MB
  const size_t BOUNCE_BYTES = (size_t)D_ * L_ * 4;    // 6 MB

  int nb; bool bounce;
  if (ws_size >= small_end + AGG_BYTES + PBQK) {
    bounce = false;
    size_t n = (ws_size - small_end - AGG_BYTES) / PBQK;
    nb = (int)(n > 16 ? 16 : n);
  } else {
    bounce = true;
    size_t rem = (ws_size > small_end + BOUNCE_BYTES) ? (ws_size - small_end - BOUNCE_BYTES) : 0;
    size_t n = rem / PBQK; nb = (int)(n > 16 ? 16 : n);
    if (nb < 1) nb = 1;
  }

  double* top_vals = (double*)(ws + tv_off);
  int*    top_idx  = (int*)(ws + ti_off);
  float*  weights  = (float*)(ws + w_off);
  int*    shifts   = (int*)(ws + sh_off);

  float* VcAgg;
  float* bounce_buf = nullptr;
  size_t qk_off;
  if (!bounce) {
    VcAgg = (float*)(ws + small_end);
    qk_off = small_end + al(AGG_BYTES);
  } else {
    bounce_buf = (float*)(ws + small_end);
    qk_off = small_end + al(BOUNCE_BYTES);
    VcAgg = (float*)d_out;
  }
  float* Qc = (float*)(ws + qk_off);
  float* Kc = (float*)(ws + qk_off + al((size_t)nb * QK1));

  dim3 blk(256);
  const long bXS = (long)L_ * D_;   // batch stride of inputs / out
  const long cQS = (long)D_ * L_;   // batch stride of channel-major tensors

  for (int b0 = 0; b0 < B_; b0 += nb) {
    int nbb = (B_ - b0 < nb) ? (B_ - b0) : nb;
    dim3 g(L_ / 128, D_ / 128, 2 * nbb);
    proj_qk_kernel<<<g, blk, 0, stream>>>(query + (size_t)b0 * L_ * D_,
                                          key   + (size_t)b0 * L_ * D_,
                                          Wq, Wk, bq, bk, Qc, Kc, nbb);
    cand_refine_kernel<<<nbb * D_, blk, 0, stream>>>(Qc, Kc, top_vals, top_idx, b0 * D_);
  }
  shifts_kernel<<<TOPK_, blk, 0, stream>>>(top_idx, shifts);
  softmax_kernel<<<CH_ / 256, blk, 0, stream>>>(top_vals, weights);

  {
    dim3 gp(L_ / 128, D_ / 128, B_);
    gemm_mfma<1, false, false><<<gp, blk, 0, stream>>>(
        Wv, value, bvp, VcAgg, 0, bXS, cQS, L_);
  }
  agg_kernel<<<CH_, blk, 0, stream>>>(VcAgg, weights, shifts);

  if (!bounce) {
    dim3 go(D_ / 128, L_ / 128, B_);    // (4, 24, 16)
    gemm_mfma<1, true, true><<<go, blk, 0, stream>>>(
        VcAgg, Wo, bo, out, cQS, 0, bXS, D_);
  } else {
    for (int b = 0; b < B_; ++b) {
      hipMemcpyAsync(bounce_buf, VcAgg + (size_t)b * D_ * L_, BOUNCE_BYTES,
                     hipMemcpyDeviceToDevice, stream);
      dim3 go(D_ / 128, L_ / 128, 1);
      gemm_mfma<1, true, true><<<go, blk, 0, stream>>>(
          bounce_buf, Wo, bo, out + (size_t)b * L_ * D_, 0, 0, 0, D_);
    }
  }
  (void)in_sizes; (void)n_in; (void)out_size;
}

// Round 13
// 1392.137 us; speedup vs baseline: 4.2181x; 1.0047x over previous
//
#include <hip/hip_runtime.h>
#include <hip/hip_bf16.h>
#include <math.h>

#define B_ 16
#define L_ 3072
#define D_ 512
#define CH_ (B_ * D_)   // 8192 channels
#define TOPK_ 40
#define NCAND_ 64       // candidate slots per channel
#define CFLOOR_ 52      // candidate count floor (>= RFN_ always)
#define RFN_ 24         // candidates refined exactly in f64 (rounds 3/4 proven)

typedef unsigned short ushort_t;
typedef unsigned int uint_t;
typedef __attribute__((ext_vector_type(8))) short bh8;   // 8 bf16 (4 VGPRs)
typedef __attribute__((ext_vector_type(4))) float f4;    // 4 f32 acc
typedef __attribute__((ext_vector_type(4))) int i4;      // 16B vector

__device__ __forceinline__ uint_t cvt_pk_bf16(float a, float b) {
  uint_t r;
  asm("v_cvt_pk_bf16_f32 %0, %1, %2" : "=v"(r) : "v"(a), "v"(b));
  return r;  // lo ushort = bf16(a), hi ushort = bf16(b)
}

// LDS byte-address swizzles (involutions; preserve 16B alignment)
__device__ __forceinline__ int swzq(int b) { return b ^ (((b >> 7) & 3) << 4); }
__device__ __forceinline__ int swzk(int b) { return b ^ (((b >> 9) & 7) << 4); }

// ---------------------------------------------------------------------------
// f32-VALU projection GEMM for Q AND K in one dispatch (z-split), 128x128
// tile, 8x8 per thread, ASYNC-STAGE SPLIT (T14): next j-panel's global loads
// issue into named regs right after the LDS-ready barrier, flying during the
// 2048-FMA compute phase. Values + fmaf order + LDS layout unchanged ->
// Qc/Kc BIT-IDENTICAL to rounds 4/7/12.
// LDS layout idx = 140*kk + row + 4*(row>>5): injective (offset<140), 2-way
// bank conflicts on b128 reads (free).
// ---------------------------------------------------------------------------
__device__ __forceinline__ int xidx(int kk, int row) {
  return kk * 140 + row + ((row >> 5) << 2);
}

__global__ __launch_bounds__(256) void proj_qk_kernel(const float* __restrict__ Xq,
                                                      const float* __restrict__ Xk,
                                                      const float* __restrict__ Wq_,
                                                      const float* __restrict__ Wk_,
                                                      const float* __restrict__ bq_,
                                                      const float* __restrict__ bk_,
                                                      float* __restrict__ Pq,
                                                      float* __restrict__ Pk,
                                                      int nbb) {
  __shared__ float Xs[4480];
  __shared__ float Ws[4480];
  const int z = blockIdx.z;
  const bool isK = (z >= nbb);
  const float* X    = isK ? Xk : Xq;
  const float* W    = isK ? Wk_ : Wq_;
  const float* bias = isK ? bk_ : bq_;
  float* P          = isK ? Pk : Pq;
  const int b  = isK ? (z - nbb) : z;
  const int t0 = blockIdx.x * 128;
  const int i0 = blockIdx.y * 128;
  const int tid = threadIdx.x;
  const int tx = tid & 15, ty = tid >> 4;
  const int row = tid >> 1, jh = (tid & 1) * 16;

  const float* gxb = X + ((size_t)b * L_ + t0 + row) * D_ + jh;
  const float* gwb = W + (size_t)(i0 + row) * D_ + jh;

  // prefetch regs for the j-panel about to be staged (named: rule #20)
  float4 nx0 = *(const float4*)(gxb + 0);
  float4 nx1 = *(const float4*)(gxb + 4);
  float4 nx2 = *(const float4*)(gxb + 8);
  float4 nx3 = *(const float4*)(gxb + 12);
  float4 nw0 = *(const float4*)(gwb + 0);
  float4 nw1 = *(const float4*)(gwb + 4);
  float4 nw2 = *(const float4*)(gwb + 8);
  float4 nw3 = *(const float4*)(gwb + 12);

  float acc[8][8];
#pragma unroll
  for (int r = 0; r < 8; ++r)
#pragma unroll
    for (int s = 0; s < 8; ++s) acc[r][s] = 0.0f;

  for (int j0 = 0; j0 < D_; j0 += 32) {
    __syncthreads();   // previous compute done reading LDS
    {
      Xs[xidx(jh + 0,  row)] = nx0.x;
      Xs[xidx(jh + 1,  row)] = nx0.y;
      Xs[xidx(jh + 2,  row)] = nx0.z;
      Xs[xidx(jh + 3,  row)] = nx0.w;
      Xs[xidx(jh + 4,  row)] = nx1.x;
      Xs[xidx(jh + 5,  row)] = nx1.y;
      Xs[xidx(jh + 6,  row)] = nx1.z;
      Xs[xidx(jh + 7,  row)] = nx1.w;
      Xs[xidx(jh + 8,  row)] = nx2.x;
      Xs[xidx(jh + 9,  row)] = nx2.y;
      Xs[xidx(jh + 10, row)] = nx2.z;
      Xs[xidx(jh + 11, row)] = nx2.w;
      Xs[xidx(jh + 12, row)] = nx3.x;
      Xs[xidx(jh + 13, row)] = nx3.y;
      Xs[xidx(jh + 14, row)] = nx3.z;
      Xs[xidx(jh + 15, row)] = nx3.w;
      Ws[xidx(jh + 0,  row)] = nw0.x;
      Ws[xidx(jh + 1,  row)] = nw0.y;
      Ws[xidx(jh + 2,  row)] = nw0.z;
      Ws[xidx(jh + 3,  row)] = nw0.w;
      Ws[xidx(jh + 4,  row)] = nw1.x;
      Ws[xidx(jh + 5,  row)] = nw1.y;
      Ws[xidx(jh + 6,  row)] = nw1.z;
      Ws[xidx(jh + 7,  row)] = nw1.w;
      Ws[xidx(jh + 8,  row)] = nw2.x;
      Ws[xidx(jh + 9,  row)] = nw2.y;
      Ws[xidx(jh + 10, row)] = nw2.z;
      Ws[xidx(jh + 11, row)] = nw2.w;
      Ws[xidx(jh + 12, row)] = nw3.x;
      Ws[xidx(jh + 13, row)] = nw3.y;
      Ws[xidx(jh + 14, row)] = nw3.z;
      Ws[xidx(jh + 15, row)] = nw3.w;
    }
    __syncthreads();   // LDS ready
    if (j0 + 32 < D_) {
      const float* gx = gxb + j0 + 32;
      const float* gw = gwb + j0 + 32;
      nx0 = *(const float4*)(gx + 0);
      nx1 = *(const float4*)(gx + 4);
      nx2 = *(const float4*)(gx + 8);
      nx3 = *(const float4*)(gx + 12);
      nw0 = *(const float4*)(gw + 0);
      nw1 = *(const float4*)(gw + 4);
      nw2 = *(const float4*)(gw + 8);
      nw3 = *(const float4*)(gw + 12);
    }
#pragma unroll 4
    for (int kk = 0; kk < 32; ++kk) {
      float a8[8], w8[8];
      *(float4*)&a8[0] = *(const float4*)&Xs[xidx(kk, 8 * ty)];
      *(float4*)&a8[4] = *(const float4*)&Xs[xidx(kk, 8 * ty) + 4];
      *(float4*)&w8[0] = *(const float4*)&Ws[xidx(kk, 8 * tx)];
      *(float4*)&w8[4] = *(const float4*)&Ws[xidx(kk, 8 * tx) + 4];
#pragma unroll
      for (int r = 0; r < 8; ++r)
#pragma unroll
        for (int s = 0; s < 8; ++s)
          acc[r][s] = fmaf(a8[r], w8[s], acc[r][s]);
    }
  }
#pragma unroll
  for (int s = 0; s < 8; ++s) {
    const int i = i0 + 8 * tx + s;
    const float bia = bias[i];
    float* dst = P + (size_t)(b * D_ + i) * L_ + t0 + 8 * ty;
    float4 v0 = { acc[0][s] + bia, acc[1][s] + bia, acc[2][s] + bia, acc[3][s] + bia };
    float4 v1 = { acc[4][s] + bia, acc[5][s] + bia, acc[6][s] + bia, acc[7][s] + bia };
    *(float4*)dst = v0;
    *(float4*)(dst + 4) = v1;
  }
}

// ---------------------------------------------------------------------------
// MFMA GEMM, 128x128 tile, 4 waves — LINEAR path (V proj, out GEMM).
// NPASS=1 (plain bf16): round-4/8 PROVEN config (absmax floor).
// ---------------------------------------------------------------------------
template <int NPASS, int BK, int ST>
__device__ __forceinline__ void stage_rows(const float* __restrict__ g0,
                                           ushort_t* __restrict__ Hh,
                                           ushort_t* __restrict__ Hl,
                                           int tid) {
  const int row = tid >> 1;
  const int cb = (tid & 1) * (BK / 2);
  const float* g = g0 + (size_t)row * 512 + cb;
  ushort_t* lh = Hh + row * ST + cb;
  ushort_t* ll = Hl + row * ST + cb;
#pragma unroll
  for (int p = 0; p < BK / 8; ++p) {
    float4 v = *(const float4*)(g + 4 * p);
    uint_t h01 = cvt_pk_bf16(v.x, v.y);
    uint_t h23 = cvt_pk_bf16(v.z, v.w);
    *(uint2*)(lh + 4 * p) = make_uint2(h01, h23);
    if (NPASS == 3) {
      float x0 = __builtin_bit_cast(float, h01 << 16);
      float x1 = __builtin_bit_cast(float, h01 & 0xFFFF0000u);
      float x2 = __builtin_bit_cast(float, h23 << 16);
      float x3 = __builtin_bit_cast(float, h23 & 0xFFFF0000u);
      uint_t l01 = cvt_pk_bf16(v.x - x0, v.y - x1);
      uint_t l23 = cvt_pk_bf16(v.z - x2, v.w - x3);
      *(uint2*)(ll + 4 * p) = make_uint2(l01, l23);
    }
  }
}

template <int NPASS, bool ATR, bool BIAS_N>
__global__ __launch_bounds__(256) void gemm_mfma(const float* __restrict__ Ap,
                                                 const float* __restrict__ Bp,
                                                 const float* __restrict__ bias,
                                                 float* __restrict__ Cp,
                                                 long aBS, long bBS, long cBS,
                                                 int cld) {
  constexpr int BK = (NPASS == 3) ? 32 : 64;
  constexpr int ST = (NPASS == 3) ? 40 : 72;
  __shared__ ushort_t Ah[128 * ST];
  __shared__ ushort_t Bh[128 * ST];
  __shared__ ushort_t Al[(NPASS == 3) ? 128 * ST : 8];
  __shared__ ushort_t Bl[(NPASS == 3) ? 128 * ST : 8];

  const float* Asrc = Ap + (size_t)blockIdx.z * aBS;
  const float* Bsrc = Bp + (size_t)blockIdx.z * bBS;
  float* Cb = Cp + (size_t)blockIdx.z * cBS;
  const int n0 = blockIdx.x * 128, m0 = blockIdx.y * 128;
  const int tid = threadIdx.x;
  const int lane = tid & 63, w = tid >> 6;
  const int wr = w >> 1, wc = w & 1;
  const int lj = lane & 15, lg = lane >> 4;

  f4 acc[4][4];
#pragma unroll
  for (int fm = 0; fm < 4; ++fm)
#pragma unroll
    for (int fn = 0; fn < 4; ++fn) acc[fm][fn] = (f4){0.f, 0.f, 0.f, 0.f};

  for (int kc = 0; kc < 512; kc += BK) {
    if (!ATR) {
      stage_rows<NPASS, BK, ST>(Asrc + (size_t)m0 * 512 + kc, Ah, Al, tid);
    } else {
      constexpr int TPC = 256 / BK;
      constexpr int TC  = 128 / TPC;
      const int jl = tid / TPC, ts = tid % TPC;
      const float* g = Asrc + (size_t)(kc + jl) * L_ + m0 + ts * TC;
#pragma unroll
      for (int p = 0; p < TC / 4; ++p) {
        float4 v = *(const float4*)(g + 4 * p);
        uint_t h01 = cvt_pk_bf16(v.x, v.y);
        uint_t h23 = cvt_pk_bf16(v.z, v.w);
        int t = ts * TC + 4 * p;
        Ah[(t + 0) * ST + jl] = (ushort_t)(h01 & 0xFFFFu);
        Ah[(t + 1) * ST + jl] = (ushort_t)(h01 >> 16);
        Ah[(t + 2) * ST + jl] = (ushort_t)(h23 & 0xFFFFu);
        Ah[(t + 3) * ST + jl] = (ushort_t)(h23 >> 16);
        if (NPASS == 3) {
          float x0 = __builtin_bit_cast(float, h01 << 16);
          float x1 = __builtin_bit_cast(float, h01 & 0xFFFF0000u);
          float x2 = __builtin_bit_cast(float, h23 << 16);
          float x3 = __builtin_bit_cast(float, h23 & 0xFFFF0000u);
          uint_t l01 = cvt_pk_bf16(v.x - x0, v.y - x1);
          uint_t l23 = cvt_pk_bf16(v.z - x2, v.w - x3);
          Al[(t + 0) * ST + jl] = (ushort_t)(l01 & 0xFFFFu);
          Al[(t + 1) * ST + jl] = (ushort_t)(l01 >> 16);
          Al[(t + 2) * ST + jl] = (ushort_t)(l23 & 0xFFFFu);
          Al[(t + 3) * ST + jl] = (ushort_t)(l23 >> 16);
        }
      }
    }
    stage_rows<NPASS, BK, ST>(Bsrc + (size_t)n0 * 512 + kc, Bh, Bl, tid);
    __syncthreads();

#pragma unroll
    for (int ks = 0; ks < BK / 32; ++ks) {
      const int kk = ks * 32 + 8 * lg;
      bh8 af[4], bf[4];
#pragma unroll
      for (int f = 0; f < 4; ++f)
        af[f] = *(const bh8*)&Ah[(64 * wr + 16 * f + lj) * ST + kk];
#pragma unroll
      for (int f = 0; f < 4; ++f)
        bf[f] = *(const bh8*)&Bh[(64 * wc + 16 * f + lj) * ST + kk];
#pragma unroll
      for (int fm = 0; fm < 4; ++fm)
#pragma unroll
        for (int fn = 0; fn < 4; ++fn)
          acc[fm][fn] = __builtin_amdgcn_mfma_f32_16x16x32_bf16(af[fm], bf[fn],
                                                                acc[fm][fn], 0, 0, 0);
      if (NPASS == 3) {
        bh8 bl_[4];
#pragma unroll
        for (int f = 0; f < 4; ++f)
          bl_[f] = *(const bh8*)&Bl[(64 * wc + 16 * f + lj) * ST + kk];
#pragma unroll
        for (int fm = 0; fm < 4; ++fm)
#pragma unroll
          for (int fn = 0; fn < 4; ++fn)
            acc[fm][fn] = __builtin_amdgcn_mfma_f32_16x16x32_bf16(af[fm], bl_[fn],
                                                                  acc[fm][fn], 0, 0, 0);
        bh8 al_[4];
#pragma unroll
        for (int f = 0; f < 4; ++f)
          al_[f] = *(const bh8*)&Al[(64 * wr + 16 * f + lj) * ST + kk];
#pragma unroll
        for (int fm = 0; fm < 4; ++fm)
#pragma unroll
          for (int fn = 0; fn < 4; ++fn)
            acc[fm][fn] = __builtin_amdgcn_mfma_f32_16x16x32_bf16(al_[fm], bf[fn],
                                                                  acc[fm][fn], 0, 0, 0);
      }
    }
    __syncthreads();
  }

#pragma unroll
  for (int fm = 0; fm < 4; ++fm) {
    const int mrow = m0 + 64 * wr + 16 * fm + 4 * lg;
#pragma unroll
    for (int fn = 0; fn < 4; ++fn) {
      const int ncol = n0 + 64 * wc + 16 * fn + lj;
      const float bn = BIAS_N ? bias[ncol] : 0.0f;
#pragma unroll
      for (int r = 0; r < 4; ++r) {
        float val = acc[fm][fn][r] + (BIAS_N ? bn : bias[mrow + r]);
        Cb[(size_t)(mrow + r) * cld + ncol] = val;
      }
    }
  }
}

// ---------------------------------------------------------------------------
// FUSED MFMA autocorrelation + candidate selection + f64 refinement + top-40.
// (Round-12 structure, PASSED at absmax floor — unchanged.)
// ---------------------------------------------------------------------------
template <int P>
__device__ __forceinline__ void ac_kloop(const char* __restrict__ qb,
                                         const char* __restrict__ kb,
                                         const int* __restrict__ aswz,
                                         int bbyte, f4 acc[4]) {
#pragma unroll
  for (int it = 0; it < 12; ++it) {
    const int t512 = it * 512;
    const int b512 = bbyte + t512;
    const int msk = ((b512 >> 9) & 7) << 4;
    const int e0 = b512 ^ msk;
    const int e1 = (b512 + 64) ^ msk;
#pragma unroll
    for (int u = 0; u < 8; ++u) {
      i4 w0 = *(const i4*)(qb + (aswz[2 * u] + t512));
      i4 w1 = *(const i4*)(qb + (aswz[2 * u + 1] + t512));
      uint_t w[8] = { (uint_t)w0.x, (uint_t)w0.y, (uint_t)w0.z, (uint_t)w0.w,
                      (uint_t)w1.x, (uint_t)w1.y, (uint_t)w1.z, (uint_t)w1.w };
      const int bb = ((u & 1) ? e1 : e0) + 128 * (u >> 1);
      bh8 Bf = *(const bh8*)(kb + bb);
#pragma unroll
      for (int e = 0; e < 4; ++e) {
        const int ro = (e >> 1) + 2 * P;
        const int sh = (e & 1) * 16;
        uint_t a0v = (uint_t)((((unsigned long long)w[ro + 1] << 32) | w[ro + 0]) >> sh);
        uint_t a1v = (uint_t)((((unsigned long long)w[ro + 2] << 32) | w[ro + 1]) >> sh);
        uint_t a2v = (uint_t)((((unsigned long long)w[ro + 3] << 32) | w[ro + 2]) >> sh);
        uint_t a3v = (uint_t)((((unsigned long long)w[ro + 4] << 32) | w[ro + 3]) >> sh);
        i4 ai = { (int)a0v, (int)a1v, (int)a2v, (int)a3v };
        bh8 Af = __builtin_bit_cast(bh8, ai);
        acc[e] = __builtin_amdgcn_mfma_f32_16x16x32_bf16(Af, Bf, acc[e], 0, 0, 0);
      }
    }
  }
}

__global__ __launch_bounds__(256) void cand_refine_kernel(const float* __restrict__ Q,
                                                          const float* __restrict__ K,
                                                          double* __restrict__ top_vals,
                                                          int* __restrict__ top_idx,
                                                          int c0) {
  // phase A: [0,6912) q bf16 (swz) | [6912,18688) k bf16 (swz)
  // post-kloop: ac f32 at [0,12288)
  // phase C:   qf f32 [0,12292) (incl. qf[L] pad) | kf f32 [12304,24592)
  __shared__ __align__(16) char smem[24608];
  __shared__ float redf[8];
  __shared__ int   redi[4];
  __shared__ int   cnt_s;
  __shared__ float cv[NCAND_];
  __shared__ int   ci[NCAND_];
  __shared__ float sv[TOPK_];
  __shared__ int   si[TOPK_];
  __shared__ double refv[RFN_];
  char* kbase = smem + 6912;
  float* ac_s = (float*)smem;
  const int c = blockIdx.x;
  const int tid = threadIdx.x;
  const float* Qp = Q + (size_t)c * L_;
  const float* Kp = K + (size_t)c * L_;

  // ---- Phase A staging: f32 -> bf16 (cvt_pk), swizzled stores ----
  for (int x8 = tid; x8 < 432; x8 += 256) {
    int x = x8 * 8; int src = x - (x >= L_ ? L_ : 0);
    float4 f0 = *(const float4*)(Qp + src);
    float4 f1 = *(const float4*)(Qp + src + 4);
    i4 pk = { (int)cvt_pk_bf16(f0.x, f0.y), (int)cvt_pk_bf16(f0.z, f0.w),
              (int)cvt_pk_bf16(f1.x, f1.y), (int)cvt_pk_bf16(f1.z, f1.w) };
    *(i4*)(smem + swzq(16 * x8)) = pk;
  }
  for (int x8 = tid; x8 < 736; x8 += 256) {
    int x = x8 * 8; int src = x - 2816 + (x < 2816 ? L_ : 0);
    float4 f0 = *(const float4*)(Kp + src);
    float4 f1 = *(const float4*)(Kp + src + 4);
    i4 pk = { (int)cvt_pk_bf16(f0.x, f0.y), (int)cvt_pk_bf16(f0.z, f0.w),
              (int)cvt_pk_bf16(f1.x, f1.y), (int)cvt_pk_bf16(f1.z, f1.w) };
    *(i4*)(kbase + swzk(16 * x8)) = pk;
  }
  __syncthreads();

  const int lane = tid & 63, fg = tid >> 6;
  const int lg = lane >> 4, lj = lane & 15;
  const int abyte = 16 * lg + 32 * lj + 16 * (fg >> 1);
  const int jvalid = (lj < 12) ? 1 : 0;
  const int bbyte = 5632 + 16 * lg - (jvalid ? 512 * lj : 0);

  int aswz[16];
#pragma unroll
  for (int u = 0; u < 8; ++u) {
    aswz[2 * u]     = swzq(abyte + 64 * u);
    aswz[2 * u + 1] = swzq(abyte + 64 * u + 16);
  }

  f4 acc[4];
#pragma unroll
  for (int e = 0; e < 4; ++e) acc[e] = (f4){0.f, 0.f, 0.f, 0.f};

  if (fg & 1) ac_kloop<1>(smem, kbase, aswz, bbyte, acc);
  else        ac_kloop<0>(smem, kbase, aswz, bbyte, acc);

  __syncthreads();   // all kloop q/k reads done before ac overlays them

  if (jvalid) {
#pragma unroll
    for (int e = 0; e < 4; ++e) {
      int f = 4 * fg + e;
#pragma unroll
      for (int r = 0; r < 4; ++r) {
        int g = f + 16 * (4 * lg + r);      // fine lag in [0,256)
        ac_s[lj + 12 * g] = acc[e][r];      // tau = g + 256*lj
      }
    }
  }
  __syncthreads();

  float v[12];
#pragma unroll
  for (int it = 0; it < 12; ++it) v[it] = ac_s[tid + 256 * it];

  // block max
  float lm = v[0];
#pragma unroll
  for (int it = 1; it < 12; ++it) lm = fmaxf(lm, v[it]);
  for (int o = 32; o; o >>= 1) lm = fmaxf(lm, __shfl_down(lm, o));
  if ((tid & 63) == 0) redf[tid >> 6] = lm;
  __syncthreads();
  if (tid == 0) redf[4] = fmaxf(fmaxf(redf[0], redf[1]), fmaxf(redf[2], redf[3]));
  __syncthreads();
  const float Tmax = redf[4];

  auto bcount = [&](float T) -> int {
    int lc = 0;
#pragma unroll
    for (int it = 0; it < 12; ++it) lc += (v[it] > T) ? 1 : 0;
    for (int o = 32; o; o >>= 1) lc += __shfl_down(lc, o);
    __syncthreads();
    if ((tid & 63) == 0) redi[tid >> 6] = lc;
    __syncthreads();
    return redi[0] + redi[1] + redi[2] + redi[3];
  };

  float lo = Tmax - 128.0f;
  int cl = bcount(lo);
  for (int wd = 1; wd <= 5 && cl < CFLOOR_; ++wd) {
    lo = Tmax - 128.0f * (float)(1 << wd); cl = bcount(lo);
  }
  float hi = Tmax, T = lo;
  int cT = cl;
  for (int i = 0; i < 26 && cT > NCAND_; ++i) {
    float mid = 0.5f * (lo + hi);
    int cm = bcount(mid);
    if (cm >= CFLOOR_) { lo = mid; T = mid; cT = cm; } else hi = mid;
  }

  if (tid == 0) cnt_s = 0;
  __syncthreads();
#pragma unroll
  for (int it = 0; it < 12; ++it) {
    if (v[it] > T) {
      int pos = atomicAdd(&cnt_s, 1);
      if (pos < NCAND_) {
        int m = tid + 256 * it;
        int g = m / 12, j = m - 12 * g;
        cv[pos] = v[it];
        ci[pos] = g + 256 * j;
      }
    }
  }
  __syncthreads();
  const int cnt = cnt_s < NCAND_ ? cnt_s : NCAND_;

  // ---- Phase B (wave 0: rank-based f32 top-40) || C-staging (waves 1-3) ---
  float* qf = (float*)smem;
  float* kf = (float*)(smem + 12304);
  if (tid >= 64) {
    for (int i = (tid - 64) * 4; i < L_; i += 768) {
      *(float4*)&qf[i] = *(const float4*)(Qp + i);
      *(float4*)&kf[i] = *(const float4*)(Kp + i);
    }
    if (tid == 64) qf[L_] = qf[0];   // circular pad for phase-C pair reads
  } else {
    float vi = (tid < cnt) ? cv[tid] : -1e30f;
    int   ii = (tid < cnt) ? ci[tid] : (1 << 30);
    int rank = 0;
#pragma unroll 8
    for (int j = 0; j < 64; ++j) {
      float vj = __shfl(vi, j);
      int   ij = __shfl(ii, j);
      rank += ((vj > vi) || (vj == vi && ij < ii)) ? 1 : 0;
    }
    if (rank < TOPK_) { sv[rank] = vi; si[rank] = (ii < L_) ? ii : 0; }
  }
  __syncthreads();

  // ---- Phase C: exact f64 ac for top-RFN_, one WAVE per candidate, 2-wide -
  for (int r = fg; r < RFN_; r += 4) {
    const int tau = si[r];
    double a = 0.0;
#pragma unroll 4
    for (int u = 0; u < 24; ++u) {
      int t = 2 * lane + 128 * u;
      int qi = t + tau; qi -= (qi >= L_) ? L_ : 0;
      float q0 = qf[qi], q1 = qf[qi + 1];
      float k0 = kf[t],  k1 = kf[t + 1];
      a = fma((double)q0, (double)k0, a);
      a = fma((double)q1, (double)k1, a);
    }
#pragma unroll
    for (int o = 32; o; o >>= 1) a += __shfl_down(a, o);
    if (lane == 0) refv[r] = a;
  }
  __syncthreads();

  // ---- Phase D: rank-based f64 sort of refined -> ranks 0..RFN_-1;
  //      ranks RFN_..39 from f32 order (rounds 3/4 proven harmless) ----
  double* out_v = top_vals + (size_t)(c0 + c) * TOPK_;
  int*    out_i = top_idx  + (size_t)(c0 + c) * TOPK_;
  if (tid < 64) {
    double dv = (tid < RFN_) ? refv[tid] : -1e300;
    int    di = (tid < RFN_) ? si[tid]   : (1 << 30);
    int rank = 0;
#pragma unroll 8
    for (int j = 0; j < RFN_; ++j) {
      double dj = __shfl(dv, j);
      int    ij = __shfl(di, j);
      rank += ((dj > dv) || (dj == dv && ij < di)) ? 1 : 0;
    }
    if (tid < RFN_) { out_v[rank] = dv; out_i[rank] = di; }
    if (tid >= RFN_ && tid < TOPK_) {
      out_v[tid] = (double)sv[tid];
      out_i[tid] = si[tid];
    }
  }
}

// ---------------------------------------------------------------------------
__global__ __launch_bounds__(256) void shifts_kernel(const int* __restrict__ top_idx,
                                                     int* __restrict__ shifts) {
  const int k = blockIdx.x;
  __shared__ double sred[256];
  double s = 0.0;
  for (int c = threadIdx.x; c < CH_; c += 256) s += (double)top_idx[(size_t)c * TOPK_ + k];
  sred[threadIdx.x] = s;
  __syncthreads();
  for (int o = 128; o > 0; o >>= 1) {
    if (threadIdx.x < o) sred[threadIdx.x] += sred[threadIdx.x + o];
    __syncthreads();
  }
  if (threadIdx.x == 0) shifts[k] = (int)((float)(sred[0] / (double)CH_));
}

__global__ __launch_bounds__(256) void softmax_kernel(const double* __restrict__ top_vals,
                                                      float* __restrict__ weights) {
  const int c = blockIdx.x * 256 + threadIdx.x;
  const double* v = top_vals + (size_t)c * TOPK_;
  double m = v[0];
  for (int k = 1; k < TOPK_; ++k) m = fmax(m, v[k]);
  double sum = 0.0;
  for (int k = 0; k < TOPK_; ++k) sum += exp(v[k] - m);
  double inv = 1.0 / sum;
  for (int k = 0; k < TOPK_; ++k)
    weights[(size_t)c * TOPK_ + k] = (float)(exp(v[k] - m) * inv);
}

// agg[c][t] = sum_k w[c][k] * V[c][(t+shift[k]) mod L], in place.
__global__ __launch_bounds__(256) void agg_kernel(float* __restrict__ Vc,
                                                  const float* __restrict__ weights,
                                                  const int* __restrict__ shifts) {
  const int c = blockIdx.x;
  __shared__ float v_s[L_ + 4];
  __shared__ float w_s[TOPK_];
  __shared__ int   s_s[TOPK_];
  float* row = Vc + (size_t)c * L_;
  for (int i = threadIdx.x * 4; i < L_; i += 1024)
    *(float4*)&v_s[i] = *(const float4*)(row + i);
  if (threadIdx.x < TOPK_) {
    w_s[threadIdx.x] = weights[(size_t)c * TOPK_ + threadIdx.x];
    s_s[threadIdx.x] = shifts[threadIdx.x];
  }
  __syncthreads();
  if (threadIdx.x < 4) v_s[L_ + threadIdx.x] = v_s[threadIdx.x];
  __syncthreads();
  for (int t = threadIdx.x * 4; t < L_; t += 1024) {
    float s0 = 0.f, s1 = 0.f, s2 = 0.f, s3 = 0.f;
#pragma unroll
    for (int k = 0; k < TOPK_; ++k) {
      int idx = t + s_s[k];
      if (idx >= L_) idx -= L_;
      const float w = w_s[k];
      s0 = fmaf(w, v_s[idx],     s0);
      s1 = fmaf(w, v_s[idx + 1], s1);
      s2 = fmaf(w, v_s[idx + 2], s2);
      s3 = fmaf(w, v_s[idx + 3], s3);
    }
    float4 o = { s0, s1, s2, s3 };
    *(float4*)(row + t) = o;
  }
}

// ---------------------------------------------------------------------------
extern "C" void kernel_launch(void* const* d_in, const int* in_sizes, int n_in,
                              void* d_out, int out_size, void* d_ws, size_t ws_size,
                              hipStream_t stream) {
  const float* query = (const float*)d_in[0];
  const float* key   = (const float*)d_in[1];
  const float* value = (const float*)d_in[2];
  const float* Wq = (const float*)d_in[3];
  const float* bq = (const float*)d_in[4];
  const float* Wk = (const float*)d_in[5];
  const float* bk = (const float*)d_in[6];
  const float* Wv = (const float*)d_in[7];
  const float* bvp = (const float*)d_in[8];
  const float* Wo = (const float*)d_in[9];
  const float* bo = (const float*)d_in[10];
  float* out = (float*)d_out;
  char* ws = (char*)d_ws;

  auto al = [](size_t x) { return (x + 255) & ~(size_t)255; };
  size_t off = 0;
  const size_t tv_off = off; off = al(off + (size_t)CH_ * TOPK_ * 8);
  const size_t ti_off = off; off = al(off + (size_t)CH_ * TOPK_ * 4);
  const size_t w_off  = off; off = al(off + (size_t)CH_ * TOPK_ * 4);
  const size_t sh_off = off; off = al(off + (size_t)TOPK_ * 4);
  const size_t small_end = off;                       // ~5.3 MB

  const size_t QK1   = (size_t)D_ * L_ * 4;           // 6.29 MB f32, one batch
  const size_t PBQK  = al(2 * QK1);                   // ~12.6 MB per batch
  const size_t AGG_BYTES    = (size_t)CH_ * L_ * 4;   // 96 MB
  const size_t BOUNCE_BYTES = (size_t)D_ * L_ * 4;    // 6 MB

  int nb; bool bounce;
  if (ws_size >= small_end + AGG_BYTES + PBQK) {
    bounce = false;
    size_t n = (ws_size - small_end - AGG_BYTES) / PBQK;
    nb = (int)(n > 16 ? 16 : n);
  } else {
    bounce = true;
    size_t rem = (ws_size > small_end + BOUNCE_BYTES) ? (ws_size - small_end - BOUNCE_BYTES) : 0;
    size_t n = rem / PBQK; nb = (int)(n > 16 ? 16 : n);
    if (nb < 1) nb = 1;
  }

  double* top_vals = (double*)(ws + tv_off);
  int*    top_idx  = (int*)(ws + ti_off);
  float*  weights  = (float*)(ws + w_off);
  int*    shifts   = (int*)(ws + sh_off);

  float* VcAgg;
  float* bounce_buf = nullptr;
  size_t qk_off;
  if (!bounce) {
    VcAgg = (float*)(ws + small_end);
    qk_off = small_end + al(AGG_BYTES);
  } else {
    bounce_buf = (float*)(ws + small_end);
    qk_off = small_end + al(BOUNCE_BYTES);
    VcAgg = (float*)d_out;
  }
  float* Qc = (float*)(ws + qk_off);
  float* Kc = (float*)(ws + qk_off + al((size_t)nb * QK1));

  dim3 blk(256);
  const long bXS = (long)L_ * D_;   // batch stride of inputs / out
  const long cQS = (long)D_ * L_;   // batch stride of channel-major tensors

  for (int b0 = 0; b0 < B_; b0 += nb) {
    int nbb = (B_ - b0 < nb) ? (B_ - b0) : nb;
    dim3 g(L_ / 128, D_ / 128, 2 * nbb);
    proj_qk_kernel<<<g, blk, 0, stream>>>(query + (size_t)b0 * L_ * D_,
                                          key   + (size_t)b0 * L_ * D_,
                                          Wq, Wk, bq, bk, Qc, Kc, nbb);
    cand_refine_kernel<<<nbb * D_, blk, 0, stream>>>(Qc, Kc, top_vals, top_idx, b0 * D_);
  }
  shifts_kernel<<<TOPK_, blk, 0, stream>>>(top_idx, shifts);
  softmax_kernel<<<CH_ / 256, blk, 0, stream>>>(top_vals, weights);

  {
    dim3 gp(L_ / 128, D_ / 128, B_);
    gemm_mfma<1, false, false><<<gp, blk, 0, stream>>>(
        Wv, value, bvp, VcAgg, 0, bXS, cQS, L_);
  }
  agg_kernel<<<CH_, blk, 0, stream>>>(VcAgg, weights, shifts);

  if (!bounce) {
    dim3 go(D_ / 128, L_ / 128, B_);    // (4, 24, 16)
    gemm_mfma<1, true, true><<<go, blk, 0, stream>>>(
        VcAgg, Wo, bo, out, cQS, 0, bXS, D_);
  } else {
    for (int b = 0; b < B_; ++b) {
      hipMemcpyAsync(bounce_buf, VcAgg + (size_t)b * D_ * L_, BOUNCE_BYTES,
                     hipMemcpyDeviceToDevice, stream);
      dim3 go(D_ / 128, L_ / 128, 1);
      gemm_mfma<1, true, true><<<go, blk, 0, stream>>>(
          bounce_buf, Wo, bo, out + (size_t)b * L_ * D_, 0, 0, 0, D_);
    }
  }
  (void)in_sizes; (void)n_in; (void)out_size;
}